// Round 1
// 12153.587 us; speedup vs baseline: 8.0379x; 8.0379x over previous
//
#include <hip/hip_runtime.h>

// ============================================================================
// InformationInteractive (gcn, cross_attn, gcn, cross_attn).
// Round 12: algebraic decomposition of the gather-GEMM
//   einsum([center|neigh-center], W) = X@(Wc-Wn)^T [n] + X@Wn^T [gathered j]
// (16x FLOP reduction), max_k commuted past lrelu/inorm (both monotone),
// and a single tiled f32 GEMM (64x64x16, k-major LDS, prefetch) replacing
// the naive one-row-per-block k_lin everywhere (incl. QK^T and PV with
// split-K). Output stays f32 (round-11 forensics). knn kernel untouched
// (verified watermarked 17-pass argmin).
// ============================================================================

namespace {

constexpr int BB = 2, NPV = 2048, CCH = 256, KNB = 16;
typedef long long i64;
constexpr i64 NSTR  = (i64)NPV * 256;   // 524288 floats
constexpr i64 NSTR2 = (i64)NPV * 512;   // 1048576 floats
constexpr i64 MB = 1048576;

__device__ __forceinline__ float lrelu(float v) { return v >= 0.f ? v : 0.2f * v; }

// ---- diagnostics (f32) ------------------------------------------------------
__global__ __launch_bounds__(256) void k_diag(float* out, int n, float v) {
  int i = blockIdx.x * 256 + threadIdx.x;
  if (i < n) out[i] = v;
}

// ---- feats (B,C,N) f32 -> X (B,N,C) f32 ------------------------------------
__global__ __launch_bounds__(256) void k_cvt(const float* __restrict__ f,
                                             float* __restrict__ X) {
  int idx = blockIdx.x * 256 + threadIdx.x;   // (b*2048 + n)*256 + c
  int b = idx >> 19;
  int n = (idx >> 8) & (NPV - 1);
  int c = idx & (CCH - 1);
  X[idx] = f[((i64)b * CCH + c) * NPV + n];
}

// ---- X (B,N,C) f32 -> out (B,C,N) f32 --------------------------------------
__global__ __launch_bounds__(256) void k_final(const float* __restrict__ X,
                                               float* __restrict__ out) {
  int idx = blockIdx.x * 256 + threadIdx.x;   // (b*256 + c)*2048 + n
  int b = idx >> 19;
  int c = (idx >> 11) & (CCH - 1);
  int n = idx & (NPV - 1);
  out[idx] = X[((i64)b * NPV + n) * CCH + c];
}

// ---- knn: 17 watermarked argmin passes (stable (d,m) order), drop rank 0 ---
__global__ __launch_bounds__(256) void k_knn(const float* __restrict__ coords,
                                             int* __restrict__ knn) {
#pragma clang fp contract(off)   // match np mul-then-add distance arithmetic
  __shared__ float cx[NPV], cy[NPV], cz[NPV], sq[NPV];
  int b = blockIdx.y;
  const float* cb = coords + (i64)b * 3 * NPV;
  for (int m = threadIdx.x; m < NPV; m += 256) {
    float x = cb[m], y = cb[NPV + m], z = cb[2 * NPV + m];
    cx[m] = x; cy[m] = y; cz[m] = z;
    sq[m] = x * x + y * y + z * z;
  }
  __syncthreads();
  int n = blockIdx.x * 256 + threadIdx.x;
  float xn = cx[n], yn = cy[n], zn = cz[n], sn = sq[n];
  float wd = -3.4e38f; int wm = -1;
  int* o = knn + ((i64)b * NPV + n) * KNB;
  for (int r = 0; r < KNB + 1; r++) {
    float bestd = 3.4e38f; int bestm = -1;
    for (int m = 0; m < NPV; m++) {
      float dot = xn * cx[m] + yn * cy[m] + zn * cz[m];
      float d = (sn + sq[m]) - 2.0f * dot;
      bool gt = (d > wd) || (d == wd && m > wm);
      if (gt && d < bestd) { bestd = d; bestm = m; }
    }
    if (r > 0) o[r - 1] = bestm & (NPV - 1);
    wd = bestd; wm = bestm;
  }
}

// ---- tiled f32 GEMM: C[M,N] = scale * A[M,K] @ W[N,K]^T (+bias / +=) -------
// grid: (M/64, N/64, nb*kchunks). mode 0: write (+bias); mode 1: C += .
// kchunks>1: K split over z, each slice written to C + kc*sKC (mode 0).
__global__ __launch_bounds__(256) void k_gemm(
    const float* __restrict__ A, int lda, i64 sA,
    const float* __restrict__ W, int ldw,
    const float* __restrict__ bias,
    float* __restrict__ C, int ldc, i64 sC, i64 sKC,
    int K, int kchunks, float scale, int mode) {
  __shared__ float As[16][68], Ws[16][68];
  int bz = blockIdx.z;
  int b = bz / kchunks, kc = bz - b * kchunks;
  A += (i64)b * sA;
  C += (i64)b * sC + (i64)kc * sKC;
  int m0 = blockIdx.x * 64, n0 = blockIdx.y * 64;
  int tid = threadIdx.x;
  int tx = tid & 15, ty = tid >> 4;
  int lr = tid >> 2, lk = (tid & 3) * 4;
  int kPer = K / kchunks;
  const float* Ap = A + (i64)(m0 + lr) * lda + kc * kPer + lk;
  const float* Wp = W + (i64)(n0 + lr) * ldw + kc * kPer + lk;
  float4 av = *(const float4*)Ap;
  float4 wv = *(const float4*)Wp;
  float acc[4][4] = {};
  for (int kt = 0; kt < kPer; kt += 16) {
    __syncthreads();
    As[lk + 0][lr] = av.x; As[lk + 1][lr] = av.y;
    As[lk + 2][lr] = av.z; As[lk + 3][lr] = av.w;
    Ws[lk + 0][lr] = wv.x; Ws[lk + 1][lr] = wv.y;
    Ws[lk + 2][lr] = wv.z; Ws[lk + 3][lr] = wv.w;
    __syncthreads();
    if (kt + 16 < kPer) {
      av = *(const float4*)(Ap + kt + 16);
      wv = *(const float4*)(Wp + kt + 16);
    }
#pragma unroll
    for (int k = 0; k < 16; k++) {
      float4 a = *(const float4*)&As[k][ty * 4];
      float4 w = *(const float4*)&Ws[k][tx * 4];
      acc[0][0] += a.x * w.x; acc[0][1] += a.x * w.y;
      acc[0][2] += a.x * w.z; acc[0][3] += a.x * w.w;
      acc[1][0] += a.y * w.x; acc[1][1] += a.y * w.y;
      acc[1][2] += a.y * w.z; acc[1][3] += a.y * w.w;
      acc[2][0] += a.z * w.x; acc[2][1] += a.z * w.y;
      acc[2][2] += a.z * w.z; acc[2][3] += a.z * w.w;
      acc[3][0] += a.w * w.x; acc[3][1] += a.w * w.y;
      acc[3][2] += a.w * w.z; acc[3][3] += a.w * w.w;
    }
  }
  int col = n0 + tx * 4;
  float4 bv = make_float4(0.f, 0.f, 0.f, 0.f);
  if (mode == 0 && bias) bv = *(const float4*)&bias[col];
#pragma unroll
  for (int i = 0; i < 4; i++) {
    float* cp = &C[(i64)(m0 + ty * 4 + i) * ldc + col];
    float4 r;
    r.x = acc[i][0] * scale; r.y = acc[i][1] * scale;
    r.z = acc[i][2] * scale; r.w = acc[i][3] * scale;
    if (mode == 0) {
      r.x += bv.x; r.y += bv.y; r.z += bv.z; r.w += bv.w;
    } else {
      float4 old = *(const float4*)cp;
      r.x += old.x; r.y += old.y; r.z += old.z; r.w += old.w;
    }
    *(float4*)cp = r;
  }
}

// ---- weight split: U = Wc - Wn, V = Wn (Wc = cols 0:256, Wn = 256:512) -----
__global__ __launch_bounds__(256) void k_wsplit(const float* __restrict__ W,
                                                float* __restrict__ U,
                                                float* __restrict__ V) {
  int i = blockIdx.x * 256 + threadIdx.x;
  int o = i >> 8, c = i & 255;
  float wc = W[(i64)o * 512 + c], wn = W[(i64)o * 512 + 256 + c];
  U[i] = wc - wn;
  V[i] = wn;
}

// ---- fused gather: RM[n,o] = P[n,o] + max_k Q[j,o]; partial inorm stats ----
// grid: (O/256, 64, B), 32 rows per block.
__global__ __launch_bounds__(256) void k_gstat(const float* __restrict__ P,
                                               const float* __restrict__ Q,
                                               const int* __restrict__ knn,
                                               int O, float* __restrict__ RM,
                                               float* __restrict__ part) {
  int b = blockIdx.z;
  int o = blockIdx.x * 256 + threadIdx.x;
  int n0 = blockIdx.y * 32;
  P += (i64)b * 2048 * O; Q += (i64)b * 2048 * O; RM += (i64)b * 2048 * O;
  knn += ((i64)b * 2048 + n0) * KNB;
  __shared__ int js[32 * KNB];
  for (int i = threadIdx.x; i < 32 * KNB; i += 256) js[i] = knn[i];
  __syncthreads();
  float s = 0.f, ss = 0.f;
  for (int r = 0; r < 32; r++) {
    int n = n0 + r;
    float p = P[(i64)n * O + o];
    float qm = -3.4e38f, qs = 0.f, qss = 0.f;
#pragma unroll
    for (int k = 0; k < KNB; k++) {
      float q = Q[(i64)js[r * KNB + k] * O + o];
      qm = fmaxf(qm, q); qs += q; qss += q * q;
    }
    RM[(i64)n * O + o] = p + qm;
    s  += 16.f * p + qs;
    ss += 16.f * p * p + 2.f * p * qs + qss;
  }
  i64 slot = ((i64)b * 64 + blockIdx.y) * O + o;
  part[slot * 2] = s; part[slot * 2 + 1] = ss;
}

// ---- partial inorm stats over row chunks -----------------------------------
// grid: (cols/256, nch, B)
__global__ __launch_bounds__(256) void k_part2(const float* __restrict__ Y,
                                               int cols, int rps, int nch,
                                               float* __restrict__ part) {
  int b = blockIdx.z;
  int c = blockIdx.x * 256 + threadIdx.x;
  int r0 = blockIdx.y * rps;
  const float* Yb = Y + (i64)b * 2048 * cols;
  float s = 0.f, ss = 0.f;
  for (int r = r0; r < r0 + rps; r++) {
    float v = Yb[(i64)r * cols + c];
    s += v; ss += v * v;
  }
  i64 slot = ((i64)b * nch + blockIdx.y) * cols + c;
  part[slot * 2] = s; part[slot * 2 + 1] = ss;
}

// ---- finalize mean/rstd; grid: (cols/256, 1, B) -----------------------------
__global__ __launch_bounds__(256) void k_fin2(const float* __restrict__ part,
                                              int cols, int nch, float inv,
                                              float* __restrict__ mean,
                                              float* __restrict__ rstd) {
  int b = blockIdx.z;
  int c = blockIdx.x * 256 + threadIdx.x;
  const float* pb = part + (i64)b * nch * cols * 2;
  float s = 0.f, ss = 0.f;
  for (int h = 0; h < nch; h++) {
    s  += pb[((i64)h * cols + c) * 2];
    ss += pb[((i64)h * cols + c) * 2 + 1];
  }
  float mu = s * inv;
  float var = ss * inv - mu * mu;
  mean[(i64)b * cols + c] = mu;
  rstd[(i64)b * cols + c] = 1.0f / sqrtf(var + 1e-5f);
}

// ---- normalize + activation (1=lrelu, 2=relu); grid (2048, cols/256, B) ----
__global__ __launch_bounds__(256) void k_norm2(const float* __restrict__ src,
                                               float* __restrict__ dst, int cols,
                                               const float* __restrict__ mean,
                                               const float* __restrict__ rstd,
                                               int act) {
  int b = blockIdx.z;
  i64 n = blockIdx.x;
  int c = blockIdx.y * 256 + threadIdx.x;
  i64 off = ((i64)b * 2048 + n) * cols + c;
  float v = (src[off] - mean[(i64)b * cols + c]) * rstd[(i64)b * cols + c];
  dst[off] = (act == 1) ? lrelu(v) : fmaxf(v, 0.f);
}

// ---- softmax over rows of length 2048 ---------------------------------------
__global__ __launch_bounds__(256) void k_softmax(float* __restrict__ S) {
  i64 row = blockIdx.x;
  float* s = S + row * (i64)NPV;
  int t = threadIdx.x;
  float v[8];
  float mx = -3.4e38f;
#pragma unroll
  for (int i = 0; i < 8; i++) { v[i] = s[t + 256 * i]; mx = fmaxf(mx, v[i]); }
  __shared__ float red[256];
  red[t] = mx; __syncthreads();
  for (int off = 128; off > 0; off >>= 1) {
    if (t < off) red[t] = fmaxf(red[t], red[t + off]);
    __syncthreads();
  }
  mx = red[0]; __syncthreads();
  float sum = 0.f;
#pragma unroll
  for (int i = 0; i < 8; i++) { v[i] = expf(v[i] - mx); sum += v[i]; }
  red[t] = sum; __syncthreads();
  for (int off = 128; off > 0; off >>= 1) {
    if (t < off) red[t] += red[t + off];
    __syncthreads();
  }
  float inv = 1.0f / red[0];
#pragma unroll
  for (int i = 0; i < 8; i++) s[t + 256 * i] = v[i] * inv;
}

// ---- head repack: D[b][h][n][d] = S[b][n][4d+h]; grid (2048,1,B) -----------
__global__ __launch_bounds__(256) void k_headify(const float* __restrict__ Sp,
                                                 float* __restrict__ D) {
  int b = blockIdx.z, n = blockIdx.x, c = threadIdx.x;
  int h = c & 3, d = c >> 2;
  D[(((i64)b * 4 + h) * 2048 + n) * 64 + d] = Sp[((i64)b * 2048 + n) * 256 + c];
}

// ---- V transpose: Vt[b][h][d][m] = Vp[b][m][4d+h]; grid (32, 4, B) ---------
__global__ __launch_bounds__(256) void k_vtrans(const float* __restrict__ Vp,
                                                float* __restrict__ Vt) {
  __shared__ float t[64][65];
  int b = blockIdx.z;
  int m0 = blockIdx.x * 64, c0 = blockIdx.y * 64;
  int tid = threadIdx.x;
  int mr = tid >> 2, cq = (tid & 3) * 16;
  const float* src = &Vp[((i64)b * 2048 + m0 + mr) * 256 + c0 + cq];
#pragma unroll
  for (int i = 0; i < 16; i += 4) {
    float4 v = *(const float4*)(src + i);
    t[mr][cq + i + 0] = v.x; t[mr][cq + i + 1] = v.y;
    t[mr][cq + i + 2] = v.z; t[mr][cq + i + 3] = v.w;
  }
  __syncthreads();
  int cc = tid >> 2, mq = (tid & 3) * 16;
  int c = c0 + cc, h = c & 3, d = c >> 2;
  float* dst = &Vt[(((i64)b * 4 + h) * 64 + d) * 2048 + m0 + mq];
#pragma unroll
  for (int i = 0; i < 16; i += 4) {
    float4 v = make_float4(t[mq + i][cc], t[mq + i + 1][cc],
                           t[mq + i + 2][cc], t[mq + i + 3][cc]);
    *(float4*)(dst + i) = v;
  }
}

// ---- reduce 4 split-K slices + interleave head channel ----------------------
// Ocat[n][4d+h] = sum_kc Op8[kc][n*64+d]; grid (512)
__global__ __launch_bounds__(256) void k_redocat(const float* __restrict__ Op8,
                                                 float* __restrict__ OcatB, int h) {
  int i = blockIdx.x * 256 + threadIdx.x;   // over 2048*64
  int n = i >> 6, d = i & 63;
  float s = Op8[i] + Op8[131072 + i] + Op8[262144 + i] + Op8[393216 + i];
  OcatB[(i64)n * 256 + 4 * d + h] = s;
}

// ---- copy XA into Ccat cols 0:256; grid (2048,1,B) --------------------------
__global__ __launch_bounds__(256) void k_cpy2(const float* __restrict__ XA,
                                              float* __restrict__ Ccat) {
  int b = blockIdx.z;
  i64 n = blockIdx.x; int c = threadIdx.x;
  Ccat[((i64)b * 2048 + n) * 512 + c] = XA[((i64)b * 2048 + n) * 256 + c];
}

}  // namespace

// ============================================================================
extern "C" void kernel_launch(void* const* d_in, const int* in_sizes, int n_in,
                              void* d_out, int out_size, void* d_ws, size_t ws_size,
                              hipStream_t stream) {
  float* outp = (float*)d_out;
  auto diag = [&](float v) {
    k_diag<<<dim3((out_size + 255) / 256), dim3(256), 0, stream>>>(outp, out_size, v);
  };

  // -------- assumption guards (verified in rounds 8-11) ---------------------
  static const int DSZ[19] = {12288, 1048576, 12288, 1048576, 262144, 524288, 524288,
                              131072, 512, 131072, 512, 131072, 512, 131072, 512,
                              524288, 1024, 262144, 512};
  if (n_in != 19) { diag(1000.f + (float)n_in); return; }
  for (int i = 0; i < 19; i++) {
    if (in_sizes[i] != DSZ[i]) { diag(2000.f + (float)i); return; }
  }
  if (out_size != 2097152) { diag(3000.f); return; }
  constexpr size_t NEED = 50331648;  // 48 MiB (verified present)
  if (ws_size < NEED) { diag((float)(ws_size >> 20)); return; }

  // -------- workspace map (bytes) --------------------------------------------
  char* w = (char*)d_ws;
  float* SL0 = (float*)(w + 0);               // f32 slots (B,N,C), 4 MB each
  float* SL1 = (float*)(w + 4 * MB);
  float* SL2 = (float*)(w + 8 * MB);
  int*   KN1 = (int*)(w + 12 * MB);           // 256 KB
  int*   KN2 = (int*)(w + 12 * MB + 262144);  // 256 KB
  float* MEAN = (float*)(w + 12 * MB + 524288);          // [B][512]
  float* RSTD = (float*)(w + 12 * MB + 524288 + 4096);   // [B][512]
  float* PART = (float*)(w + 12 * MB + 524288 + 8192);   // [B][64][512][2] = 512 KB
  char* AR = w + 14 * MB;                     // 34 MB arena

  // gcn overlay
  float* P1 = (float*)(AR);                   // [B][2048][256] 4 MB
  float* Q1 = (float*)(AR + 4 * MB);          // 4 MB
  float* F1 = (float*)(AR + 8 * MB);          // 4 MB (RM1 then normed F1)
  float* P2 = (float*)(AR);                   // [B][2048][512] 8 MB (over P1,Q1)
  float* Q2 = (float*)(AR + 12 * MB);         // 8 MB
  float* F2 = (float*)(AR + 20 * MB);         // 8 MB (RM2 then normed F2)
  float* Y3 = (float*)(AR + 12 * MB);         // 4 MB (over Q2 after dead)
  float* U1 = (float*)(AR + 28 * MB);                 // 256 KB
  float* V1 = (float*)(AR + 28 * MB + 262144);        // 256 KB
  float* U2 = (float*)(AR + 28 * MB + 524288);        // 512 KB
  float* V2 = (float*)(AR + 28 * MB + 1048576);       // 512 KB
  // attention overlay
  float* Qp = (float*)(AR);                   // 4 MB
  float* Kp = (float*)(AR + 4 * MB);          // 4 MB
  float* Vp = (float*)(AR + 8 * MB);          // 4 MB
  float* Qh = (float*)(AR + 16 * MB);         // [B][4][2048][64] 4 MB
  float* Kh = (float*)(AR + 20 * MB);         // 4 MB
  float* Vt = (float*)(AR + 24 * MB);         // [B][4][64][2048] 4 MB
  float* Sf = (float*)(AR);                   // 16 MB (after repack)
  float* Ocat = (float*)(AR + 28 * MB);       // [B][2048][256] 4 MB
  float* Op8 = (float*)(AR + 32 * MB);        // [4][2048][64] 2 MB
  float* Ccat = (float*)(AR + 16 * MB);       // [B][2048][512] 8 MB (after QK)
  float* Hh = (float*)(AR);                   // 8 MB (after PV)

  const float* W1b = (const float*)d_in[4];
  const float* W2b = (const float*)d_in[5];
  const float* W3b = (const float*)d_in[6];
  const float* Wqb = (const float*)d_in[7];   const float* bqb = (const float*)d_in[8];
  const float* Wkb = (const float*)d_in[9];   const float* bkb = (const float*)d_in[10];
  const float* Wvb = (const float*)d_in[11];  const float* bvb = (const float*)d_in[12];
  const float* Wob = (const float*)d_in[13];  const float* bob = (const float*)d_in[14];
  const float* Wm1b = (const float*)d_in[15]; const float* bm1b = (const float*)d_in[16];
  const float* Wm2b = (const float*)d_in[17]; const float* bm2b = (const float*)d_in[18];

  auto gemm = [&](const float* A, int lda, i64 sA, const float* W, int ldw,
                  const float* bias, float* C, int ldc, i64 sC, i64 sKC,
                  int M, int N, int K, int nb, int kchunks, float scale, int mode) {
    k_gemm<<<dim3(M / 64, N / 64, nb * kchunks), dim3(256), 0, stream>>>(
        A, lda, sA, W, ldw, bias, C, ldc, sC, sKC, K, kchunks, scale, mode);
  };

  // -------- setup --------
  k_cvt<<<dim3(4096), dim3(256), 0, stream>>>((const float*)d_in[1], SL0);
  k_cvt<<<dim3(4096), dim3(256), 0, stream>>>((const float*)d_in[3], SL1);
  k_knn<<<dim3(NPV / 256, BB), dim3(256), 0, stream>>>((const float*)d_in[0], KN1);
  k_knn<<<dim3(NPV / 256, BB), dim3(256), 0, stream>>>((const float*)d_in[2], KN2);

  // -------- gcn layer (both batches in one set of launches) --------
  auto gcn = [&](const float* Xc, float* Xn, const int* knnb, int li) {
    const float* W1 = W1b + (i64)li * 131072;   // (256,512)
    const float* W2 = W2b + (i64)li * 262144;   // (512,512)
    const float* W3 = W3b + (i64)li * 262144;   // (256,1024)
    k_wsplit<<<dim3(256), dim3(256), 0, stream>>>(W1, U1, V1);
    k_wsplit<<<dim3(512), dim3(256), 0, stream>>>(W2, U2, V2);
    // hop 1: P1 = X@U1^T, Q1 = X@V1^T; RM1 = P1 + max_k gather(Q1); stats
    gemm(Xc, 256, NSTR, U1, 256, nullptr, P1, 256, NSTR, 0, 2048, 256, 256, 2, 1, 1.f, 0);
    gemm(Xc, 256, NSTR, V1, 256, nullptr, Q1, 256, NSTR, 0, 2048, 256, 256, 2, 1, 1.f, 0);
    k_gstat<<<dim3(1, 64, BB), dim3(256), 0, stream>>>(P1, Q1, knnb, 256, F1, PART);
    k_fin2<<<dim3(1, 1, BB), dim3(256), 0, stream>>>(PART, 256, 64, 1.f / 32768.f, MEAN, RSTD);
    k_norm2<<<dim3(2048, 1, BB), dim3(256), 0, stream>>>(F1, F1, 256, MEAN, RSTD, 1);
    // hop 2
    gemm(F1, 256, NSTR, U2, 256, nullptr, P2, 512, NSTR2, 0, 2048, 512, 256, 2, 1, 1.f, 0);
    gemm(F1, 256, NSTR, V2, 256, nullptr, Q2, 512, NSTR2, 0, 2048, 512, 256, 2, 1, 1.f, 0);
    k_gstat<<<dim3(2, 64, BB), dim3(256), 0, stream>>>(P2, Q2, knnb, 512, F2, PART);
    k_fin2<<<dim3(2, 1, BB), dim3(256), 0, stream>>>(PART, 512, 64, 1.f / 32768.f, MEAN, RSTD);
    k_norm2<<<dim3(2048, 2, BB), dim3(256), 0, stream>>>(F2, F2, 512, MEAN, RSTD, 1);
    // out: Y3 = [X|F1|F2] @ W3^T  (3 accumulating sub-GEMMs, no concat)
    gemm(Xc, 256, NSTR, W3,       1024, nullptr, Y3, 256, NSTR, 0, 2048, 256, 256, 2, 1, 1.f, 0);
    gemm(F1, 256, NSTR, W3 + 256, 1024, nullptr, Y3, 256, NSTR, 0, 2048, 256, 256, 2, 1, 1.f, 1);
    gemm(F2, 512, NSTR2, W3 + 512, 1024, nullptr, Y3, 256, NSTR, 0, 2048, 256, 512, 2, 1, 1.f, 1);
    k_part2<<<dim3(1, 8, BB), dim3(256), 0, stream>>>(Y3, 256, 256, 8, PART);
    k_fin2<<<dim3(1, 1, BB), dim3(256), 0, stream>>>(PART, 256, 8, 1.f / 2048.f, MEAN, RSTD);
    k_norm2<<<dim3(2048, 1, BB), dim3(256), 0, stream>>>(Y3, Xn, 256, MEAN, RSTD, 1);
  };

  // -------- cross attention --------
  auto attn = [&](const float* XA, const float* XB, float* XO, int li) {
    const float* Wq = Wqb + (i64)li * 65536;   const float* bq = bqb + (i64)li * 256;
    const float* Wk = Wkb + (i64)li * 65536;   const float* bk = bkb + (i64)li * 256;
    const float* Wv = Wvb + (i64)li * 65536;   const float* bv = bvb + (i64)li * 256;
    const float* Wo = Wob + (i64)li * 65536;   const float* bo = bob + (i64)li * 256;
    const float* Wm1 = Wm1b + (i64)li * 262144; const float* bm1 = bm1b + (i64)li * 512;
    const float* Wm2 = Wm2b + (i64)li * 131072; const float* bm2 = bm2b + (i64)li * 256;
    gemm(XA, 256, NSTR, Wq, 256, bq, Qp, 256, NSTR, 0, 2048, 256, 256, 2, 1, 1.f, 0);
    gemm(XB, 256, NSTR, Wk, 256, bk, Kp, 256, NSTR, 0, 2048, 256, 256, 2, 1, 1.f, 0);
    gemm(XB, 256, NSTR, Wv, 256, bv, Vp, 256, NSTR, 0, 2048, 256, 256, 2, 1, 1.f, 0);
    k_headify<<<dim3(2048, 1, BB), dim3(256), 0, stream>>>(Qp, Qh);
    k_headify<<<dim3(2048, 1, BB), dim3(256), 0, stream>>>(Kp, Kh);
    k_vtrans<<<dim3(32, 4, BB), dim3(256), 0, stream>>>(Vp, Vt);
    for (int b = 0; b < BB; b++) {
      for (int h = 0; h < 4; h++) {
        const float* qh = Qh + ((i64)b * 4 + h) * NPV * 64;
        const float* kh = Kh + ((i64)b * 4 + h) * NPV * 64;
        const float* vt = Vt + ((i64)b * 4 + h) * 64 * NPV;
        gemm(qh, 64, 0, kh, 64, nullptr, Sf, 2048, 0, 0, 2048, 2048, 64, 1, 1, 0.125f, 0);
        k_softmax<<<dim3(2048), dim3(256), 0, stream>>>(Sf);
        gemm(Sf, 2048, 0, vt, 2048, nullptr, Op8, 64, 0, (i64)NPV * 64,
             2048, 64, 2048, 1, 4, 1.f, 0);
        k_redocat<<<dim3(512), dim3(256), 0, stream>>>(Op8, Ocat + (i64)b * NSTR, h);
      }
    }
    gemm(Ocat, 256, NSTR, Wo, 256, bo, Ccat + 256, 512, NSTR2, 0, 2048, 256, 256, 2, 1, 1.f, 0);
    k_cpy2<<<dim3(2048, 1, BB), dim3(256), 0, stream>>>(XA, Ccat);
    gemm(Ccat, 512, NSTR2, Wm1, 512, bm1, Hh, 512, NSTR2, 0, 2048, 512, 512, 2, 1, 1.f, 0);
    k_part2<<<dim3(2, 8, BB), dim3(256), 0, stream>>>(Hh, 512, 256, 8, PART);
    k_fin2<<<dim3(2, 1, BB), dim3(256), 0, stream>>>(PART, 512, 8, 1.f / 2048.f, MEAN, RSTD);
    k_norm2<<<dim3(2048, 2, BB), dim3(256), 0, stream>>>(Hh, Hh, 512, MEAN, RSTD, 2);
    gemm(Hh, 512, NSTR2, Wm2, 512, bm2, XO, 256, NSTR, 0, 2048, 256, 512, 2, 1, 1.f, 0);
  };

  // -------- 4 layers, explicit hard-coded schedule --------
  gcn(SL0, SL2, KN1, 0);        // f1.a -> SL2
  gcn(SL1, SL0, KN2, 0);        // f2.a -> SL0   (SL1 free)
  attn(SL2, SL0, SL1, 0);       // f1.b = CA(f1.a, f2.a) -> SL1
  attn(SL0, SL1, SL2, 0);       // f2.b = CA(f2.a, f1.b) -> SL2
  gcn(SL1, SL0, KN1, 1);        // f1.c -> SL0
  gcn(SL2, SL1, KN2, 1);        // f2.c -> SL1
  attn(SL0, SL1, SL2, 1);       // f1.d = CA(f1.c, f2.c) -> SL2
  attn(SL1, SL2, SL0, 1);       // f2.d = CA(f2.c, f1.d) -> SL0
  // outputs: feats1 = SL2, feats2 = SL0

  k_final<<<dim3(4096), dim3(256), 0, stream>>>(SL2, outp);
  k_final<<<dim3(4096), dim3(256), 0, stream>>>(SL0, outp + (i64)BB * CCH * NPV);
}

// Round 2
// 12052.694 us; speedup vs baseline: 8.1051x; 1.0084x over previous
//
#include <hip/hip_runtime.h>

// ============================================================================
// InformationInteractive (gcn, cross_attn, gcn, cross_attn).
// Round 13: all GEMMs -> bf16 MFMA (v_mfma_f32_16x16x32_bf16) with
// SPLIT-PRECISION operands: x = hi(bf16) + lo(bf16), 3 MFMAs per K-slice
// (hi*hi + hi*lo + lo*hi), f32 accumulate -> ~2^-16 relative error, i.e.
// f32-equivalent for the 2%-of-max threshold. Conversion f32->hi/lo happens
// during LDS staging (global reads stay f32). Tiles 128x128 (128x64 for
// N=64), 4 waves, 64x64 wave-tile, padded LDS rows (80B) -> conflict-free.
// Fragment layouts per guide-verified mapping (m89/m91/m92).
// Rest of pipeline (knn, gather-stats, norms, softmax, repacks) unchanged
// from round 12 (12.15 ms, passed, absmax 0.0156).
// ============================================================================

namespace {

constexpr int BB = 2, NPV = 2048, CCH = 256, KNB = 16;
typedef long long i64;
typedef unsigned short u16;
constexpr i64 NSTR  = (i64)NPV * 256;   // 524288 floats
constexpr i64 NSTR2 = (i64)NPV * 512;   // 1048576 floats
constexpr i64 MB = 1048576;

typedef __attribute__((ext_vector_type(8))) short short8v;   // 8 bf16
typedef __attribute__((ext_vector_type(4))) float f32x4;

__device__ __forceinline__ float lrelu(float v) { return v >= 0.f ? v : 0.2f * v; }

// split f32 into hi/lo bf16 (truncation; x - hi exact in f32)
__device__ __forceinline__ void splitbf(float x, u16& h, u16& l) {
  unsigned u = __float_as_uint(x);
  h = (u16)(u >> 16);
  float hf = __uint_as_float(u & 0xffff0000u);
  l = (u16)(__float_as_uint(x - hf) >> 16);
}

// ---- diagnostics (f32) ------------------------------------------------------
__global__ __launch_bounds__(256) void k_diag(float* out, int n, float v) {
  int i = blockIdx.x * 256 + threadIdx.x;
  if (i < n) out[i] = v;
}

// ---- feats (B,C,N) f32 -> X (B,N,C) f32 ------------------------------------
__global__ __launch_bounds__(256) void k_cvt(const float* __restrict__ f,
                                             float* __restrict__ X) {
  int idx = blockIdx.x * 256 + threadIdx.x;   // (b*2048 + n)*256 + c
  int b = idx >> 19;
  int n = (idx >> 8) & (NPV - 1);
  int c = idx & (CCH - 1);
  X[idx] = f[((i64)b * CCH + c) * NPV + n];
}

// ---- X (B,N,C) f32 -> out (B,C,N) f32 --------------------------------------
__global__ __launch_bounds__(256) void k_final(const float* __restrict__ X,
                                               float* __restrict__ out) {
  int idx = blockIdx.x * 256 + threadIdx.x;   // (b*256 + c)*2048 + n
  int b = idx >> 19;
  int c = (idx >> 11) & (CCH - 1);
  int n = idx & (NPV - 1);
  out[idx] = X[((i64)b * NPV + n) * CCH + c];
}

// ---- knn: 17 watermarked argmin passes (stable (d,m) order), drop rank 0 ---
__global__ __launch_bounds__(256) void k_knn(const float* __restrict__ coords,
                                             int* __restrict__ knn) {
#pragma clang fp contract(off)   // match np mul-then-add distance arithmetic
  __shared__ float cx[NPV], cy[NPV], cz[NPV], sq[NPV];
  int b = blockIdx.y;
  const float* cb = coords + (i64)b * 3 * NPV;
  for (int m = threadIdx.x; m < NPV; m += 256) {
    float x = cb[m], y = cb[NPV + m], z = cb[2 * NPV + m];
    cx[m] = x; cy[m] = y; cz[m] = z;
    sq[m] = x * x + y * y + z * z;
  }
  __syncthreads();
  int n = blockIdx.x * 256 + threadIdx.x;
  float xn = cx[n], yn = cy[n], zn = cz[n], sn = sq[n];
  float wd = -3.4e38f; int wm = -1;
  int* o = knn + ((i64)b * NPV + n) * KNB;
  for (int r = 0; r < KNB + 1; r++) {
    float bestd = 3.4e38f; int bestm = -1;
    for (int m = 0; m < NPV; m++) {
      float dot = xn * cx[m] + yn * cy[m] + zn * cz[m];
      float d = (sn + sq[m]) - 2.0f * dot;
      bool gt = (d > wd) || (d == wd && m > wm);
      if (gt && d < bestd) { bestd = d; bestm = m; }
    }
    if (r > 0) o[r - 1] = bestm & (NPV - 1);
    wd = bestd; wm = bestm;
  }
}

// ---- MFMA split-precision GEMM: C[M,N] = scale*A[M,K]@W[N,K]^T (+bias/+=) --
// BM=128 fixed, BN in {64,128}. 256 threads = 4 waves (2x2), wave tile
// 64 x BN/2. grid: (M/128, N/BN, nb*kchunks). mode 0: write (+bias);
// mode 1: C +=. kchunks>1: K split over z, slice -> C + kc*sKC.
template <int BN>
__global__ __launch_bounds__(256) void k_gemm_mfma(
    const float* __restrict__ A, int lda, i64 sA,
    const float* __restrict__ W, int ldw,
    const float* __restrict__ bias,
    float* __restrict__ C, int ldc, i64 sC, i64 sKC,
    int K, int kchunks, float scale, int mode) {
  constexpr int HN = BN / 2;    // wave col extent
  constexpr int TN = BN / 32;   // 16-col frags per wave
  // padded rows: 32 data shorts + 8 pad = 40 shorts (80B) -> 2-way max
  __shared__ __align__(16) u16 Ah[128][40], Al[128][40];
  __shared__ __align__(16) u16 Bh[BN][40], Bl[BN][40];
  int bz = blockIdx.z;
  int b = bz / kchunks, kc = bz - b * kchunks;
  A += (i64)b * sA;
  C += (i64)b * sC + (i64)kc * sKC;
  int kPer = K / kchunks;
  int kbase = kc * kPer;
  int m0 = blockIdx.x * 128, n0 = blockIdx.y * BN;
  int tid = threadIdx.x;
  int w = tid >> 6, l = tid & 63;
  int wr = w >> 1, wc = w & 1;
  int lc = l & 15, lq = l >> 4;

  // staging: chunk = 16 consecutive k of one row
  int srow = tid >> 1, skh = (tid & 1) * 16;
  const float* Ap = A + (i64)(m0 + srow) * lda + kbase + skh;
  const float* Wp = W + (i64)(n0 + srow) * ldw + kbase + skh;
  bool doB = (tid < BN * 2);

  float4 ar[4], br[4];
#pragma unroll
  for (int j = 0; j < 4; j++) ar[j] = *(const float4*)(Ap + j * 4);
  if (doB) {
#pragma unroll
    for (int j = 0; j < 4; j++) br[j] = *(const float4*)(Wp + j * 4);
  }

  f32x4 acc[4][TN];
#pragma unroll
  for (int i = 0; i < 4; i++)
#pragma unroll
    for (int j = 0; j < TN; j++)
#pragma unroll
      for (int r = 0; r < 4; r++) acc[i][j][r] = 0.f;

  int koff = lq * 8;  // shorts
  for (int kt = 0; kt < kPer; kt += 32) {
    __syncthreads();   // previous iteration's LDS reads done
    // convert + store hi/lo tiles
#pragma unroll
    for (int j = 0; j < 4; j++) {
      u16 h0, h1, h2, h3, l0, l1, l2, l3;
      splitbf(ar[j].x, h0, l0); splitbf(ar[j].y, h1, l1);
      splitbf(ar[j].z, h2, l2); splitbf(ar[j].w, h3, l3);
      *(ushort4*)&Ah[srow][skh + j * 4] = make_ushort4(h0, h1, h2, h3);
      *(ushort4*)&Al[srow][skh + j * 4] = make_ushort4(l0, l1, l2, l3);
    }
    if (doB) {
#pragma unroll
      for (int j = 0; j < 4; j++) {
        u16 h0, h1, h2, h3, l0, l1, l2, l3;
        splitbf(br[j].x, h0, l0); splitbf(br[j].y, h1, l1);
        splitbf(br[j].z, h2, l2); splitbf(br[j].w, h3, l3);
        *(ushort4*)&Bh[srow][skh + j * 4] = make_ushort4(h0, h1, h2, h3);
        *(ushort4*)&Bl[srow][skh + j * 4] = make_ushort4(l0, l1, l2, l3);
      }
    }
    __syncthreads();
    if (kt + 32 < kPer) {   // prefetch next k-tile under MFMA
#pragma unroll
      for (int j = 0; j < 4; j++) ar[j] = *(const float4*)(Ap + kt + 32 + j * 4);
      if (doB) {
#pragma unroll
        for (int j = 0; j < 4; j++) br[j] = *(const float4*)(Wp + kt + 32 + j * 4);
      }
    }
    // fragment loads (A[M,K]/W[N,K] row-major, 8 contiguous k per lane)
    short8v ah[4], al4[4], bh[TN], bl4[TN];
#pragma unroll
    for (int i = 0; i < 4; i++) {
      int r = wr * 64 + i * 16 + lc;
      ah[i]  = *(const short8v*)&Ah[r][koff];
      al4[i] = *(const short8v*)&Al[r][koff];
    }
#pragma unroll
    for (int j = 0; j < TN; j++) {
      int r = wc * HN + j * 16 + lc;
      bh[j]  = *(const short8v*)&Bh[r][koff];
      bl4[j] = *(const short8v*)&Bl[r][koff];
    }
#pragma unroll
    for (int i = 0; i < 4; i++) {
#pragma unroll
      for (int j = 0; j < TN; j++) {
        acc[i][j] = __builtin_amdgcn_mfma_f32_16x16x32_bf16(ah[i], bh[j], acc[i][j], 0, 0, 0);
        acc[i][j] = __builtin_amdgcn_mfma_f32_16x16x32_bf16(al4[i], bh[j], acc[i][j], 0, 0, 0);
        acc[i][j] = __builtin_amdgcn_mfma_f32_16x16x32_bf16(ah[i], bl4[j], acc[i][j], 0, 0, 0);
      }
    }
  }

  // epilogue: D col = lane&15, rows (lane>>4)*4 + r
#pragma unroll
  for (int j = 0; j < TN; j++) {
    int col = n0 + wc * HN + j * 16 + lc;
    float bv = (mode == 0 && bias) ? bias[col] : 0.f;
#pragma unroll
    for (int i = 0; i < 4; i++) {
      int rbase = m0 + wr * 64 + i * 16 + lq * 4;
#pragma unroll
      for (int r = 0; r < 4; r++) {
        float* cp = &C[(i64)(rbase + r) * ldc + col];
        float v = acc[i][j][r] * scale;
        v += (mode == 0) ? bv : *cp;
        *cp = v;
      }
    }
  }
}

// ---- weight split: U = Wc - Wn, V = Wn (Wc = cols 0:256, Wn = 256:512) -----
__global__ __launch_bounds__(256) void k_wsplit(const float* __restrict__ W,
                                                float* __restrict__ U,
                                                float* __restrict__ V) {
  int i = blockIdx.x * 256 + threadIdx.x;
  int o = i >> 8, c = i & 255;
  float wc = W[(i64)o * 512 + c], wn = W[(i64)o * 512 + 256 + c];
  U[i] = wc - wn;
  V[i] = wn;
}

// ---- fused gather: RM[n,o] = P[n,o] + max_k Q[j,o]; partial inorm stats ----
// grid: (O/256, 64, B), 32 rows per block.
__global__ __launch_bounds__(256) void k_gstat(const float* __restrict__ P,
                                               const float* __restrict__ Q,
                                               const int* __restrict__ knn,
                                               int O, float* __restrict__ RM,
                                               float* __restrict__ part) {
  int b = blockIdx.z;
  int o = blockIdx.x * 256 + threadIdx.x;
  int n0 = blockIdx.y * 32;
  P += (i64)b * 2048 * O; Q += (i64)b * 2048 * O; RM += (i64)b * 2048 * O;
  knn += ((i64)b * 2048 + n0) * KNB;
  __shared__ int js[32 * KNB];
  for (int i = threadIdx.x; i < 32 * KNB; i += 256) js[i] = knn[i];
  __syncthreads();
  float s = 0.f, ss = 0.f;
  for (int r = 0; r < 32; r++) {
    int n = n0 + r;
    float p = P[(i64)n * O + o];
    float qm = -3.4e38f, qs = 0.f, qss = 0.f;
#pragma unroll
    for (int k = 0; k < KNB; k++) {
      float q = Q[(i64)js[r * KNB + k] * O + o];
      qm = fmaxf(qm, q); qs += q; qss += q * q;
    }
    RM[(i64)n * O + o] = p + qm;
    s  += 16.f * p + qs;
    ss += 16.f * p * p + 2.f * p * qs + qss;
  }
  i64 slot = ((i64)b * 64 + blockIdx.y) * O + o;
  part[slot * 2] = s; part[slot * 2 + 1] = ss;
}

// ---- partial inorm stats over row chunks -----------------------------------
// grid: (cols/256, nch, B)
__global__ __launch_bounds__(256) void k_part2(const float* __restrict__ Y,
                                               int cols, int rps, int nch,
                                               float* __restrict__ part) {
  int b = blockIdx.z;
  int c = blockIdx.x * 256 + threadIdx.x;
  int r0 = blockIdx.y * rps;
  const float* Yb = Y + (i64)b * 2048 * cols;
  float s = 0.f, ss = 0.f;
  for (int r = r0; r < r0 + rps; r++) {
    float v = Yb[(i64)r * cols + c];
    s += v; ss += v * v;
  }
  i64 slot = ((i64)b * nch + blockIdx.y) * cols + c;
  part[slot * 2] = s; part[slot * 2 + 1] = ss;
}

// ---- finalize mean/rstd; grid: (cols/256, 1, B) -----------------------------
__global__ __launch_bounds__(256) void k_fin2(const float* __restrict__ part,
                                              int cols, int nch, float inv,
                                              float* __restrict__ mean,
                                              float* __restrict__ rstd) {
  int b = blockIdx.z;
  int c = blockIdx.x * 256 + threadIdx.x;
  const float* pb = part + (i64)b * nch * cols * 2;
  float s = 0.f, ss = 0.f;
  for (int h = 0; h < nch; h++) {
    s  += pb[((i64)h * cols + c) * 2];
    ss += pb[((i64)h * cols + c) * 2 + 1];
  }
  float mu = s * inv;
  float var = ss * inv - mu * mu;
  mean[(i64)b * cols + c] = mu;
  rstd[(i64)b * cols + c] = 1.0f / sqrtf(var + 1e-5f);
}

// ---- normalize + activation (1=lrelu, 2=relu); grid (2048, cols/256, B) ----
__global__ __launch_bounds__(256) void k_norm2(const float* __restrict__ src,
                                               float* __restrict__ dst, int cols,
                                               const float* __restrict__ mean,
                                               const float* __restrict__ rstd,
                                               int act) {
  int b = blockIdx.z;
  i64 n = blockIdx.x;
  int c = blockIdx.y * 256 + threadIdx.x;
  i64 off = ((i64)b * 2048 + n) * cols + c;
  float v = (src[off] - mean[(i64)b * cols + c]) * rstd[(i64)b * cols + c];
  dst[off] = (act == 1) ? lrelu(v) : fmaxf(v, 0.f);
}

// ---- softmax over rows of length 2048 ---------------------------------------
__global__ __launch_bounds__(256) void k_softmax(float* __restrict__ S) {
  i64 row = blockIdx.x;
  float* s = S + row * (i64)NPV;
  int t = threadIdx.x;
  float v[8];
  float mx = -3.4e38f;
#pragma unroll
  for (int i = 0; i < 8; i++) { v[i] = s[t + 256 * i]; mx = fmaxf(mx, v[i]); }
  __shared__ float red[256];
  red[t] = mx; __syncthreads();
  for (int off = 128; off > 0; off >>= 1) {
    if (t < off) red[t] = fmaxf(red[t], red[t + off]);
    __syncthreads();
  }
  mx = red[0]; __syncthreads();
  float sum = 0.f;
#pragma unroll
  for (int i = 0; i < 8; i++) { v[i] = expf(v[i] - mx); sum += v[i]; }
  red[t] = sum; __syncthreads();
  for (int off = 128; off > 0; off >>= 1) {
    if (t < off) red[t] += red[t + off];
    __syncthreads();
  }
  float inv = 1.0f / red[0];
#pragma unroll
  for (int i = 0; i < 8; i++) s[t + 256 * i] = v[i] * inv;
}

// ---- head repack: D[b][h][n][d] = S[b][n][4d+h]; grid (2048,1,B) -----------
__global__ __launch_bounds__(256) void k_headify(const float* __restrict__ Sp,
                                                 float* __restrict__ D) {
  int b = blockIdx.z, n = blockIdx.x, c = threadIdx.x;
  int h = c & 3, d = c >> 2;
  D[(((i64)b * 4 + h) * 2048 + n) * 64 + d] = Sp[((i64)b * 2048 + n) * 256 + c];
}

// ---- V transpose: Vt[b][h][d][m] = Vp[b][m][4d+h]; grid (32, 4, B) ---------
__global__ __launch_bounds__(256) void k_vtrans(const float* __restrict__ Vp,
                                                float* __restrict__ Vt) {
  __shared__ float t[64][65];
  int b = blockIdx.z;
  int m0 = blockIdx.x * 64, c0 = blockIdx.y * 64;
  int tid = threadIdx.x;
  int mr = tid >> 2, cq = (tid & 3) * 16;
  const float* src = &Vp[((i64)b * 2048 + m0 + mr) * 256 + c0 + cq];
#pragma unroll
  for (int i = 0; i < 16; i += 4) {
    float4 v = *(const float4*)(src + i);
    t[mr][cq + i + 0] = v.x; t[mr][cq + i + 1] = v.y;
    t[mr][cq + i + 2] = v.z; t[mr][cq + i + 3] = v.w;
  }
  __syncthreads();
  int cc = tid >> 2, mq = (tid & 3) * 16;
  int c = c0 + cc, h = c & 3, d = c >> 2;
  float* dst = &Vt[(((i64)b * 4 + h) * 64 + d) * 2048 + m0 + mq];
#pragma unroll
  for (int i = 0; i < 16; i += 4) {
    float4 v = make_float4(t[mq + i][cc], t[mq + i + 1][cc],
                           t[mq + i + 2][cc], t[mq + i + 3][cc]);
    *(float4*)(dst + i) = v;
  }
}

// ---- reduce 4 split-K slices + interleave head channel ----------------------
// Ocat[n][4d+h] = sum_kc Op8[kc][n*64+d]; grid (512)
__global__ __launch_bounds__(256) void k_redocat(const float* __restrict__ Op8,
                                                 float* __restrict__ OcatB, int h) {
  int i = blockIdx.x * 256 + threadIdx.x;   // over 2048*64
  int n = i >> 6, d = i & 63;
  float s = Op8[i] + Op8[131072 + i] + Op8[262144 + i] + Op8[393216 + i];
  OcatB[(i64)n * 256 + 4 * d + h] = s;
}

// ---- copy XA into Ccat cols 0:256; grid (2048,1,B) --------------------------
__global__ __launch_bounds__(256) void k_cpy2(const float* __restrict__ XA,
                                              float* __restrict__ Ccat) {
  int b = blockIdx.z;
  i64 n = blockIdx.x; int c = threadIdx.x;
  Ccat[((i64)b * 2048 + n) * 512 + c] = XA[((i64)b * 2048 + n) * 256 + c];
}

}  // namespace

// ============================================================================
extern "C" void kernel_launch(void* const* d_in, const int* in_sizes, int n_in,
                              void* d_out, int out_size, void* d_ws, size_t ws_size,
                              hipStream_t stream) {
  float* outp = (float*)d_out;
  auto diag = [&](float v) {
    k_diag<<<dim3((out_size + 255) / 256), dim3(256), 0, stream>>>(outp, out_size, v);
  };

  // -------- assumption guards (verified in rounds 8-11) ---------------------
  static const int DSZ[19] = {12288, 1048576, 12288, 1048576, 262144, 524288, 524288,
                              131072, 512, 131072, 512, 131072, 512, 131072, 512,
                              524288, 1024, 262144, 512};
  if (n_in != 19) { diag(1000.f + (float)n_in); return; }
  for (int i = 0; i < 19; i++) {
    if (in_sizes[i] != DSZ[i]) { diag(2000.f + (float)i); return; }
  }
  if (out_size != 2097152) { diag(3000.f); return; }
  constexpr size_t NEED = 50331648;  // 48 MiB (verified present)
  if (ws_size < NEED) { diag((float)(ws_size >> 20)); return; }

  // -------- workspace map (bytes) --------------------------------------------
  char* w = (char*)d_ws;
  float* SL0 = (float*)(w + 0);               // f32 slots (B,N,C), 4 MB each
  float* SL1 = (float*)(w + 4 * MB);
  float* SL2 = (float*)(w + 8 * MB);
  int*   KN1 = (int*)(w + 12 * MB);           // 256 KB
  int*   KN2 = (int*)(w + 12 * MB + 262144);  // 256 KB
  float* MEAN = (float*)(w + 12 * MB + 524288);          // [B][512]
  float* RSTD = (float*)(w + 12 * MB + 524288 + 4096);   // [B][512]
  float* PART = (float*)(w + 12 * MB + 524288 + 8192);   // [B][64][512][2] = 512 KB
  char* AR = w + 14 * MB;                     // 34 MB arena

  // gcn overlay
  float* P1 = (float*)(AR);                   // [B][2048][256] 4 MB
  float* Q1 = (float*)(AR + 4 * MB);          // 4 MB
  float* F1 = (float*)(AR + 8 * MB);          // 4 MB (RM1 then normed F1)
  float* P2 = (float*)(AR);                   // [B][2048][512] 8 MB (over P1,Q1)
  float* Q2 = (float*)(AR + 12 * MB);         // 8 MB
  float* F2 = (float*)(AR + 20 * MB);         // 8 MB (RM2 then normed F2)
  float* Y3 = (float*)(AR + 12 * MB);         // 4 MB (over Q2 after dead)
  float* U1 = (float*)(AR + 28 * MB);                 // 256 KB
  float* V1 = (float*)(AR + 28 * MB + 262144);        // 256 KB
  float* U2 = (float*)(AR + 28 * MB + 524288);        // 512 KB
  float* V2 = (float*)(AR + 28 * MB + 1048576);       // 512 KB
  // attention overlay
  float* Qp = (float*)(AR);                   // 4 MB
  float* Kp = (float*)(AR + 4 * MB);          // 4 MB
  float* Vp = (float*)(AR + 8 * MB);          // 4 MB
  float* Qh = (float*)(AR + 16 * MB);         // [B][4][2048][64] 4 MB
  float* Kh = (float*)(AR + 20 * MB);         // 4 MB
  float* Vt = (float*)(AR + 24 * MB);         // [B][4][64][2048] 4 MB
  float* Sf = (float*)(AR);                   // 16 MB (after repack)
  float* Ocat = (float*)(AR + 28 * MB);       // [B][2048][256] 4 MB
  float* Op8 = (float*)(AR + 32 * MB);        // [4][2048][64] 2 MB
  float* Ccat = (float*)(AR + 16 * MB);       // [B][2048][512] 8 MB (after QK)
  float* Hh = (float*)(AR);                   // 8 MB (after PV)

  const float* W1b = (const float*)d_in[4];
  const float* W2b = (const float*)d_in[5];
  const float* W3b = (const float*)d_in[6];
  const float* Wqb = (const float*)d_in[7];   const float* bqb = (const float*)d_in[8];
  const float* Wkb = (const float*)d_in[9];   const float* bkb = (const float*)d_in[10];
  const float* Wvb = (const float*)d_in[11];  const float* bvb = (const float*)d_in[12];
  const float* Wob = (const float*)d_in[13];  const float* bob = (const float*)d_in[14];
  const float* Wm1b = (const float*)d_in[15]; const float* bm1b = (const float*)d_in[16];
  const float* Wm2b = (const float*)d_in[17]; const float* bm2b = (const float*)d_in[18];

  auto gemm = [&](const float* A, int lda, i64 sA, const float* W, int ldw,
                  const float* bias, float* C, int ldc, i64 sC, i64 sKC,
                  int M, int N, int K, int nb, int kchunks, float scale, int mode) {
    if (N % 128 == 0) {
      k_gemm_mfma<128><<<dim3(M / 128, N / 128, nb * kchunks), dim3(256), 0, stream>>>(
          A, lda, sA, W, ldw, bias, C, ldc, sC, sKC, K, kchunks, scale, mode);
    } else {
      k_gemm_mfma<64><<<dim3(M / 128, N / 64, nb * kchunks), dim3(256), 0, stream>>>(
          A, lda, sA, W, ldw, bias, C, ldc, sC, sKC, K, kchunks, scale, mode);
    }
  };

  // -------- setup --------
  k_cvt<<<dim3(4096), dim3(256), 0, stream>>>((const float*)d_in[1], SL0);
  k_cvt<<<dim3(4096), dim3(256), 0, stream>>>((const float*)d_in[3], SL1);
  k_knn<<<dim3(NPV / 256, BB), dim3(256), 0, stream>>>((const float*)d_in[0], KN1);
  k_knn<<<dim3(NPV / 256, BB), dim3(256), 0, stream>>>((const float*)d_in[2], KN2);

  // -------- gcn layer (both batches in one set of launches) --------
  auto gcn = [&](const float* Xc, float* Xn, const int* knnb, int li) {
    const float* W1 = W1b + (i64)li * 131072;   // (256,512)
    const float* W2 = W2b + (i64)li * 262144;   // (512,512)
    const float* W3 = W3b + (i64)li * 262144;   // (256,1024)
    k_wsplit<<<dim3(256), dim3(256), 0, stream>>>(W1, U1, V1);
    k_wsplit<<<dim3(512), dim3(256), 0, stream>>>(W2, U2, V2);
    // hop 1: P1 = X@U1^T, Q1 = X@V1^T; RM1 = P1 + max_k gather(Q1); stats
    gemm(Xc, 256, NSTR, U1, 256, nullptr, P1, 256, NSTR, 0, 2048, 256, 256, 2, 1, 1.f, 0);
    gemm(Xc, 256, NSTR, V1, 256, nullptr, Q1, 256, NSTR, 0, 2048, 256, 256, 2, 1, 1.f, 0);
    k_gstat<<<dim3(1, 64, BB), dim3(256), 0, stream>>>(P1, Q1, knnb, 256, F1, PART);
    k_fin2<<<dim3(1, 1, BB), dim3(256), 0, stream>>>(PART, 256, 64, 1.f / 32768.f, MEAN, RSTD);
    k_norm2<<<dim3(2048, 1, BB), dim3(256), 0, stream>>>(F1, F1, 256, MEAN, RSTD, 1);
    // hop 2
    gemm(F1, 256, NSTR, U2, 256, nullptr, P2, 512, NSTR2, 0, 2048, 512, 256, 2, 1, 1.f, 0);
    gemm(F1, 256, NSTR, V2, 256, nullptr, Q2, 512, NSTR2, 0, 2048, 512, 256, 2, 1, 1.f, 0);
    k_gstat<<<dim3(2, 64, BB), dim3(256), 0, stream>>>(P2, Q2, knnb, 512, F2, PART);
    k_fin2<<<dim3(2, 1, BB), dim3(256), 0, stream>>>(PART, 512, 64, 1.f / 32768.f, MEAN, RSTD);
    k_norm2<<<dim3(2048, 2, BB), dim3(256), 0, stream>>>(F2, F2, 512, MEAN, RSTD, 1);
    // out: Y3 = [X|F1|F2] @ W3^T  (3 accumulating sub-GEMMs, no concat)
    gemm(Xc, 256, NSTR, W3,       1024, nullptr, Y3, 256, NSTR, 0, 2048, 256, 256, 2, 1, 1.f, 0);
    gemm(F1, 256, NSTR, W3 + 256, 1024, nullptr, Y3, 256, NSTR, 0, 2048, 256, 256, 2, 1, 1.f, 1);
    gemm(F2, 512, NSTR2, W3 + 512, 1024, nullptr, Y3, 256, NSTR, 0, 2048, 256, 512, 2, 1, 1.f, 1);
    k_part2<<<dim3(1, 8, BB), dim3(256), 0, stream>>>(Y3, 256, 256, 8, PART);
    k_fin2<<<dim3(1, 1, BB), dim3(256), 0, stream>>>(PART, 256, 8, 1.f / 2048.f, MEAN, RSTD);
    k_norm2<<<dim3(2048, 1, BB), dim3(256), 0, stream>>>(Y3, Xn, 256, MEAN, RSTD, 1);
  };

  // -------- cross attention --------
  auto attn = [&](const float* XA, const float* XB, float* XO, int li) {
    const float* Wq = Wqb + (i64)li * 65536;   const float* bq = bqb + (i64)li * 256;
    const float* Wk = Wkb + (i64)li * 65536;   const float* bk = bkb + (i64)li * 256;
    const float* Wv = Wvb + (i64)li * 65536;   const float* bv = bvb + (i64)li * 256;
    const float* Wo = Wob + (i64)li * 65536;   const float* bo = bob + (i64)li * 256;
    const float* Wm1 = Wm1b + (i64)li * 262144; const float* bm1 = bm1b + (i64)li * 512;
    const float* Wm2 = Wm2b + (i64)li * 131072; const float* bm2 = bm2b + (i64)li * 256;
    gemm(XA, 256, NSTR, Wq, 256, bq, Qp, 256, NSTR, 0, 2048, 256, 256, 2, 1, 1.f, 0);
    gemm(XB, 256, NSTR, Wk, 256, bk, Kp, 256, NSTR, 0, 2048, 256, 256, 2, 1, 1.f, 0);
    gemm(XB, 256, NSTR, Wv, 256, bv, Vp, 256, NSTR, 0, 2048, 256, 256, 2, 1, 1.f, 0);
    k_headify<<<dim3(2048, 1, BB), dim3(256), 0, stream>>>(Qp, Qh);
    k_headify<<<dim3(2048, 1, BB), dim3(256), 0, stream>>>(Kp, Kh);
    k_vtrans<<<dim3(32, 4, BB), dim3(256), 0, stream>>>(Vp, Vt);
    for (int b = 0; b < BB; b++) {
      for (int h = 0; h < 4; h++) {
        const float* qh = Qh + ((i64)b * 4 + h) * NPV * 64;
        const float* kh = Kh + ((i64)b * 4 + h) * NPV * 64;
        const float* vt = Vt + ((i64)b * 4 + h) * 64 * NPV;
        gemm(qh, 64, 0, kh, 64, nullptr, Sf, 2048, 0, 0, 2048, 2048, 64, 1, 1, 0.125f, 0);
        k_softmax<<<dim3(2048), dim3(256), 0, stream>>>(Sf);
        gemm(Sf, 2048, 0, vt, 2048, nullptr, Op8, 64, 0, (i64)NPV * 64,
             2048, 64, 2048, 1, 4, 1.f, 0);
        k_redocat<<<dim3(512), dim3(256), 0, stream>>>(Op8, Ocat + (i64)b * NSTR, h);
      }
    }
    gemm(Ocat, 256, NSTR, Wo, 256, bo, Ccat + 256, 512, NSTR2, 0, 2048, 256, 256, 2, 1, 1.f, 0);
    k_cpy2<<<dim3(2048, 1, BB), dim3(256), 0, stream>>>(XA, Ccat);
    gemm(Ccat, 512, NSTR2, Wm1, 512, bm1, Hh, 512, NSTR2, 0, 2048, 512, 512, 2, 1, 1.f, 0);
    k_part2<<<dim3(2, 8, BB), dim3(256), 0, stream>>>(Hh, 512, 256, 8, PART);
    k_fin2<<<dim3(2, 1, BB), dim3(256), 0, stream>>>(PART, 512, 8, 1.f / 2048.f, MEAN, RSTD);
    k_norm2<<<dim3(2048, 2, BB), dim3(256), 0, stream>>>(Hh, Hh, 512, MEAN, RSTD, 2);
    gemm(Hh, 512, NSTR2, Wm2, 512, bm2, XO, 256, NSTR, 0, 2048, 256, 512, 2, 1, 1.f, 0);
  };

  // -------- 4 layers, explicit hard-coded schedule --------
  gcn(SL0, SL2, KN1, 0);        // f1.a -> SL2
  gcn(SL1, SL0, KN2, 0);        // f2.a -> SL0   (SL1 free)
  attn(SL2, SL0, SL1, 0);       // f1.b = CA(f1.a, f2.a) -> SL1
  attn(SL0, SL1, SL2, 0);       // f2.b = CA(f2.a, f1.b) -> SL2
  gcn(SL1, SL0, KN1, 1);        // f1.c -> SL0
  gcn(SL2, SL1, KN2, 1);        // f2.c -> SL1
  attn(SL0, SL1, SL2, 1);       // f1.d = CA(f1.c, f2.c) -> SL2
  attn(SL1, SL2, SL0, 1);       // f2.d = CA(f2.c, f1.d) -> SL0
  // outputs: feats1 = SL2, feats2 = SL0

  k_final<<<dim3(4096), dim3(256), 0, stream>>>(SL2, outp);
  k_final<<<dim3(4096), dim3(256), 0, stream>>>(SL0, outp + (i64)BB * CCH * NPV);
}

// Round 4
// 2524.030 us; speedup vs baseline: 38.7035x; 4.7752x over previous
//
#include <hip/hip_runtime.h>

// ============================================================================
// InformationInteractive (gcn, cross_attn, gcn, cross_attn).
// Round 15: fix round-14 OOB crash. k_cvt2/k_final2 used mask (1<<21) [total
// elems] instead of (1<<20) [per-tensor elems]; b reached 3 -> 4MB overread
// of d_in[1]/d_in[3] -> HSA fault -> abort. Split fixed to 1<<20. All other
// round-14 content unchanged: flash attention (1 launch/layer), parallel knn
// (wave/point lex-min == serial watermarked argmin), [U;V] concat hop GEMMs,
// inorm+lrelu fused into GEMM A-staging, epilogue column stats. 71 launches.
// ============================================================================

namespace {

constexpr int BB = 2, NPV = 2048, CCH = 256, KNB = 16;
typedef long long i64;
typedef unsigned short u16;
constexpr i64 NSTR  = (i64)NPV * 256;
constexpr i64 NSTR2 = (i64)NPV * 512;
constexpr i64 NSTR4 = (i64)NPV * 1024;
constexpr i64 MB = 1048576;

typedef __attribute__((ext_vector_type(8))) short short8v;   // 8 bf16
typedef __attribute__((ext_vector_type(4))) float f32x4;

__device__ __forceinline__ float lrelu(float v) { return v >= 0.f ? v : 0.2f * v; }

// split f32 into hi/lo bf16 (truncation; x - hi exact in f32)
__device__ __forceinline__ void splitbf(float x, u16& h, u16& l) {
  unsigned u = __float_as_uint(x);
  h = (u16)(u >> 16);
  float hf = __uint_as_float(u & 0xffff0000u);
  l = (u16)(__float_as_uint(x - hf) >> 16);
}

// ---- diagnostics ------------------------------------------------------------
__global__ __launch_bounds__(256) void k_diag(float* out, int n, float v) {
  int i = blockIdx.x * 256 + threadIdx.x;
  if (i < n) out[i] = v;
}

// ---- both feats (B,C,N) -> X (B,N,C); grid 8192 (2 tensors x 2^20 elems) ---
__global__ __launch_bounds__(256) void k_cvt2(const float* __restrict__ fa,
                                              const float* __restrict__ fb,
                                              float* __restrict__ Xa,
                                              float* __restrict__ Xb) {
  int gi = blockIdx.x * 256 + threadIdx.x;
  bool second = gi >= (1 << 20);
  int idx = gi & ((1 << 20) - 1);
  int b = idx >> 19;
  int n = (idx >> 8) & (NPV - 1);
  int c = idx & (CCH - 1);
  const float* f = second ? fb : fa;
  float* X = second ? Xb : Xa;
  X[idx] = f[((i64)b * CCH + c) * NPV + n];
}

// ---- both X (B,N,C) -> out (B,C,N); grid 8192 -------------------------------
__global__ __launch_bounds__(256) void k_final2(const float* __restrict__ Xa,
                                                const float* __restrict__ Xb,
                                                float* __restrict__ out) {
  int gi = blockIdx.x * 256 + threadIdx.x;
  bool second = gi >= (1 << 20);
  int idx = gi & ((1 << 20) - 1);
  int b = idx >> 19;
  int c = (idx >> 11) & (CCH - 1);
  int n = idx & (NPV - 1);
  const float* X = second ? Xb : Xa;
  out[gi] = X[((i64)b * NPV + n) * CCH + c];
}

// ---- knn: parallel 17-pass watermarked argmin, one wave per point -----------
// Exactly equivalent to the serial scan: each pass selects the lex-min (d,m)
// among candidates strictly greater than the watermark (wd,wm).
__global__ __launch_bounds__(256) void k_knnp(const float* __restrict__ c1,
                                              const float* __restrict__ c2,
                                              int* __restrict__ o1,
                                              int* __restrict__ o2) {
#pragma clang fp contract(off)   // match np mul-then-add distance arithmetic
  __shared__ float cx[NPV], cy[NPV], cz[NPV], sq[NPV];
  int set = blockIdx.y >> 1, b = blockIdx.y & 1;
  const float* cb = (set ? c2 : c1) + (i64)b * 3 * NPV;
  int* ob = (set ? o2 : o1) + (i64)b * NPV * KNB;
  for (int m = threadIdx.x; m < NPV; m += 256) {
    float x = cb[m], y = cb[NPV + m], z = cb[2 * NPV + m];
    cx[m] = x; cy[m] = y; cz[m] = z;
    sq[m] = x * x + y * y + z * z;
  }
  __syncthreads();
  int w = threadIdx.x >> 6, lane = threadIdx.x & 63;
  int n = blockIdx.x * 4 + w;
  float xn = cx[n], yn = cy[n], zn = cz[n], sn = sq[n];
  float wd = -3.4e38f; int wm = -1;
  int* o = ob + (i64)n * KNB;
  for (int r = 0; r < KNB + 1; r++) {
    float bd = 3.4e38f; int bm = 0x7fffffff;
    for (int t = 0; t < 32; t++) {
      int m = t * 64 + lane;
      float dot = xn * cx[m] + yn * cy[m] + zn * cz[m];
      float d = (sn + sq[m]) - 2.0f * dot;
      bool valid = (d > wd) || (d == wd && m > wm);
      if (valid && (d < bd || (d == bd && m < bm))) { bd = d; bm = m; }
    }
    for (int mask = 1; mask < 64; mask <<= 1) {
      float od = __shfl_xor(bd, mask);
      int om = __shfl_xor(bm, mask);
      if (od < bd || (od == bd && om < bm)) { bd = od; bm = om; }
    }
    if (r > 0 && lane == 0) o[r - 1] = bm & (NPV - 1);
    wd = bd; wm = bm;
  }
}

// ---- weight prep: UV1=[W1c-W1n; W1n] (512x256), UV2=[W2c-W2n; W2n] (1024x256)
__global__ __launch_bounds__(256) void k_wsplit2(const float* __restrict__ W1,
                                                 const float* __restrict__ W2,
                                                 float* __restrict__ UV1,
                                                 float* __restrict__ UV2) {
  int i = blockIdx.x * 256 + threadIdx.x;
  if (i < 131072) {
    int r = i >> 8, c = i & 255;
    UV1[i] = (r < 256) ? W1[(i64)r * 512 + c] - W1[(i64)r * 512 + 256 + c]
                       : W1[(i64)(r - 256) * 512 + 256 + c];
  } else {
    int j = i - 131072;
    int r = j >> 8, c = j & 255;
    UV2[j] = (r < 512) ? W2[(i64)r * 512 + c] - W2[(i64)r * 512 + 256 + c]
                       : W2[(i64)(r - 512) * 512 + 256 + c];
  }
}

// ---- MFMA split-precision GEMM: C[M,N] = A[M,K]@W[N,K]^T (+bias / +=) -------
// BM=128, BN=128, 256 threads = 4 waves (2x2), wave tile 64x64.
// ANORM: A passes through inorm+lrelu, stats computed from pin (nchA chunks).
// ACAT : A cols 0:255 from A, 256:511 from A2 (both row-stride 256).
// ESTAT: epilogue writes per-block column sums/sumsq to pout (chunk=blockIdx.x).
template <bool ANORM, bool ACAT, bool ESTAT>
__global__ __launch_bounds__(256) void k_gemm(
    const float* __restrict__ A, int lda, i64 sA,
    const float* __restrict__ A2,
    const float* __restrict__ W, int ldw,
    const float* __restrict__ bias,
    float* __restrict__ C, int ldc, i64 sC,
    int K, int mode,
    const float* __restrict__ pin, int nchA, float invA,
    float* __restrict__ pout, int ncolsTot) {
  __shared__ __align__(16) u16 Ah[128][40], Al[128][40], Bh[128][40], Bl[128][40];
  __shared__ float mv[512], rv[512];
  __shared__ float cs[128][2];
  int b = blockIdx.z;
  A += (i64)b * sA;
  if (ACAT) A2 += (i64)b * NSTR;
  C += (i64)b * sC;
  int m0 = blockIdx.x * 128, n0 = blockIdx.y * 128;
  int tid = threadIdx.x;
  int w = tid >> 6, l = tid & 63;
  int wr = w >> 1, wc = w & 1;
  int lc = l & 15, lq = l >> 4;
  int srow = tid >> 1, skh = (tid & 1) * 16;

  if (ANORM) {
    for (int c = tid; c < K; c += 256) {
      float s = 0.f, ss = 0.f;
      for (int hh = 0; hh < nchA; hh++) {
        s  += pin[((i64)(b * nchA + hh) * K + c) * 2];
        ss += pin[((i64)(b * nchA + hh) * K + c) * 2 + 1];
      }
      float mu = s * invA;
      mv[c] = mu;
      rv[c] = 1.0f / sqrtf(ss * invA - mu * mu + 1e-5f);
    }
    __syncthreads();
  }

  const float* Ap = A + (i64)(m0 + srow) * lda + skh;
  const float* Wp = W + (i64)(n0 + srow) * ldw + skh;

  auto loadA = [&](int kt, float4* v) {
#pragma unroll
    for (int j = 0; j < 4; j++) {
      if (ACAT) {
        int col0 = kt + skh;
        const float* ap = (col0 < 256)
            ? A  + (i64)(m0 + srow) * 256 + col0
            : A2 + (i64)(m0 + srow) * 256 + (col0 - 256);
        v[j] = *(const float4*)(ap + j * 4);
      } else {
        v[j] = *(const float4*)(Ap + kt + j * 4);
      }
    }
  };
  auto loadW = [&](int kt, float4* v) {
#pragma unroll
    for (int j = 0; j < 4; j++) v[j] = *(const float4*)(Wp + kt + j * 4);
  };

  float4 ar[4], wv4[4];
  loadA(0, ar); loadW(0, wv4);

  f32x4 acc[4][4];
#pragma unroll
  for (int i = 0; i < 4; i++)
#pragma unroll
    for (int j = 0; j < 4; j++)
#pragma unroll
      for (int r = 0; r < 4; r++) acc[i][j][r] = 0.f;

  int koff = lq * 8;
  for (int kt = 0; kt < K; kt += 32) {
    __syncthreads();
#pragma unroll
    for (int j = 0; j < 4; j++) {
      float4 a = ar[j];
      if (ANORM) {
        float4 mu = *(const float4*)&mv[kt + skh + j * 4];
        float4 rs = *(const float4*)&rv[kt + skh + j * 4];
        a.x = lrelu((a.x - mu.x) * rs.x);
        a.y = lrelu((a.y - mu.y) * rs.y);
        a.z = lrelu((a.z - mu.z) * rs.z);
        a.w = lrelu((a.w - mu.w) * rs.w);
      }
      u16 h0, h1, h2, h3, l0, l1, l2, l3;
      splitbf(a.x, h0, l0); splitbf(a.y, h1, l1);
      splitbf(a.z, h2, l2); splitbf(a.w, h3, l3);
      *(ushort4*)&Ah[srow][skh + j * 4] = make_ushort4(h0, h1, h2, h3);
      *(ushort4*)&Al[srow][skh + j * 4] = make_ushort4(l0, l1, l2, l3);
      float4 bb = wv4[j];
      splitbf(bb.x, h0, l0); splitbf(bb.y, h1, l1);
      splitbf(bb.z, h2, l2); splitbf(bb.w, h3, l3);
      *(ushort4*)&Bh[srow][skh + j * 4] = make_ushort4(h0, h1, h2, h3);
      *(ushort4*)&Bl[srow][skh + j * 4] = make_ushort4(l0, l1, l2, l3);
    }
    __syncthreads();
    if (kt + 32 < K) { loadA(kt + 32, ar); loadW(kt + 32, wv4); }
    short8v ah[4], al4[4], bh[4], bl4[4];
#pragma unroll
    for (int i = 0; i < 4; i++) {
      int r = wr * 64 + i * 16 + lc;
      ah[i]  = *(const short8v*)&Ah[r][koff];
      al4[i] = *(const short8v*)&Al[r][koff];
    }
#pragma unroll
    for (int j = 0; j < 4; j++) {
      int r = wc * 64 + j * 16 + lc;
      bh[j]  = *(const short8v*)&Bh[r][koff];
      bl4[j] = *(const short8v*)&Bl[r][koff];
    }
#pragma unroll
    for (int i = 0; i < 4; i++) {
#pragma unroll
      for (int j = 0; j < 4; j++) {
        acc[i][j] = __builtin_amdgcn_mfma_f32_16x16x32_bf16(ah[i], bh[j], acc[i][j], 0, 0, 0);
        acc[i][j] = __builtin_amdgcn_mfma_f32_16x16x32_bf16(al4[i], bh[j], acc[i][j], 0, 0, 0);
        acc[i][j] = __builtin_amdgcn_mfma_f32_16x16x32_bf16(ah[i], bl4[j], acc[i][j], 0, 0, 0);
      }
    }
  }

  float sj[4] = {0.f, 0.f, 0.f, 0.f}, ssj[4] = {0.f, 0.f, 0.f, 0.f};
#pragma unroll
  for (int j = 0; j < 4; j++) {
    int col = n0 + wc * 64 + j * 16 + lc;
    float bv = (mode == 0 && bias) ? bias[col] : 0.f;
#pragma unroll
    for (int i = 0; i < 4; i++) {
      int rbase = m0 + wr * 64 + i * 16 + lq * 4;
#pragma unroll
      for (int r = 0; r < 4; r++) {
        float* cp = &C[(i64)(rbase + r) * ldc + col];
        float v = acc[i][j][r] + ((mode == 0) ? bv : *cp);
        *cp = v;
        if (ESTAT) { sj[j] += v; ssj[j] += v * v; }
      }
    }
  }
  if (ESTAT) {
#pragma unroll
    for (int j = 0; j < 4; j++) {
      sj[j]  += __shfl_xor(sj[j], 16);  sj[j]  += __shfl_xor(sj[j], 32);
      ssj[j] += __shfl_xor(ssj[j], 16); ssj[j] += __shfl_xor(ssj[j], 32);
    }
    __syncthreads();
    if (wr == 0 && lq == 0) {
#pragma unroll
      for (int j = 0; j < 4; j++) {
        int cl = wc * 64 + j * 16 + lc;
        cs[cl][0] = sj[j]; cs[cl][1] = ssj[j];
      }
    }
    __syncthreads();
    if (wr == 1 && lq == 0) {
#pragma unroll
      for (int j = 0; j < 4; j++) {
        int cl = wc * 64 + j * 16 + lc;
        cs[cl][0] += sj[j]; cs[cl][1] += ssj[j];
      }
    }
    __syncthreads();
    if (tid < 128) {
      i64 slot = ((i64)(b * gridDim.x + blockIdx.x) * ncolsTot + n0 + tid) * 2;
      pout[slot] = cs[tid][0];
      pout[slot + 1] = cs[tid][1];
    }
  }
}

// ---- fused gather: RM[n,o] = P[n,o] + max_k Q[j,o]; partial inorm stats ----
// P/Q live in one PQ buffer with row stride ldpq. grid: (O/256, 64, B).
__global__ __launch_bounds__(256) void k_gstat(const float* __restrict__ P,
                                               const float* __restrict__ Q,
                                               int ldpq,
                                               const int* __restrict__ knn,
                                               int O, float* __restrict__ RM,
                                               float* __restrict__ part) {
  int b = blockIdx.z;
  int o = blockIdx.x * 256 + threadIdx.x;
  int n0 = blockIdx.y * 32;
  P += (i64)b * 2048 * ldpq; Q += (i64)b * 2048 * ldpq; RM += (i64)b * 2048 * O;
  knn += ((i64)b * 2048 + n0) * KNB;
  __shared__ int js[32 * KNB];
  for (int i = threadIdx.x; i < 32 * KNB; i += 256) js[i] = knn[i];
  __syncthreads();
  float s = 0.f, ss = 0.f;
  for (int r = 0; r < 32; r++) {
    int n = n0 + r;
    float p = P[(i64)n * ldpq + o];
    float qm = -3.4e38f, qs = 0.f, qss = 0.f;
#pragma unroll
    for (int k = 0; k < KNB; k++) {
      float q = Q[(i64)js[r * KNB + k] * ldpq + o];
      qm = fmaxf(qm, q); qs += q; qss += q * q;
    }
    RM[(i64)n * O + o] = p + qm;
    s  += 16.f * p + qs;
    ss += 16.f * p * p + 2.f * p * qs + qss;
  }
  i64 slot = ((i64)b * 64 + blockIdx.y) * O + o;
  part[slot * 2] = s; part[slot * 2 + 1] = ss;
}

// ---- normalize + act, stats from PART; grid (2048, cols/256, B) ------------
__global__ __launch_bounds__(256) void k_normP(const float* __restrict__ src,
                                               float* __restrict__ dst, int cols,
                                               const float* __restrict__ part,
                                               int nch, float inv, int act) {
  int b = blockIdx.z;
  i64 n = blockIdx.x;
  int c = blockIdx.y * 256 + threadIdx.x;
  float s = 0.f, ss = 0.f;
  for (int h = 0; h < nch; h++) {
    s  += part[((i64)(b * nch + h) * cols + c) * 2];
    ss += part[((i64)(b * nch + h) * cols + c) * 2 + 1];
  }
  float mu = s * inv;
  float rs = 1.0f / sqrtf(ss * inv - mu * mu + 1e-5f);
  i64 off = ((i64)b * 2048 + n) * cols + c;
  float v = (src[off] - mu) * rs;
  dst[off] = (act == 1) ? lrelu(v) : fmaxf(v, 0.f);
}

// ---- flash attention: grid (32 qtiles, 4 heads, B), 256 thr = 4 waves ------
// Q/K/V in [n][256] layout, channel c = 4d+h. BQ=64 (16 rows/wave), BK=64.
__global__ __launch_bounds__(256) void k_flash(const float* __restrict__ Qp,
                                               const float* __restrict__ Kp,
                                               const float* __restrict__ Vp,
                                               float* __restrict__ Op) {
  __shared__ __align__(16) u16 Kh[64][72], Kl[64][72];
  __shared__ __align__(16) u16 Vh[64][72], Vl[64][72];   // [d][m]
  __shared__ __align__(16) u16 Ph[4][16][72], Pl[4][16][72];
  int qt = blockIdx.x, h = blockIdx.y, b = blockIdx.z;
  const float* Qb = Qp + (i64)b * NSTR;
  const float* Kb = Kp + (i64)b * NSTR;
  const float* Vb = Vp + (i64)b * NSTR;
  int tid = threadIdx.x;
  int w = tid >> 6, l = tid & 63;
  int lc = l & 15, lq = l >> 4;
  // Q fragments in registers: wave w owns q rows qt*64 + w*16 + (0..15)
  short8v qh[2], ql[2];
  int qrow = qt * 64 + w * 16 + lc;
#pragma unroll
  for (int ks = 0; ks < 2; ks++) {
#pragma unroll
    for (int j = 0; j < 8; j++) {
      float v = Qb[(i64)qrow * 256 + 4 * (ks * 32 + lq * 8 + j) + h];
      u16 hh, ll; splitbf(v, hh, ll);
      qh[ks][j] = (short)hh; ql[ks][j] = (short)ll;
    }
  }
  float m_r[4] = {-3.0e38f, -3.0e38f, -3.0e38f, -3.0e38f};
  float l_r[4] = {0.f, 0.f, 0.f, 0.f};
  f32x4 acc[4];
#pragma unroll
  for (int j = 0; j < 4; j++)
#pragma unroll
    for (int r = 0; r < 4; r++) acc[j][r] = 0.f;

  for (int kt = 0; kt < 32; kt++) {
    __syncthreads();
    for (int i = tid; i < 4096; i += 256) {
      int m = i >> 6, dd = i & 63;
      u16 hh, ll;
      float kv = Kb[(i64)(kt * 64 + m) * 256 + 4 * dd + h];
      splitbf(kv, hh, ll);
      Kh[m][dd] = hh; Kl[m][dd] = ll;
      float vv = Vb[(i64)(kt * 64 + m) * 256 + 4 * dd + h];
      splitbf(vv, hh, ll);
      Vh[dd][m] = hh; Vl[dd][m] = ll;
    }
    __syncthreads();
    // S = 0.125 * Q K^T
    f32x4 s[4];
#pragma unroll
    for (int j = 0; j < 4; j++)
#pragma unroll
      for (int r = 0; r < 4; r++) s[j][r] = 0.f;
#pragma unroll
    for (int ks = 0; ks < 2; ks++) {
      int ko = ks * 32 + lq * 8;
#pragma unroll
      for (int j = 0; j < 4; j++) {
        short8v bh = *(const short8v*)&Kh[j * 16 + lc][ko];
        short8v bl = *(const short8v*)&Kl[j * 16 + lc][ko];
        s[j] = __builtin_amdgcn_mfma_f32_16x16x32_bf16(qh[ks], bh, s[j], 0, 0, 0);
        s[j] = __builtin_amdgcn_mfma_f32_16x16x32_bf16(ql[ks], bh, s[j], 0, 0, 0);
        s[j] = __builtin_amdgcn_mfma_f32_16x16x32_bf16(qh[ks], bl, s[j], 0, 0, 0);
      }
    }
#pragma unroll
    for (int j = 0; j < 4; j++)
#pragma unroll
      for (int r = 0; r < 4; r++) s[j][r] *= 0.125f;
    // online softmax (rows q = lq*4 + r; reduce over 16 lc lanes)
    float rmax[4];
#pragma unroll
    for (int r = 0; r < 4; r++)
      rmax[r] = fmaxf(fmaxf(s[0][r], s[1][r]), fmaxf(s[2][r], s[3][r]));
#pragma unroll
    for (int mask = 1; mask < 16; mask <<= 1)
#pragma unroll
      for (int r = 0; r < 4; r++) rmax[r] = fmaxf(rmax[r], __shfl_xor(rmax[r], mask));
    float fs[4], rsum[4];
#pragma unroll
    for (int r = 0; r < 4; r++) {
      float mn = fmaxf(m_r[r], rmax[r]);
      fs[r] = expf(m_r[r] - mn);
      m_r[r] = mn; rsum[r] = 0.f;
    }
#pragma unroll
    for (int j = 0; j < 4; j++)
#pragma unroll
      for (int r = 0; r < 4; r++) {
        float p = expf(s[j][r] - m_r[r]);
        rsum[r] += p;
        u16 hh, ll; splitbf(p, hh, ll);
        Ph[w][lq * 4 + r][j * 16 + lc] = hh;
        Pl[w][lq * 4 + r][j * 16 + lc] = ll;
      }
#pragma unroll
    for (int mask = 1; mask < 16; mask <<= 1)
#pragma unroll
      for (int r = 0; r < 4; r++) rsum[r] += __shfl_xor(rsum[r], mask);
#pragma unroll
    for (int r = 0; r < 4; r++) l_r[r] = l_r[r] * fs[r] + rsum[r];
#pragma unroll
    for (int j = 0; j < 4; j++)
#pragma unroll
      for (int r = 0; r < 4; r++) acc[j][r] *= fs[r];
    // O += P V  (A = P rows q, k = m; B = V [d][m])
#pragma unroll
    for (int ks = 0; ks < 2; ks++) {
      int ko = ks * 32 + lq * 8;
      short8v ph = *(const short8v*)&Ph[w][lc][ko];
      short8v pl = *(const short8v*)&Pl[w][lc][ko];
#pragma unroll
      for (int j = 0; j < 4; j++) {
        short8v bh = *(const short8v*)&Vh[j * 16 + lc][ko];
        short8v bl = *(const short8v*)&Vl[j * 16 + lc][ko];
        acc[j] = __builtin_amdgcn_mfma_f32_16x16x32_bf16(ph, bh, acc[j], 0, 0, 0);
        acc[j] = __builtin_amdgcn_mfma_f32_16x16x32_bf16(pl, bh, acc[j], 0, 0, 0);
        acc[j] = __builtin_amdgcn_mfma_f32_16x16x32_bf16(ph, bl, acc[j], 0, 0, 0);
      }
    }
  }
  float* Ob = Op + (i64)b * NSTR;
#pragma unroll
  for (int j = 0; j < 4; j++) {
    int dd = j * 16 + lc;
#pragma unroll
    for (int r = 0; r < 4; r++) {
      int q = qt * 64 + w * 16 + lq * 4 + r;
      Ob[(i64)q * 256 + 4 * dd + h] = acc[j][r] / l_r[r];
    }
  }
}

}  // namespace

// ============================================================================
extern "C" void kernel_launch(void* const* d_in, const int* in_sizes, int n_in,
                              void* d_out, int out_size, void* d_ws, size_t ws_size,
                              hipStream_t stream) {
  float* outp = (float*)d_out;
  auto diag = [&](float v) {
    k_diag<<<dim3((out_size + 255) / 256), dim3(256), 0, stream>>>(outp, out_size, v);
  };

  // -------- assumption guards (verified rounds 8-13) -------------------------
  static const int DSZ[19] = {12288, 1048576, 12288, 1048576, 262144, 524288, 524288,
                              131072, 512, 131072, 512, 131072, 512, 131072, 512,
                              524288, 1024, 262144, 512};
  if (n_in != 19) { diag(1000.f + (float)n_in); return; }
  for (int i = 0; i < 19; i++) {
    if (in_sizes[i] != DSZ[i]) { diag(2000.f + (float)i); return; }
  }
  if (out_size != 2097152) { diag(3000.f); return; }
  constexpr size_t NEED = 50331648;  // 48 MiB
  if (ws_size < NEED) { diag((float)(ws_size >> 20)); return; }

  // -------- workspace map ----------------------------------------------------
  char* w = (char*)d_ws;
  float* SL0 = (float*)(w + 0);
  float* SL1 = (float*)(w + 4 * MB);
  float* SL2 = (float*)(w + 8 * MB);
  int*   KN1 = (int*)(w + 12 * MB);
  int*   KN2 = (int*)(w + 12 * MB + 262144);
  float* PARTA = (float*)(w + 12 * MB + 524288);            // 256 KB (hop1)
  float* PARTB = (float*)(w + 12 * MB + 786432);            // 512 KB (hop2)
  float* PARTC = (float*)(w + 12 * MB + 1310720);           // 128 KB (estat)
  char* AR = w + 14 * MB;                                   // 34 MB arena

  // gcn overlay
  float* PQ1 = (float*)(AR);                  // [B][2048][512]  8 MB
  float* F1  = (float*)(AR + 8 * MB);         // [B][2048][256]  4 MB
  float* PQ2 = (float*)(AR + 12 * MB);        // [B][2048][1024] 16 MB
  float* F2  = (float*)(AR);                  // [B][2048][512]  8 MB (over PQ1)
  float* Y3  = (float*)(AR + 12 * MB);        // 4 MB (over dead PQ2)
  float* UV1 = (float*)(AR + 28 * MB);        // 512 KB
  float* UV2 = (float*)(AR + 28 * MB + 524288); // 1 MB
  // attention overlay
  float* Qp = (float*)(AR);                   // 4 MB
  float* Kp = (float*)(AR + 4 * MB);          // 4 MB
  float* Vp = (float*)(AR + 8 * MB);          // 4 MB
  float* Oc = (float*)(AR + 12 * MB);         // 4 MB (attn out, pre-Wo)
  float* Wo_ = (float*)(AR + 16 * MB);        // 4 MB (Wo output)
  float* Hh = (float*)(AR + 20 * MB);         // 8 MB

  const float* W1b = (const float*)d_in[4];
  const float* W2b = (const float*)d_in[5];
  const float* W3b = (const float*)d_in[6];
  const float* Wqb = (const float*)d_in[7];   const float* bqb = (const float*)d_in[8];
  const float* Wkb = (const float*)d_in[9];   const float* bkb = (const float*)d_in[10];
  const float* Wvb = (const float*)d_in[11];  const float* bvb = (const float*)d_in[12];
  const float* Wob = (const float*)d_in[13];  const float* bob = (const float*)d_in[14];
  const float* Wm1b = (const float*)d_in[15]; const float* bm1b = (const float*)d_in[16];
  const float* Wm2b = (const float*)d_in[17]; const float* bm2b = (const float*)d_in[18];

  // -------- setup --------
  k_cvt2<<<dim3(8192), dim3(256), 0, stream>>>((const float*)d_in[1],
                                               (const float*)d_in[3], SL0, SL1);
  k_knnp<<<dim3(NPV / 4, 4), dim3(256), 0, stream>>>((const float*)d_in[0],
                                                     (const float*)d_in[2], KN1, KN2);

  // -------- gcn layer --------
  auto gcn = [&](const float* Xc, float* Xn, const int* knnb, int li) {
    const float* W1 = W1b + (i64)li * 131072;
    const float* W2 = W2b + (i64)li * 262144;
    const float* W3 = W3b + (i64)li * 262144;
    k_wsplit2<<<dim3(1536), dim3(256), 0, stream>>>(W1, W2, UV1, UV2);
    // hop 1: PQ1 = X @ [U1;V1]^T  (P cols 0:256, Q cols 256:512)
    k_gemm<false, false, false><<<dim3(16, 4, 2), dim3(256), 0, stream>>>(
        Xc, 256, NSTR, nullptr, UV1, 256, nullptr, PQ1, 512, NSTR2, 256, 0,
        nullptr, 0, 0.f, nullptr, 0);
    k_gstat<<<dim3(1, 64, BB), dim3(256), 0, stream>>>(PQ1, PQ1 + 256, 512, knnb,
                                                       256, F1, PARTA);
    // hop 2: PQ2 = norm(F1) @ [U2;V2]^T
    k_gemm<true, false, false><<<dim3(16, 8, 2), dim3(256), 0, stream>>>(
        F1, 256, NSTR, nullptr, UV2, 256, nullptr, PQ2, 1024, NSTR4, 256, 0,
        PARTA, 64, 1.f / 32768.f, nullptr, 0);
    k_gstat<<<dim3(2, 64, BB), dim3(256), 0, stream>>>(PQ2, PQ2 + 512, 1024, knnb,
                                                       512, F2, PARTB);
    // Y3 = [X | norm(F1) | norm(F2)] @ W3^T
    k_gemm<false, false, false><<<dim3(16, 2, 2), dim3(256), 0, stream>>>(
        Xc, 256, NSTR, nullptr, W3, 1024, nullptr, Y3, 256, NSTR, 256, 0,
        nullptr, 0, 0.f, nullptr, 0);
    k_gemm<true, false, false><<<dim3(16, 2, 2), dim3(256), 0, stream>>>(
        F1, 256, NSTR, nullptr, W3 + 256, 1024, nullptr, Y3, 256, NSTR, 256, 1,
        PARTA, 64, 1.f / 32768.f, nullptr, 0);
    k_gemm<true, false, true><<<dim3(16, 2, 2), dim3(256), 0, stream>>>(
        F2, 512, NSTR2, nullptr, W3 + 512, 1024, nullptr, Y3, 256, NSTR, 512, 1,
        PARTB, 64, 1.f / 32768.f, PARTC, 256);
    k_normP<<<dim3(2048, 1, BB), dim3(256), 0, stream>>>(Y3, Xn, 256, PARTC, 16,
                                                         1.f / 2048.f, 1);
  };

  // -------- cross attention --------
  auto attn = [&](const float* XA, const float* XB, float* XO, int li) {
    const float* Wq = Wqb + (i64)li * 65536;   const float* bq = bqb + (i64)li * 256;
    const float* Wk = Wkb + (i64)li * 65536;   const float* bk = bkb + (i64)li * 256;
    const float* Wv = Wvb + (i64)li * 65536;   const float* bv = bvb + (i64)li * 256;
    const float* Wo = Wob + (i64)li * 65536;   const float* bo = bob + (i64)li * 256;
    const float* Wm1 = Wm1b + (i64)li * 262144; const float* bm1 = bm1b + (i64)li * 512;
    const float* Wm2 = Wm2b + (i64)li * 131072; const float* bm2 = bm2b + (i64)li * 256;
    k_gemm<false, false, false><<<dim3(16, 2, 2), dim3(256), 0, stream>>>(
        XA, 256, NSTR, nullptr, Wq, 256, bq, Qp, 256, NSTR, 256, 0,
        nullptr, 0, 0.f, nullptr, 0);
    k_gemm<false, false, false><<<dim3(16, 2, 2), dim3(256), 0, stream>>>(
        XB, 256, NSTR, nullptr, Wk, 256, bk, Kp, 256, NSTR, 256, 0,
        nullptr, 0, 0.f, nullptr, 0);
    k_gemm<false, false, false><<<dim3(16, 2, 2), dim3(256), 0, stream>>>(
        XB, 256, NSTR, nullptr, Wv, 256, bv, Vp, 256, NSTR, 256, 0,
        nullptr, 0, 0.f, nullptr, 0);
    k_flash<<<dim3(32, 4, BB), dim3(256), 0, stream>>>(Qp, Kp, Vp, Oc);
    k_gemm<false, false, false><<<dim3(16, 2, 2), dim3(256), 0, stream>>>(
        Oc, 256, NSTR, nullptr, Wo, 256, bo, Wo_, 256, NSTR, 256, 0,
        nullptr, 0, 0.f, nullptr, 0);
    // Hh = [XA | Wo_] @ Wm1^T + bm1, with epilogue stats
    k_gemm<false, true, true><<<dim3(16, 4, 2), dim3(256), 0, stream>>>(
        XA, 256, NSTR, Wo_, Wm1, 512, bm1, Hh, 512, NSTR2, 512, 0,
        nullptr, 0, 0.f, PARTC, 512);
    k_normP<<<dim3(2048, 2, BB), dim3(256), 0, stream>>>(Hh, Hh, 512, PARTC, 16,
                                                         1.f / 2048.f, 2);
    k_gemm<false, false, false><<<dim3(16, 2, 2), dim3(256), 0, stream>>>(
        Hh, 512, NSTR2, nullptr, Wm2, 512, bm2, XO, 256, NSTR, 512, 0,
        nullptr, 0, 0.f, nullptr, 0);
  };

  // -------- 4 layers --------
  gcn(SL0, SL2, KN1, 0);        // f1.a -> SL2
  gcn(SL1, SL0, KN2, 0);        // f2.a -> SL0
  attn(SL2, SL0, SL1, 0);       // f1.b -> SL1
  attn(SL0, SL1, SL2, 0);       // f2.b -> SL2
  gcn(SL1, SL0, KN1, 1);        // f1.c -> SL0
  gcn(SL2, SL1, KN2, 1);        // f2.c -> SL1
  attn(SL0, SL1, SL2, 1);       // f1.d -> SL2
  attn(SL1, SL2, SL0, 1);       // f2.d -> SL0

  k_final2<<<dim3(8192), dim3(256), 0, stream>>>(SL2, SL0, outp);
}

// Round 5
// 1947.592 us; speedup vs baseline: 50.1588x; 1.2960x over previous
//
#include <hip/hip_runtime.h>

// ============================================================================
// InformationInteractive (gcn, cross_attn, gcn, cross_attn).
// Round 16: counters (r15: top dispatch k_knnp 191us, rest <190, total 2524)
// say launch/serialization + knn LDS-issue bound. Changes:
//  - knn: float4-packed LDS (1x ds_read_b128 vs 4x ds_read_b32 per candidate).
//  - launches 71 -> 52: QKV merged (z=6), Y3 = single segmented K=1024 GEMM
//    (X | norm(F1) | norm(F2)) with epilogue stats, UV weight prep hoisted to
//    setup (both layers).
//  - K/V projections write head-major [b][h][n][64] (permuted epilogue) ->
//    flash stages K/V with coalesced float4 loads (4x fewer load instrs).
// Numerics: identical arithmetic everywhere (absmax expected 0.015625).
// ============================================================================

namespace {

constexpr int BB = 2, NPV = 2048, CCH = 256, KNB = 16;
typedef long long i64;
typedef unsigned short u16;
constexpr i64 NSTR  = (i64)NPV * 256;
constexpr i64 NSTR2 = (i64)NPV * 512;
constexpr i64 NSTR4 = (i64)NPV * 1024;
constexpr i64 MB = 1048576;

typedef __attribute__((ext_vector_type(8))) short short8v;   // 8 bf16
typedef __attribute__((ext_vector_type(4))) float f32x4;

__device__ __forceinline__ float lrelu(float v) { return v >= 0.f ? v : 0.2f * v; }

// split f32 into hi/lo bf16 (truncation; x - hi exact in f32)
__device__ __forceinline__ void splitbf(float x, u16& h, u16& l) {
  unsigned u = __float_as_uint(x);
  h = (u16)(u >> 16);
  float hf = __uint_as_float(u & 0xffff0000u);
  l = (u16)(__float_as_uint(x - hf) >> 16);
}

// ---- diagnostics ------------------------------------------------------------
__global__ __launch_bounds__(256) void k_diag(float* out, int n, float v) {
  int i = blockIdx.x * 256 + threadIdx.x;
  if (i < n) out[i] = v;
}

// ---- both feats (B,C,N) -> X (B,N,C); grid 8192 (2 tensors x 2^20 elems) ---
__global__ __launch_bounds__(256) void k_cvt2(const float* __restrict__ fa,
                                              const float* __restrict__ fb,
                                              float* __restrict__ Xa,
                                              float* __restrict__ Xb) {
  int gi = blockIdx.x * 256 + threadIdx.x;
  bool second = gi >= (1 << 20);
  int idx = gi & ((1 << 20) - 1);
  int b = idx >> 19;
  int n = (idx >> 8) & (NPV - 1);
  int c = idx & (CCH - 1);
  const float* f = second ? fb : fa;
  float* X = second ? Xb : Xa;
  X[idx] = f[((i64)b * CCH + c) * NPV + n];
}

// ---- both X (B,N,C) -> out (B,C,N); grid 8192 -------------------------------
__global__ __launch_bounds__(256) void k_final2(const float* __restrict__ Xa,
                                                const float* __restrict__ Xb,
                                                float* __restrict__ out) {
  int gi = blockIdx.x * 256 + threadIdx.x;
  bool second = gi >= (1 << 20);
  int idx = gi & ((1 << 20) - 1);
  int b = idx >> 19;
  int c = (idx >> 11) & (CCH - 1);
  int n = idx & (NPV - 1);
  const float* X = second ? Xb : Xa;
  out[gi] = X[((i64)b * NPV + n) * CCH + c];
}

// ---- knn: parallel 17-pass watermarked argmin, one wave per point -----------
// float4-packed LDS: one ds_read_b128 per candidate (was 4x ds_read_b32).
__global__ __launch_bounds__(256) void k_knnp(const float* __restrict__ c1,
                                              const float* __restrict__ c2,
                                              int* __restrict__ o1,
                                              int* __restrict__ o2) {
#pragma clang fp contract(off)   // match np mul-then-add distance arithmetic
  __shared__ float4 csq[NPV];
  int set = blockIdx.y >> 1, b = blockIdx.y & 1;
  const float* cb = (set ? c2 : c1) + (i64)b * 3 * NPV;
  int* ob = (set ? o2 : o1) + (i64)b * NPV * KNB;
  for (int m = threadIdx.x; m < NPV; m += 256) {
    float x = cb[m], y = cb[NPV + m], z = cb[2 * NPV + m];
    csq[m] = make_float4(x, y, z, x * x + y * y + z * z);
  }
  __syncthreads();
  int w = threadIdx.x >> 6, lane = threadIdx.x & 63;
  int n = blockIdx.x * 4 + w;
  float4 cn = csq[n];
  float xn = cn.x, yn = cn.y, zn = cn.z, sn = cn.w;
  float wd = -3.4e38f; int wm = -1;
  int* o = ob + (i64)n * KNB;
  for (int r = 0; r < KNB + 1; r++) {
    float bd = 3.4e38f; int bm = 0x7fffffff;
    for (int t = 0; t < 32; t++) {
      int m = t * 64 + lane;
      float4 c = csq[m];
      float dot = xn * c.x + yn * c.y + zn * c.z;
      float d = (sn + c.w) - 2.0f * dot;
      bool valid = (d > wd) || (d == wd && m > wm);
      if (valid && (d < bd || (d == bd && m < bm))) { bd = d; bm = m; }
    }
    for (int mask = 1; mask < 64; mask <<= 1) {
      float od = __shfl_xor(bd, mask);
      int om = __shfl_xor(bm, mask);
      if (od < bd || (od == bd && om < bm)) { bd = od; bm = om; }
    }
    if (r > 0 && lane == 0) o[r - 1] = bm & (NPV - 1);
    wd = bd; wm = bm;
  }
}

// ---- weight prep (both layers): UVS[li] = [W1c-W1n; W1n | W2c-W2n; W2n] ----
__global__ __launch_bounds__(256) void k_wprep(const float* __restrict__ W1b,
                                               const float* __restrict__ W2b,
                                               float* __restrict__ UVS) {
  int i = blockIdx.x * 256 + threadIdx.x;   // 0..786431
  int li = i / 393216;
  int r0 = i - li * 393216;
  const float* W1 = W1b + (i64)li * 131072;
  const float* W2 = W2b + (i64)li * 262144;
  float* dst = UVS + (i64)li * 393216;
  if (r0 < 131072) {
    int r = r0 >> 8, c = r0 & 255;
    dst[r0] = (r < 256) ? W1[(i64)r * 512 + c] - W1[(i64)r * 512 + 256 + c]
                        : W1[(i64)(r - 256) * 512 + 256 + c];
  } else {
    int j = r0 - 131072;
    int r = j >> 8, c = j & 255;
    dst[131072 + j] = (r < 512) ? W2[(i64)r * 512 + c] - W2[(i64)r * 512 + 256 + c]
                                : W2[(i64)(r - 512) * 512 + 256 + c];
  }
}

// ---- MFMA split-precision GEMM: C[M,N] = A[M,K]@W[N,K]^T (+bias / +=) -------
// BM=128, BN=128, 256 threads = 4 waves (2x2), wave tile 64x64.
// ANORM: A passes through inorm+lrelu, stats computed from pin (nchA chunks).
// ACAT : A cols 0:255 from A, 256:511 from A2 (both row-stride 256).
// ESTAT: epilogue writes per-block column sums/sumsq to pout (chunk=blockIdx.x).
template <bool ANORM, bool ACAT, bool ESTAT>
__global__ __launch_bounds__(256) void k_gemm(
    const float* __restrict__ A, int lda, i64 sA,
    const float* __restrict__ A2,
    const float* __restrict__ W, int ldw,
    const float* __restrict__ bias,
    float* __restrict__ C, int ldc, i64 sC,
    int K, int mode,
    const float* __restrict__ pin, int nchA, float invA,
    float* __restrict__ pout, int ncolsTot) {
  __shared__ __align__(16) u16 Ah[128][40], Al[128][40], Bh[128][40], Bl[128][40];
  __shared__ float mv[512], rv[512];
  __shared__ float cs[128][2];
  int b = blockIdx.z;
  A += (i64)b * sA;
  if (ACAT) A2 += (i64)b * NSTR;
  C += (i64)b * sC;
  int m0 = blockIdx.x * 128, n0 = blockIdx.y * 128;
  int tid = threadIdx.x;
  int w = tid >> 6, l = tid & 63;
  int wr = w >> 1, wc = w & 1;
  int lc = l & 15, lq = l >> 4;
  int srow = tid >> 1, skh = (tid & 1) * 16;

  if (ANORM) {
    for (int c = tid; c < K; c += 256) {
      float s = 0.f, ss = 0.f;
      for (int hh = 0; hh < nchA; hh++) {
        s  += pin[((i64)(b * nchA + hh) * K + c) * 2];
        ss += pin[((i64)(b * nchA + hh) * K + c) * 2 + 1];
      }
      float mu = s * invA;
      mv[c] = mu;
      rv[c] = 1.0f / sqrtf(ss * invA - mu * mu + 1e-5f);
    }
    __syncthreads();
  }

  const float* Ap = A + (i64)(m0 + srow) * lda + skh;
  const float* Wp = W + (i64)(n0 + srow) * ldw + skh;

  auto loadA = [&](int kt, float4* v) {
#pragma unroll
    for (int j = 0; j < 4; j++) {
      if (ACAT) {
        int col0 = kt + skh;
        const float* ap = (col0 < 256)
            ? A  + (i64)(m0 + srow) * 256 + col0
            : A2 + (i64)(m0 + srow) * 256 + (col0 - 256);
        v[j] = *(const float4*)(ap + j * 4);
      } else {
        v[j] = *(const float4*)(Ap + kt + j * 4);
      }
    }
  };
  auto loadW = [&](int kt, float4* v) {
#pragma unroll
    for (int j = 0; j < 4; j++) v[j] = *(const float4*)(Wp + kt + j * 4);
  };

  float4 ar[4], wv4[4];
  loadA(0, ar); loadW(0, wv4);

  f32x4 acc[4][4];
#pragma unroll
  for (int i = 0; i < 4; i++)
#pragma unroll
    for (int j = 0; j < 4; j++)
#pragma unroll
      for (int r = 0; r < 4; r++) acc[i][j][r] = 0.f;

  int koff = lq * 8;
  for (int kt = 0; kt < K; kt += 32) {
    __syncthreads();
#pragma unroll
    for (int j = 0; j < 4; j++) {
      float4 a = ar[j];
      if (ANORM) {
        float4 mu = *(const float4*)&mv[kt + skh + j * 4];
        float4 rs = *(const float4*)&rv[kt + skh + j * 4];
        a.x = lrelu((a.x - mu.x) * rs.x);
        a.y = lrelu((a.y - mu.y) * rs.y);
        a.z = lrelu((a.z - mu.z) * rs.z);
        a.w = lrelu((a.w - mu.w) * rs.w);
      }
      u16 h0, h1, h2, h3, l0, l1, l2, l3;
      splitbf(a.x, h0, l0); splitbf(a.y, h1, l1);
      splitbf(a.z, h2, l2); splitbf(a.w, h3, l3);
      *(ushort4*)&Ah[srow][skh + j * 4] = make_ushort4(h0, h1, h2, h3);
      *(ushort4*)&Al[srow][skh + j * 4] = make_ushort4(l0, l1, l2, l3);
      float4 bb = wv4[j];
      splitbf(bb.x, h0, l0); splitbf(bb.y, h1, l1);
      splitbf(bb.z, h2, l2); splitbf(bb.w, h3, l3);
      *(ushort4*)&Bh[srow][skh + j * 4] = make_ushort4(h0, h1, h2, h3);
      *(ushort4*)&Bl[srow][skh + j * 4] = make_ushort4(l0, l1, l2, l3);
    }
    __syncthreads();
    if (kt + 32 < K) { loadA(kt + 32, ar); loadW(kt + 32, wv4); }
    short8v ah[4], al4[4], bh[4], bl4[4];
#pragma unroll
    for (int i = 0; i < 4; i++) {
      int r = wr * 64 + i * 16 + lc;
      ah[i]  = *(const short8v*)&Ah[r][koff];
      al4[i] = *(const short8v*)&Al[r][koff];
    }
#pragma unroll
    for (int j = 0; j < 4; j++) {
      int r = wc * 64 + j * 16 + lc;
      bh[j]  = *(const short8v*)&Bh[r][koff];
      bl4[j] = *(const short8v*)&Bl[r][koff];
    }
#pragma unroll
    for (int i = 0; i < 4; i++) {
#pragma unroll
      for (int j = 0; j < 4; j++) {
        acc[i][j] = __builtin_amdgcn_mfma_f32_16x16x32_bf16(ah[i], bh[j], acc[i][j], 0, 0, 0);
        acc[i][j] = __builtin_amdgcn_mfma_f32_16x16x32_bf16(al4[i], bh[j], acc[i][j], 0, 0, 0);
        acc[i][j] = __builtin_amdgcn_mfma_f32_16x16x32_bf16(ah[i], bl4[j], acc[i][j], 0, 0, 0);
      }
    }
  }

  float sj[4] = {0.f, 0.f, 0.f, 0.f}, ssj[4] = {0.f, 0.f, 0.f, 0.f};
#pragma unroll
  for (int j = 0; j < 4; j++) {
    int col = n0 + wc * 64 + j * 16 + lc;
    float bv = (mode == 0 && bias) ? bias[col] : 0.f;
#pragma unroll
    for (int i = 0; i < 4; i++) {
      int rbase = m0 + wr * 64 + i * 16 + lq * 4;
#pragma unroll
      for (int r = 0; r < 4; r++) {
        float* cp = &C[(i64)(rbase + r) * ldc + col];
        float v = acc[i][j][r] + ((mode == 0) ? bv : *cp);
        *cp = v;
        if (ESTAT) { sj[j] += v; ssj[j] += v * v; }
      }
    }
  }
  if (ESTAT) {
#pragma unroll
    for (int j = 0; j < 4; j++) {
      sj[j]  += __shfl_xor(sj[j], 16);  sj[j]  += __shfl_xor(sj[j], 32);
      ssj[j] += __shfl_xor(ssj[j], 16); ssj[j] += __shfl_xor(ssj[j], 32);
    }
    __syncthreads();
    if (wr == 0 && lq == 0) {
#pragma unroll
      for (int j = 0; j < 4; j++) {
        int cl = wc * 64 + j * 16 + lc;
        cs[cl][0] = sj[j]; cs[cl][1] = ssj[j];
      }
    }
    __syncthreads();
    if (wr == 1 && lq == 0) {
#pragma unroll
      for (int j = 0; j < 4; j++) {
        int cl = wc * 64 + j * 16 + lc;
        cs[cl][0] += sj[j]; cs[cl][1] += ssj[j];
      }
    }
    __syncthreads();
    if (tid < 128) {
      i64 slot = ((i64)(b * gridDim.x + blockIdx.x) * ncolsTot + n0 + tid) * 2;
      pout[slot] = cs[tid][0];
      pout[slot + 1] = cs[tid][1];
    }
  }
}

// ---- QKV: 3 projections in one launch; grid (16, 2, 6), z = mat*2 + b ------
// mat0: Q = XA@Wq+bq -> Qp [n][256]; mat1/2: K/V = XB@W+b -> head-major
// dst[((c&3)*2048 + n)*64 + (c>>2)]  (c = 4d+h channel index).
__global__ __launch_bounds__(256) void k_qkv(
    const float* __restrict__ XA, const float* __restrict__ XB,
    const float* __restrict__ Wq, const float* __restrict__ Wk,
    const float* __restrict__ Wv,
    const float* __restrict__ bq, const float* __restrict__ bk,
    const float* __restrict__ bv,
    float* __restrict__ Qp, float* __restrict__ Kp, float* __restrict__ Vp) {
  __shared__ __align__(16) u16 Ah[128][40], Al[128][40], Bh[128][40], Bl[128][40];
  int z = blockIdx.z;
  int mat = z >> 1, b = z & 1;
  const float* A = (mat == 0 ? XA : XB) + (i64)b * NSTR;
  const float* W = (mat == 0 ? Wq : (mat == 1 ? Wk : Wv));
  const float* bias = (mat == 0 ? bq : (mat == 1 ? bk : bv));
  float* C = (mat == 0 ? Qp : (mat == 1 ? Kp : Vp)) + (i64)b * NSTR;
  int m0 = blockIdx.x * 128, n0 = blockIdx.y * 128;
  int tid = threadIdx.x;
  int w = tid >> 6, l = tid & 63;
  int wr = w >> 1, wc = w & 1;
  int lc = l & 15, lq = l >> 4;
  int srow = tid >> 1, skh = (tid & 1) * 16;
  const float* Ap = A + (i64)(m0 + srow) * 256 + skh;
  const float* Wp = W + (i64)(n0 + srow) * 256 + skh;
  float4 ar[4], wv4[4];
#pragma unroll
  for (int j = 0; j < 4; j++) { ar[j] = *(const float4*)(Ap + j * 4);
                                wv4[j] = *(const float4*)(Wp + j * 4); }
  f32x4 acc[4][4];
#pragma unroll
  for (int i = 0; i < 4; i++)
#pragma unroll
    for (int j = 0; j < 4; j++)
#pragma unroll
      for (int r = 0; r < 4; r++) acc[i][j][r] = 0.f;
  int koff = lq * 8;
  for (int kt = 0; kt < 256; kt += 32) {
    __syncthreads();
#pragma unroll
    for (int j = 0; j < 4; j++) {
      u16 h0, h1, h2, h3, l0, l1, l2, l3;
      splitbf(ar[j].x, h0, l0); splitbf(ar[j].y, h1, l1);
      splitbf(ar[j].z, h2, l2); splitbf(ar[j].w, h3, l3);
      *(ushort4*)&Ah[srow][skh + j * 4] = make_ushort4(h0, h1, h2, h3);
      *(ushort4*)&Al[srow][skh + j * 4] = make_ushort4(l0, l1, l2, l3);
      splitbf(wv4[j].x, h0, l0); splitbf(wv4[j].y, h1, l1);
      splitbf(wv4[j].z, h2, l2); splitbf(wv4[j].w, h3, l3);
      *(ushort4*)&Bh[srow][skh + j * 4] = make_ushort4(h0, h1, h2, h3);
      *(ushort4*)&Bl[srow][skh + j * 4] = make_ushort4(l0, l1, l2, l3);
    }
    __syncthreads();
    if (kt + 32 < 256) {
#pragma unroll
      for (int j = 0; j < 4; j++) { ar[j] = *(const float4*)(Ap + kt + 32 + j * 4);
                                    wv4[j] = *(const float4*)(Wp + kt + 32 + j * 4); }
    }
    short8v ah[4], al4[4], bh[4], bl4[4];
#pragma unroll
    for (int i = 0; i < 4; i++) {
      int r = wr * 64 + i * 16 + lc;
      ah[i]  = *(const short8v*)&Ah[r][koff];
      al4[i] = *(const short8v*)&Al[r][koff];
    }
#pragma unroll
    for (int j = 0; j < 4; j++) {
      int r = wc * 64 + j * 16 + lc;
      bh[j]  = *(const short8v*)&Bh[r][koff];
      bl4[j] = *(const short8v*)&Bl[r][koff];
    }
#pragma unroll
    for (int i = 0; i < 4; i++)
#pragma unroll
      for (int j = 0; j < 4; j++) {
        acc[i][j] = __builtin_amdgcn_mfma_f32_16x16x32_bf16(ah[i], bh[j], acc[i][j], 0, 0, 0);
        acc[i][j] = __builtin_amdgcn_mfma_f32_16x16x32_bf16(al4[i], bh[j], acc[i][j], 0, 0, 0);
        acc[i][j] = __builtin_amdgcn_mfma_f32_16x16x32_bf16(ah[i], bl4[j], acc[i][j], 0, 0, 0);
      }
  }
#pragma unroll
  for (int j = 0; j < 4; j++) {
    int col = n0 + wc * 64 + j * 16 + lc;
    float bv = bias[col];
#pragma unroll
    for (int i = 0; i < 4; i++) {
      int rbase = m0 + wr * 64 + i * 16 + lq * 4;
#pragma unroll
      for (int r = 0; r < 4; r++) {
        float v = acc[i][j][r] + bv;
        int row = rbase + r;
        if (mat == 0) C[(i64)row * 256 + col] = v;
        else C[((i64)(col & 3) * 2048 + row) * 64 + (col >> 2)] = v;
      }
    }
  }
}

// ---- Y3 = [X | norm(F1) | norm(F2)] @ W3^T, segmented K=1024, + stats ------
// grid (16, 2, B). Norm stats from pA (256 cols) / pB (512 cols), nch=64.
__global__ __launch_bounds__(256) void k_y3(
    const float* __restrict__ X, const float* __restrict__ F1,
    const float* __restrict__ F2, const float* __restrict__ W3,
    float* __restrict__ C,
    const float* __restrict__ pA, const float* __restrict__ pB,
    float* __restrict__ pout) {
  __shared__ __align__(16) u16 Ah[128][40], Al[128][40], Bh[128][40], Bl[128][40];
  __shared__ float mv[1024], rv[1024];
  __shared__ float cs[128][2];
  int b = blockIdx.z;
  X += (i64)b * NSTR; F1 += (i64)b * NSTR; F2 += (i64)b * NSTR2;
  C += (i64)b * NSTR;
  int m0 = blockIdx.x * 128, n0 = blockIdx.y * 128;
  int tid = threadIdx.x;
  int w = tid >> 6, l = tid & 63;
  int wr = w >> 1, wc = w & 1;
  int lc = l & 15, lq = l >> 4;
  int srow = tid >> 1, skh = (tid & 1) * 16;
  for (int c = tid; c < 768; c += 256) {
    int col = 256 + c;
    const float* P; int cols, idx;
    if (col < 512) { P = pA; cols = 256; idx = col - 256; }
    else           { P = pB; cols = 512; idx = col - 512; }
    float s = 0.f, ss = 0.f;
    for (int hh = 0; hh < 64; hh++) {
      s  += P[((i64)(b * 64 + hh) * cols + idx) * 2];
      ss += P[((i64)(b * 64 + hh) * cols + idx) * 2 + 1];
    }
    float mu = s * (1.f / 32768.f);
    mv[col] = mu;
    rv[col] = 1.0f / sqrtf(ss * (1.f / 32768.f) - mu * mu + 1e-5f);
  }
  __syncthreads();
  auto loadA = [&](int kt, float4* v) {
    int col0 = kt + skh;
    const float* ap;
    if (col0 < 256)      ap = X  + (i64)(m0 + srow) * 256 + col0;
    else if (col0 < 512) ap = F1 + (i64)(m0 + srow) * 256 + (col0 - 256);
    else                 ap = F2 + (i64)(m0 + srow) * 512 + (col0 - 512);
#pragma unroll
    for (int j = 0; j < 4; j++) v[j] = *(const float4*)(ap + j * 4);
  };
  const float* Wp = W3 + (i64)(n0 + srow) * 1024 + skh;
  float4 ar[4], wv4[4];
  loadA(0, ar);
#pragma unroll
  for (int j = 0; j < 4; j++) wv4[j] = *(const float4*)(Wp + j * 4);
  f32x4 acc[4][4];
#pragma unroll
  for (int i = 0; i < 4; i++)
#pragma unroll
    for (int j = 0; j < 4; j++)
#pragma unroll
      for (int r = 0; r < 4; r++) acc[i][j][r] = 0.f;
  int koff = lq * 8;
  for (int kt = 0; kt < 1024; kt += 32) {
    __syncthreads();
    int col0 = kt + skh;
#pragma unroll
    for (int j = 0; j < 4; j++) {
      float4 a = ar[j];
      if (col0 >= 256) {
        float4 mu = *(const float4*)&mv[col0 + j * 4];
        float4 rs = *(const float4*)&rv[col0 + j * 4];
        a.x = lrelu((a.x - mu.x) * rs.x);
        a.y = lrelu((a.y - mu.y) * rs.y);
        a.z = lrelu((a.z - mu.z) * rs.z);
        a.w = lrelu((a.w - mu.w) * rs.w);
      }
      u16 h0, h1, h2, h3, l0, l1, l2, l3;
      splitbf(a.x, h0, l0); splitbf(a.y, h1, l1);
      splitbf(a.z, h2, l2); splitbf(a.w, h3, l3);
      *(ushort4*)&Ah[srow][skh + j * 4] = make_ushort4(h0, h1, h2, h3);
      *(ushort4*)&Al[srow][skh + j * 4] = make_ushort4(l0, l1, l2, l3);
      splitbf(wv4[j].x, h0, l0); splitbf(wv4[j].y, h1, l1);
      splitbf(wv4[j].z, h2, l2); splitbf(wv4[j].w, h3, l3);
      *(ushort4*)&Bh[srow][skh + j * 4] = make_ushort4(h0, h1, h2, h3);
      *(ushort4*)&Bl[srow][skh + j * 4] = make_ushort4(l0, l1, l2, l3);
    }
    __syncthreads();
    if (kt + 32 < 1024) {
      loadA(kt + 32, ar);
#pragma unroll
      for (int j = 0; j < 4; j++) wv4[j] = *(const float4*)(Wp + kt + 32 + j * 4);
    }
    short8v ah[4], al4[4], bh[4], bl4[4];
#pragma unroll
    for (int i = 0; i < 4; i++) {
      int r = wr * 64 + i * 16 + lc;
      ah[i]  = *(const short8v*)&Ah[r][koff];
      al4[i] = *(const short8v*)&Al[r][koff];
    }
#pragma unroll
    for (int j = 0; j < 4; j++) {
      int r = wc * 64 + j * 16 + lc;
      bh[j]  = *(const short8v*)&Bh[r][koff];
      bl4[j] = *(const short8v*)&Bl[r][koff];
    }
#pragma unroll
    for (int i = 0; i < 4; i++)
#pragma unroll
      for (int j = 0; j < 4; j++) {
        acc[i][j] = __builtin_amdgcn_mfma_f32_16x16x32_bf16(ah[i], bh[j], acc[i][j], 0, 0, 0);
        acc[i][j] = __builtin_amdgcn_mfma_f32_16x16x32_bf16(al4[i], bh[j], acc[i][j], 0, 0, 0);
        acc[i][j] = __builtin_amdgcn_mfma_f32_16x16x32_bf16(ah[i], bl4[j], acc[i][j], 0, 0, 0);
      }
  }
  float sj[4] = {0.f, 0.f, 0.f, 0.f}, ssj[4] = {0.f, 0.f, 0.f, 0.f};
#pragma unroll
  for (int j = 0; j < 4; j++) {
    int col = n0 + wc * 64 + j * 16 + lc;
#pragma unroll
    for (int i = 0; i < 4; i++) {
      int rbase = m0 + wr * 64 + i * 16 + lq * 4;
#pragma unroll
      for (int r = 0; r < 4; r++) {
        float v = acc[i][j][r];
        C[(i64)(rbase + r) * 256 + col] = v;
        sj[j] += v; ssj[j] += v * v;
      }
    }
  }
#pragma unroll
  for (int j = 0; j < 4; j++) {
    sj[j]  += __shfl_xor(sj[j], 16);  sj[j]  += __shfl_xor(sj[j], 32);
    ssj[j] += __shfl_xor(ssj[j], 16); ssj[j] += __shfl_xor(ssj[j], 32);
  }
  __syncthreads();
  if (wr == 0 && lq == 0) {
#pragma unroll
    for (int j = 0; j < 4; j++) {
      int cl = wc * 64 + j * 16 + lc;
      cs[cl][0] = sj[j]; cs[cl][1] = ssj[j];
    }
  }
  __syncthreads();
  if (wr == 1 && lq == 0) {
#pragma unroll
    for (int j = 0; j < 4; j++) {
      int cl = wc * 64 + j * 16 + lc;
      cs[cl][0] += sj[j]; cs[cl][1] += ssj[j];
    }
  }
  __syncthreads();
  if (tid < 128) {
    i64 slot = ((i64)(b * gridDim.x + blockIdx.x) * 256 + n0 + tid) * 2;
    pout[slot] = cs[tid][0];
    pout[slot + 1] = cs[tid][1];
  }
}

// ---- fused gather: RM[n,o] = P[n,o] + max_k Q[j,o]; partial inorm stats ----
__global__ __launch_bounds__(256) void k_gstat(const float* __restrict__ P,
                                               const float* __restrict__ Q,
                                               int ldpq,
                                               const int* __restrict__ knn,
                                               int O, float* __restrict__ RM,
                                               float* __restrict__ part) {
  int b = blockIdx.z;
  int o = blockIdx.x * 256 + threadIdx.x;
  int n0 = blockIdx.y * 32;
  P += (i64)b * 2048 * ldpq; Q += (i64)b * 2048 * ldpq; RM += (i64)b * 2048 * O;
  knn += ((i64)b * 2048 + n0) * KNB;
  __shared__ int js[32 * KNB];
  for (int i = threadIdx.x; i < 32 * KNB; i += 256) js[i] = knn[i];
  __syncthreads();
  float s = 0.f, ss = 0.f;
  for (int r = 0; r < 32; r++) {
    int n = n0 + r;
    float p = P[(i64)n * ldpq + o];
    float qm = -3.4e38f, qs = 0.f, qss = 0.f;
#pragma unroll
    for (int k = 0; k < KNB; k++) {
      float q = Q[(i64)js[r * KNB + k] * ldpq + o];
      qm = fmaxf(qm, q); qs += q; qss += q * q;
    }
    RM[(i64)n * O + o] = p + qm;
    s  += 16.f * p + qs;
    ss += 16.f * p * p + 2.f * p * qs + qss;
  }
  i64 slot = ((i64)b * 64 + blockIdx.y) * O + o;
  part[slot * 2] = s; part[slot * 2 + 1] = ss;
}

// ---- normalize + act, stats from PART; grid (2048, cols/256, B) ------------
__global__ __launch_bounds__(256) void k_normP(const float* __restrict__ src,
                                               float* __restrict__ dst, int cols,
                                               const float* __restrict__ part,
                                               int nch, float inv, int act) {
  int b = blockIdx.z;
  i64 n = blockIdx.x;
  int c = blockIdx.y * 256 + threadIdx.x;
  float s = 0.f, ss = 0.f;
  for (int h = 0; h < nch; h++) {
    s  += part[((i64)(b * nch + h) * cols + c) * 2];
    ss += part[((i64)(b * nch + h) * cols + c) * 2 + 1];
  }
  float mu = s * inv;
  float rs = 1.0f / sqrtf(ss * inv - mu * mu + 1e-5f);
  i64 off = ((i64)b * 2048 + n) * cols + c;
  float v = (src[off] - mu) * rs;
  dst[off] = (act == 1) ? lrelu(v) : fmaxf(v, 0.f);
}

// ---- flash attention: grid (32 qtiles, 4 heads, B), 256 thr = 4 waves ------
// Q in [n][256] (c=4d+h); K/V head-major [b][h][n][64] -> coalesced float4.
__global__ __launch_bounds__(256) void k_flash(const float* __restrict__ Qp,
                                               const float* __restrict__ Kp,
                                               const float* __restrict__ Vp,
                                               float* __restrict__ Op) {
  __shared__ __align__(16) u16 Kh[64][72], Kl[64][72];
  __shared__ __align__(16) u16 Vh[64][72], Vl[64][72];   // [d][m]
  __shared__ __align__(16) u16 Ph[4][16][72], Pl[4][16][72];
  int qt = blockIdx.x, h = blockIdx.y, b = blockIdx.z;
  const float* Qb = Qp + (i64)b * NSTR;
  const float* Khm = Kp + (i64)b * NSTR + (i64)h * 131072;
  const float* Vhm = Vp + (i64)b * NSTR + (i64)h * 131072;
  int tid = threadIdx.x;
  int w = tid >> 6, l = tid & 63;
  int lc = l & 15, lq = l >> 4;
  short8v qh[2], ql[2];
  int qrow = qt * 64 + w * 16 + lc;
#pragma unroll
  for (int ks = 0; ks < 2; ks++) {
#pragma unroll
    for (int j = 0; j < 8; j++) {
      float v = Qb[(i64)qrow * 256 + 4 * (ks * 32 + lq * 8 + j) + h];
      u16 hh, ll; splitbf(v, hh, ll);
      qh[ks][j] = (short)hh; ql[ks][j] = (short)ll;
    }
  }
  float m_r[4] = {-3.0e38f, -3.0e38f, -3.0e38f, -3.0e38f};
  float l_r[4] = {0.f, 0.f, 0.f, 0.f};
  f32x4 acc[4];
#pragma unroll
  for (int j = 0; j < 4; j++)
#pragma unroll
    for (int r = 0; r < 4; r++) acc[j][r] = 0.f;

  for (int kt = 0; kt < 32; kt++) {
    __syncthreads();
    {
      const float* Kt = Khm + (i64)kt * 4096;
      const float* Vt = Vhm + (i64)kt * 4096;
#pragma unroll
      for (int q = 0; q < 4; q++) {
        int v = q * 256 + tid;
        int m = v >> 4, d4 = (v & 15) * 4;
        u16 h0, h1, h2, h3, l0, l1, l2, l3;
        float4 kf = *(const float4*)(Kt + (i64)v * 4);
        splitbf(kf.x, h0, l0); splitbf(kf.y, h1, l1);
        splitbf(kf.z, h2, l2); splitbf(kf.w, h3, l3);
        *(ushort4*)&Kh[m][d4] = make_ushort4(h0, h1, h2, h3);
        *(ushort4*)&Kl[m][d4] = make_ushort4(l0, l1, l2, l3);
        float4 vf = *(const float4*)(Vt + (i64)v * 4);
        splitbf(vf.x, h0, l0); splitbf(vf.y, h1, l1);
        splitbf(vf.z, h2, l2); splitbf(vf.w, h3, l3);
        Vh[d4 + 0][m] = h0; Vh[d4 + 1][m] = h1;
        Vh[d4 + 2][m] = h2; Vh[d4 + 3][m] = h3;
        Vl[d4 + 0][m] = l0; Vl[d4 + 1][m] = l1;
        Vl[d4 + 2][m] = l2; Vl[d4 + 3][m] = l3;
      }
    }
    __syncthreads();
    f32x4 s[4];
#pragma unroll
    for (int j = 0; j < 4; j++)
#pragma unroll
      for (int r = 0; r < 4; r++) s[j][r] = 0.f;
#pragma unroll
    for (int ks = 0; ks < 2; ks++) {
      int ko = ks * 32 + lq * 8;
#pragma unroll
      for (int j = 0; j < 4; j++) {
        short8v bh = *(const short8v*)&Kh[j * 16 + lc][ko];
        short8v bl = *(const short8v*)&Kl[j * 16 + lc][ko];
        s[j] = __builtin_amdgcn_mfma_f32_16x16x32_bf16(qh[ks], bh, s[j], 0, 0, 0);
        s[j] = __builtin_amdgcn_mfma_f32_16x16x32_bf16(ql[ks], bh, s[j], 0, 0, 0);
        s[j] = __builtin_amdgcn_mfma_f32_16x16x32_bf16(qh[ks], bl, s[j], 0, 0, 0);
      }
    }
#pragma unroll
    for (int j = 0; j < 4; j++)
#pragma unroll
      for (int r = 0; r < 4; r++) s[j][r] *= 0.125f;
    float rmax[4];
#pragma unroll
    for (int r = 0; r < 4; r++)
      rmax[r] = fmaxf(fmaxf(s[0][r], s[1][r]), fmaxf(s[2][r], s[3][r]));
#pragma unroll
    for (int mask = 1; mask < 16; mask <<= 1)
#pragma unroll
      for (int r = 0; r < 4; r++) rmax[r] = fmaxf(rmax[r], __shfl_xor(rmax[r], mask));
    float fs[4], rsum[4];
#pragma unroll
    for (int r = 0; r < 4; r++) {
      float mn = fmaxf(m_r[r], rmax[r]);
      fs[r] = expf(m_r[r] - mn);
      m_r[r] = mn; rsum[r] = 0.f;
    }
#pragma unroll
    for (int j = 0; j < 4; j++)
#pragma unroll
      for (int r = 0; r < 4; r++) {
        float p = expf(s[j][r] - m_r[r]);
        rsum[r] += p;
        u16 hh, ll; splitbf(p, hh, ll);
        Ph[w][lq * 4 + r][j * 16 + lc] = hh;
        Pl[w][lq * 4 + r][j * 16 + lc] = ll;
      }
#pragma unroll
    for (int mask = 1; mask < 16; mask <<= 1)
#pragma unroll
      for (int r = 0; r < 4; r++) rsum[r] += __shfl_xor(rsum[r], mask);
#pragma unroll
    for (int r = 0; r < 4; r++) l_r[r] = l_r[r] * fs[r] + rsum[r];
#pragma unroll
    for (int j = 0; j < 4; j++)
#pragma unroll
      for (int r = 0; r < 4; r++) acc[j][r] *= fs[r];
#pragma unroll
    for (int ks = 0; ks < 2; ks++) {
      int ko = ks * 32 + lq * 8;
      short8v ph = *(const short8v*)&Ph[w][lc][ko];
      short8v pl = *(const short8v*)&Pl[w][lc][ko];
#pragma unroll
      for (int j = 0; j < 4; j++) {
        short8v bh = *(const short8v*)&Vh[j * 16 + lc][ko];
        short8v bl = *(const short8v*)&Vl[j * 16 + lc][ko];
        acc[j] = __builtin_amdgcn_mfma_f32_16x16x32_bf16(ph, bh, acc[j], 0, 0, 0);
        acc[j] = __builtin_amdgcn_mfma_f32_16x16x32_bf16(pl, bh, acc[j], 0, 0, 0);
        acc[j] = __builtin_amdgcn_mfma_f32_16x16x32_bf16(ph, bl, acc[j], 0, 0, 0);
      }
    }
  }
  float* Ob = Op + (i64)b * NSTR;
#pragma unroll
  for (int j = 0; j < 4; j++) {
    int dd = j * 16 + lc;
#pragma unroll
    for (int r = 0; r < 4; r++) {
      int q = qt * 64 + w * 16 + lq * 4 + r;
      Ob[(i64)q * 256 + 4 * dd + h] = acc[j][r] / l_r[r];
    }
  }
}

}  // namespace

// ============================================================================
extern "C" void kernel_launch(void* const* d_in, const int* in_sizes, int n_in,
                              void* d_out, int out_size, void* d_ws, size_t ws_size,
                              hipStream_t stream) {
  float* outp = (float*)d_out;
  auto diag = [&](float v) {
    k_diag<<<dim3((out_size + 255) / 256), dim3(256), 0, stream>>>(outp, out_size, v);
  };

  static const int DSZ[19] = {12288, 1048576, 12288, 1048576, 262144, 524288, 524288,
                              131072, 512, 131072, 512, 131072, 512, 131072, 512,
                              524288, 1024, 262144, 512};
  if (n_in != 19) { diag(1000.f + (float)n_in); return; }
  for (int i = 0; i < 19; i++) {
    if (in_sizes[i] != DSZ[i]) { diag(2000.f + (float)i); return; }
  }
  if (out_size != 2097152) { diag(3000.f); return; }
  constexpr size_t NEED = 50331648;  // 48 MiB
  if (ws_size < NEED) { diag((float)(ws_size >> 20)); return; }

  // -------- workspace map ----------------------------------------------------
  char* w = (char*)d_ws;
  float* SL0 = (float*)(w + 0);
  float* SL1 = (float*)(w + 4 * MB);
  float* SL2 = (float*)(w + 8 * MB);
  int*   KN1 = (int*)(w + 12 * MB);                 // 256 KB
  int*   KN2 = (int*)(w + 12 * MB + 262144);        // 256 KB
  float* PARTA = (float*)(w + 13107200);            // 256 KB
  float* PARTB = (float*)(w + 13369344);            // 512 KB
  float* PARTC = (float*)(w + 13893632);            // 128 KB
  float* UVS   = (float*)(w + 14155776);            // 3 MB (2 layers)
  char* AR = w + 17301504;                          // ~30.5 MB arena

  // gcn overlay
  float* PQ1 = (float*)(AR);                  // [B][2048][512]  8 MB
  float* F1  = (float*)(AR + 8 * MB);         // [B][2048][256]  4 MB
  float* PQ2 = (float*)(AR + 12 * MB);        // [B][2048][1024] 16 MB
  float* F2  = (float*)(AR);                  // [B][2048][512]  8 MB (over PQ1)
  float* Y3  = (float*)(AR + 12 * MB);        // 4 MB (over dead PQ2)
  // attention overlay
  float* Qp = (float*)(AR);                   // 4 MB
  float* Kp = (float*)(AR + 4 * MB);          // 4 MB head-major
  float* Vp = (float*)(AR + 8 * MB);          // 4 MB head-major
  float* Oc = (float*)(AR + 12 * MB);         // 4 MB
  float* Wo_ = (float*)(AR + 16 * MB);        // 4 MB
  float* Hh = (float*)(AR + 20 * MB);         // 8 MB

  const float* W1b = (const float*)d_in[4];
  const float* W2b = (const float*)d_in[5];
  const float* W3b = (const float*)d_in[6];
  const float* Wqb = (const float*)d_in[7];   const float* bqb = (const float*)d_in[8];
  const float* Wkb = (const float*)d_in[9];   const float* bkb = (const float*)d_in[10];
  const float* Wvb = (const float*)d_in[11];  const float* bvb = (const float*)d_in[12];
  const float* Wob = (const float*)d_in[13];  const float* bob = (const float*)d_in[14];
  const float* Wm1b = (const float*)d_in[15]; const float* bm1b = (const float*)d_in[16];
  const float* Wm2b = (const float*)d_in[17]; const float* bm2b = (const float*)d_in[18];

  // -------- setup --------
  k_cvt2<<<dim3(8192), dim3(256), 0, stream>>>((const float*)d_in[1],
                                               (const float*)d_in[3], SL0, SL1);
  k_knnp<<<dim3(NPV / 4, 4), dim3(256), 0, stream>>>((const float*)d_in[0],
                                                     (const float*)d_in[2], KN1, KN2);
  k_wprep<<<dim3(3072), dim3(256), 0, stream>>>(W1b, W2b, UVS);

  // -------- gcn layer --------
  auto gcn = [&](const float* Xc, float* Xn, const int* knnb, int li) {
    const float* UV1 = UVS + (i64)li * 393216;
    const float* UV2 = UVS + (i64)li * 393216 + 131072;
    const float* W3 = W3b + (i64)li * 262144;
    k_gemm<false, false, false><<<dim3(16, 4, 2), dim3(256), 0, stream>>>(
        Xc, 256, NSTR, nullptr, UV1, 256, nullptr, PQ1, 512, NSTR2, 256, 0,
        nullptr, 0, 0.f, nullptr, 0);
    k_gstat<<<dim3(1, 64, BB), dim3(256), 0, stream>>>(PQ1, PQ1 + 256, 512, knnb,
                                                       256, F1, PARTA);
    k_gemm<true, false, false><<<dim3(16, 8, 2), dim3(256), 0, stream>>>(
        F1, 256, NSTR, nullptr, UV2, 256, nullptr, PQ2, 1024, NSTR4, 256, 0,
        PARTA, 64, 1.f / 32768.f, nullptr, 0);
    k_gstat<<<dim3(2, 64, BB), dim3(256), 0, stream>>>(PQ2, PQ2 + 512, 1024, knnb,
                                                       512, F2, PARTB);
    k_y3<<<dim3(16, 2, 2), dim3(256), 0, stream>>>(Xc, F1, F2, W3, Y3,
                                                   PARTA, PARTB, PARTC);
    k_normP<<<dim3(2048, 1, BB), dim3(256), 0, stream>>>(Y3, Xn, 256, PARTC, 16,
                                                         1.f / 2048.f, 1);
  };

  // -------- cross attention --------
  auto attn = [&](const float* XA, const float* XB, float* XO, int li) {
    const float* Wq = Wqb + (i64)li * 65536;   const float* bq = bqb + (i64)li * 256;
    const float* Wk = Wkb + (i64)li * 65536;   const float* bk = bkb + (i64)li * 256;
    const float* Wv = Wvb + (i64)li * 65536;   const float* bv = bvb + (i64)li * 256;
    const float* Wo = Wob + (i64)li * 65536;   const float* bo = bob + (i64)li * 256;
    const float* Wm1 = Wm1b + (i64)li * 262144; const float* bm1 = bm1b + (i64)li * 512;
    const float* Wm2 = Wm2b + (i64)li * 131072; const float* bm2 = bm2b + (i64)li * 256;
    k_qkv<<<dim3(16, 2, 6), dim3(256), 0, stream>>>(XA, XB, Wq, Wk, Wv,
                                                    bq, bk, bv, Qp, Kp, Vp);
    k_flash<<<dim3(32, 4, BB), dim3(256), 0, stream>>>(Qp, Kp, Vp, Oc);
    k_gemm<false, false, false><<<dim3(16, 2, 2), dim3(256), 0, stream>>>(
        Oc, 256, NSTR, nullptr, Wo, 256, bo, Wo_, 256, NSTR, 256, 0,
        nullptr, 0, 0.f, nullptr, 0);
    k_gemm<false, true, true><<<dim3(16, 4, 2), dim3(256), 0, stream>>>(
        XA, 256, NSTR, Wo_, Wm1, 512, bm1, Hh, 512, NSTR2, 512, 0,
        nullptr, 0, 0.f, PARTC, 512);
    k_normP<<<dim3(2048, 2, BB), dim3(256), 0, stream>>>(Hh, Hh, 512, PARTC, 16,
                                                         1.f / 2048.f, 2);
    k_gemm<false, false, false><<<dim3(16, 2, 2), dim3(256), 0, stream>>>(
        Hh, 512, NSTR2, nullptr, Wm2, 512, bm2, XO, 256, NSTR, 512, 0,
        nullptr, 0, 0.f, nullptr, 0);
  };

  // -------- 4 layers --------
  gcn(SL0, SL2, KN1, 0);        // f1.a -> SL2
  gcn(SL1, SL0, KN2, 0);        // f2.a -> SL0
  attn(SL2, SL0, SL1, 0);       // f1.b -> SL1
  attn(SL0, SL1, SL2, 0);       // f2.b -> SL2
  gcn(SL1, SL0, KN1, 1);        // f1.c -> SL0
  gcn(SL2, SL1, KN2, 1);        // f2.c -> SL1
  attn(SL0, SL1, SL2, 1);       // f1.d -> SL2
  attn(SL1, SL2, SL0, 1);       // f2.d -> SL0

  k_final2<<<dim3(8192), dim3(256), 0, stream>>>(SL2, SL0, outp);
}

// Round 6
// 1642.730 us; speedup vs baseline: 59.4674x; 1.1856x over previous
//
#include <hip/hip_runtime.h>

// ============================================================================
// InformationInteractive (gcn, cross_attn, gcn, cross_attn).
// Round 17: launch count 52 -> 36 + counter-driven fixes.
//  - gcn f1/f2 PAIRED (same weights) via z=4; hop2/gstat2 z=2 x2 (PQ2 16MB);
//    F1 parked in d_out (8MB scratch); 2-slot ping-pong (slots adjacent ->
//    z-major strides).
//  - composite Wm1*Wo: Hh = [XA|Oc]@[Wm1a|Wm1b@Wo]^T + (bm1+Wm1b@bo);
//    Wcomb GEMM in setup; Wo GEMM launch eliminated. attn normP folded into
//    Wm2 ANORM(relu). attn = 4 launches.
//  - knn: 32 per-lane distances cached in regs (bit-identical), rounds do
//    compare/select only (was recomputing 544 distances + LDS reads).
//  - LDS stride 40->36 shorts in GEMMs (8-way -> ~4-way bank conflict,
//    SQ_LDS_BANK_CONFLICT 1.05M evidence); flash 72->76.
// ============================================================================

namespace {

constexpr int BB = 2, NPV = 2048, CCH = 256, KNB = 16;
typedef long long i64;
typedef unsigned short u16;
constexpr i64 NSTR  = (i64)NPV * 256;
constexpr i64 NSTR2 = (i64)NPV * 512;
constexpr i64 NSTR4 = (i64)NPV * 1024;
constexpr i64 MB = 1048576;

typedef __attribute__((ext_vector_type(8))) short short8v;   // 8 bf16
typedef __attribute__((ext_vector_type(4))) float f32x4;

__device__ __forceinline__ float lrelu(float v) { return v >= 0.f ? v : 0.2f * v; }

__device__ __forceinline__ void splitbf(float x, u16& h, u16& l) {
  unsigned u = __float_as_uint(x);
  h = (u16)(u >> 16);
  float hf = __uint_as_float(u & 0xffff0000u);
  l = (u16)(__float_as_uint(x - hf) >> 16);
}

// ---- diagnostics ------------------------------------------------------------
__global__ __launch_bounds__(256) void k_diag(float* out, int n, float v) {
  int i = blockIdx.x * 256 + threadIdx.x;
  if (i < n) out[i] = v;
}

// ---- setup: cvt both feats, UV splits, WoT, Wfull-left, bcomb --------------
// grid: 8192 cvt | 3072 UV | 512 WoT | 1024 WfullL | 4 bcomb = 12804 blocks
__global__ __launch_bounds__(256) void k_setup(
    const float* __restrict__ fa, const float* __restrict__ fb,
    float* __restrict__ Xa, float* __restrict__ Xb,
    const float* __restrict__ W1b, const float* __restrict__ W2b,
    float* __restrict__ UVS,
    const float* __restrict__ Wob, float* __restrict__ WoT,
    const float* __restrict__ Wm1b_, float* __restrict__ Wfull,
    const float* __restrict__ bm1b_, const float* __restrict__ bob,
    float* __restrict__ bcomb) {
  int blk = blockIdx.x;
  int t = threadIdx.x;
  if (blk < 8192) {
    int gi = blk * 256 + t;
    bool second = gi >= (1 << 20);
    int idx = gi & ((1 << 20) - 1);
    int b = idx >> 19;
    int n = (idx >> 8) & (NPV - 1);
    int c = idx & (CCH - 1);
    const float* f = second ? fb : fa;
    float* X = second ? Xb : Xa;
    X[idx] = f[((i64)b * CCH + c) * NPV + n];
  } else if (blk < 11264) {
    int i = (blk - 8192) * 256 + t;     // 0..786431
    int li = i / 393216;
    int r0 = i - li * 393216;
    const float* W1 = W1b + (i64)li * 131072;
    const float* W2 = W2b + (i64)li * 262144;
    float* dst = UVS + (i64)li * 393216;
    if (r0 < 131072) {
      int r = r0 >> 8, c = r0 & 255;
      dst[r0] = (r < 256) ? W1[(i64)r * 512 + c] - W1[(i64)r * 512 + 256 + c]
                          : W1[(i64)(r - 256) * 512 + 256 + c];
    } else {
      int j = r0 - 131072;
      int r = j >> 8, c = j & 255;
      dst[131072 + j] = (r < 512) ? W2[(i64)r * 512 + c] - W2[(i64)r * 512 + 256 + c]
                                  : W2[(i64)(r - 512) * 512 + 256 + c];
    }
  } else if (blk < 11776) {
    int i = (blk - 11264) * 256 + t;    // 0..131071: WoT[li][c][k] = Wo[li][k][c]
    int li = i >> 16, rem = i & 65535;
    int c = rem >> 8, k = rem & 255;
    WoT[(i64)li * 65536 + c * 256 + k] = Wob[(i64)li * 65536 + k * 256 + c];
  } else if (blk < 12800) {
    int i = (blk - 11776) * 256 + t;    // 0..262143: Wfull left half
    int li = i >> 17, rem = i & 131071;
    int o = rem >> 8, c = rem & 255;
    Wfull[(i64)li * 262144 + o * 512 + c] = Wm1b_[(i64)li * 262144 + o * 512 + c];
  } else {
    int g = (blk - 12800) * 256 + t;    // 0..1023: bcomb[li][o]
    int li = g >> 9, o = g & 511;
    const float* wm1 = Wm1b_ + (i64)li * 262144 + (i64)o * 512 + 256;
    const float* bo = bob + (i64)li * 256;
    float acc = bm1b_[(i64)li * 512 + o];
    for (int k = 0; k < 256; k++) acc += wm1[k] * bo[k];
    bcomb[(i64)li * 512 + o] = acc;
  }
}

// ---- both X (B,N,C) -> out (B,C,N); grid 8192 -------------------------------
__global__ __launch_bounds__(256) void k_final2(const float* __restrict__ Xa,
                                                const float* __restrict__ Xb,
                                                float* __restrict__ out) {
  int gi = blockIdx.x * 256 + threadIdx.x;
  bool second = gi >= (1 << 20);
  int idx = gi & ((1 << 20) - 1);
  int b = idx >> 19;
  int c = (idx >> 11) & (CCH - 1);
  int n = idx & (NPV - 1);
  const float* X = second ? Xb : Xa;
  out[gi] = X[((i64)b * NPV + n) * CCH + c];
}

// ---- knn: parallel 17-pass watermarked argmin, distances cached in regs ----
__global__ __launch_bounds__(256) void k_knnp(const float* __restrict__ c1,
                                              const float* __restrict__ c2,
                                              int* __restrict__ o1,
                                              int* __restrict__ o2) {
#pragma clang fp contract(off)   // match np mul-then-add distance arithmetic
  __shared__ float4 csq[NPV];
  int set = blockIdx.y >> 1, b = blockIdx.y & 1;
  const float* cb = (set ? c2 : c1) + (i64)b * 3 * NPV;
  int* ob = (set ? o2 : o1) + (i64)b * NPV * KNB;
  for (int m = threadIdx.x; m < NPV; m += 256) {
    float x = cb[m], y = cb[NPV + m], z = cb[2 * NPV + m];
    csq[m] = make_float4(x, y, z, x * x + y * y + z * z);
  }
  __syncthreads();
  int w = threadIdx.x >> 6, lane = threadIdx.x & 63;
  int n = blockIdx.x * 4 + w;
  float4 cn = csq[n];
  float xn = cn.x, yn = cn.y, zn = cn.z, sn = cn.w;
  float dc[32];
#pragma unroll
  for (int t = 0; t < 32; t++) {
    float4 c = csq[t * 64 + lane];
    float dot = xn * c.x + yn * c.y + zn * c.z;
    dc[t] = (sn + c.w) - 2.0f * dot;
  }
  float wd = -3.4e38f; int wm = -1;
  int* o = ob + (i64)n * KNB;
  for (int r = 0; r < KNB + 1; r++) {
    float bd = 3.4e38f; int bm = 0x7fffffff;
#pragma unroll
    for (int t = 0; t < 32; t++) {
      int m = t * 64 + lane;
      float d = dc[t];
      bool valid = (d > wd) || (d == wd && m > wm);
      if (valid && (d < bd || (d == bd && m < bm))) { bd = d; bm = m; }
    }
    for (int mask = 1; mask < 64; mask <<= 1) {
      float od = __shfl_xor(bd, mask);
      int om = __shfl_xor(bm, mask);
      if (od < bd || (od == bd && om < bm)) { bd = od; bm = om; }
    }
    if (r > 0 && lane == 0) o[r - 1] = bm & (NPV - 1);
    wd = bd; wm = bm;
  }
}

// ---- MFMA split-precision GEMM: C[M,N] = A[M,K]@W[N,K]^T (+bias / +=) -------
// BM=128, BN=128, 4 waves. ANORM: inorm+act on A (stats pin, nchA chunks).
// ACAT: A cols 256:511 from A2. ESTAT: per-block col stats -> pout.
template <bool ANORM, bool ACAT, bool ESTAT>
__global__ __launch_bounds__(256) void k_gemm(
    const float* __restrict__ A, int lda, i64 sA,
    const float* __restrict__ A2,
    const float* __restrict__ W, int ldw, i64 sW,
    const float* __restrict__ bias,
    float* __restrict__ C, int ldc, i64 sC,
    int K, int mode, int act,
    const float* __restrict__ pin, int nchA, float invA,
    float* __restrict__ pout, int ncolsTot) {
  __shared__ __align__(16) u16 Ah[128][36], Al[128][36], Bh[128][36], Bl[128][36];
  __shared__ float mv[512], rv[512];
  __shared__ float cs[128][2];
  int b = blockIdx.z;
  A += (i64)b * sA;
  if (ACAT) A2 += (i64)b * NSTR;
  C += (i64)b * sC;
  int m0 = blockIdx.x * 128, n0 = blockIdx.y * 128;
  int tid = threadIdx.x;
  int w = tid >> 6, l = tid & 63;
  int wr = w >> 1, wc = w & 1;
  int lc = l & 15, lq = l >> 4;
  int srow = tid >> 1, skh = (tid & 1) * 16;

  if (ANORM) {
    for (int c = tid; c < K; c += 256) {
      float s = 0.f, ss = 0.f;
      for (int hh = 0; hh < nchA; hh++) {
        s  += pin[((i64)(b * nchA + hh) * K + c) * 2];
        ss += pin[((i64)(b * nchA + hh) * K + c) * 2 + 1];
      }
      float mu = s * invA;
      mv[c] = mu;
      rv[c] = 1.0f / sqrtf(ss * invA - mu * mu + 1e-5f);
    }
    __syncthreads();
  }

  const float* Ap = A + (i64)(m0 + srow) * lda + skh;
  const float* Wp = W + (i64)b * sW + (i64)(n0 + srow) * ldw + skh;

  auto loadA = [&](int kt, float4* v) {
#pragma unroll
    for (int j = 0; j < 4; j++) {
      if (ACAT) {
        int col0 = kt + skh;
        const float* ap = (col0 < 256)
            ? A  + (i64)(m0 + srow) * 256 + col0
            : A2 + (i64)(m0 + srow) * 256 + (col0 - 256);
        v[j] = *(const float4*)(ap + j * 4);
      } else {
        v[j] = *(const float4*)(Ap + kt + j * 4);
      }
    }
  };
  auto loadW = [&](int kt, float4* v) {
#pragma unroll
    for (int j = 0; j < 4; j++) v[j] = *(const float4*)(Wp + kt + j * 4);
  };

  float4 ar[4], wv4[4];
  loadA(0, ar); loadW(0, wv4);

  f32x4 acc[4][4];
#pragma unroll
  for (int i = 0; i < 4; i++)
#pragma unroll
    for (int j = 0; j < 4; j++)
#pragma unroll
      for (int r = 0; r < 4; r++) acc[i][j][r] = 0.f;

  int koff = lq * 8;
  for (int kt = 0; kt < K; kt += 32) {
    __syncthreads();
#pragma unroll
    for (int j = 0; j < 4; j++) {
      float4 a = ar[j];
      if (ANORM) {
        float4 mu = *(const float4*)&mv[kt + skh + j * 4];
        float4 rs = *(const float4*)&rv[kt + skh + j * 4];
        a.x = (a.x - mu.x) * rs.x; a.y = (a.y - mu.y) * rs.y;
        a.z = (a.z - mu.z) * rs.z; a.w = (a.w - mu.w) * rs.w;
        if (act == 1) { a.x = lrelu(a.x); a.y = lrelu(a.y);
                        a.z = lrelu(a.z); a.w = lrelu(a.w); }
        else { a.x = fmaxf(a.x, 0.f); a.y = fmaxf(a.y, 0.f);
               a.z = fmaxf(a.z, 0.f); a.w = fmaxf(a.w, 0.f); }
      }
      u16 h0, h1, h2, h3, l0, l1, l2, l3;
      splitbf(a.x, h0, l0); splitbf(a.y, h1, l1);
      splitbf(a.z, h2, l2); splitbf(a.w, h3, l3);
      *(ushort4*)&Ah[srow][skh + j * 4] = make_ushort4(h0, h1, h2, h3);
      *(ushort4*)&Al[srow][skh + j * 4] = make_ushort4(l0, l1, l2, l3);
      float4 bb = wv4[j];
      splitbf(bb.x, h0, l0); splitbf(bb.y, h1, l1);
      splitbf(bb.z, h2, l2); splitbf(bb.w, h3, l3);
      *(ushort4*)&Bh[srow][skh + j * 4] = make_ushort4(h0, h1, h2, h3);
      *(ushort4*)&Bl[srow][skh + j * 4] = make_ushort4(l0, l1, l2, l3);
    }
    __syncthreads();
    if (kt + 32 < K) { loadA(kt + 32, ar); loadW(kt + 32, wv4); }
    short8v ah[4], al4[4], bh[4], bl4[4];
#pragma unroll
    for (int i = 0; i < 4; i++) {
      int r = wr * 64 + i * 16 + lc;
      ah[i]  = *(const short8v*)&Ah[r][koff];
      al4[i] = *(const short8v*)&Al[r][koff];
    }
#pragma unroll
    for (int j = 0; j < 4; j++) {
      int r = wc * 64 + j * 16 + lc;
      bh[j]  = *(const short8v*)&Bh[r][koff];
      bl4[j] = *(const short8v*)&Bl[r][koff];
    }
#pragma unroll
    for (int i = 0; i < 4; i++) {
#pragma unroll
      for (int j = 0; j < 4; j++) {
        acc[i][j] = __builtin_amdgcn_mfma_f32_16x16x32_bf16(ah[i], bh[j], acc[i][j], 0, 0, 0);
        acc[i][j] = __builtin_amdgcn_mfma_f32_16x16x32_bf16(al4[i], bh[j], acc[i][j], 0, 0, 0);
        acc[i][j] = __builtin_amdgcn_mfma_f32_16x16x32_bf16(ah[i], bl4[j], acc[i][j], 0, 0, 0);
      }
    }
  }

  float sj[4] = {0.f, 0.f, 0.f, 0.f}, ssj[4] = {0.f, 0.f, 0.f, 0.f};
#pragma unroll
  for (int j = 0; j < 4; j++) {
    int col = n0 + wc * 64 + j * 16 + lc;
    float bv = (mode == 0 && bias) ? bias[col] : 0.f;
#pragma unroll
    for (int i = 0; i < 4; i++) {
      int rbase = m0 + wr * 64 + i * 16 + lq * 4;
#pragma unroll
      for (int r = 0; r < 4; r++) {
        float* cp = &C[(i64)(rbase + r) * ldc + col];
        float v = acc[i][j][r] + ((mode == 0) ? bv : *cp);
        *cp = v;
        if (ESTAT) { sj[j] += v; ssj[j] += v * v; }
      }
    }
  }
  if (ESTAT) {
#pragma unroll
    for (int j = 0; j < 4; j++) {
      sj[j]  += __shfl_xor(sj[j], 16);  sj[j]  += __shfl_xor(sj[j], 32);
      ssj[j] += __shfl_xor(ssj[j], 16); ssj[j] += __shfl_xor(ssj[j], 32);
    }
    __syncthreads();
    if (wr == 0 && lq == 0) {
#pragma unroll
      for (int j = 0; j < 4; j++) {
        int cl = wc * 64 + j * 16 + lc;
        cs[cl][0] = sj[j]; cs[cl][1] = ssj[j];
      }
    }
    __syncthreads();
    if (wr == 1 && lq == 0) {
#pragma unroll
      for (int j = 0; j < 4; j++) {
        int cl = wc * 64 + j * 16 + lc;
        cs[cl][0] += sj[j]; cs[cl][1] += ssj[j];
      }
    }
    __syncthreads();
    if (tid < 128) {
      i64 slot = ((i64)(b * gridDim.x + blockIdx.x) * ncolsTot + n0 + tid) * 2;
      pout[slot] = cs[tid][0];
      pout[slot + 1] = cs[tid][1];
    }
  }
}

// ---- QKV: grid (16, 2, 6), z = mat*2 + b; K/V -> head-major ----------------
__global__ __launch_bounds__(256) void k_qkv(
    const float* __restrict__ XA, const float* __restrict__ XB,
    const float* __restrict__ Wq, const float* __restrict__ Wk,
    const float* __restrict__ Wv,
    const float* __restrict__ bq, const float* __restrict__ bk,
    const float* __restrict__ bv,
    float* __restrict__ Qp, float* __restrict__ Kp, float* __restrict__ Vp) {
  __shared__ __align__(16) u16 Ah[128][36], Al[128][36], Bh[128][36], Bl[128][36];
  int z = blockIdx.z;
  int mat = z >> 1, b = z & 1;
  const float* A = (mat == 0 ? XA : XB) + (i64)b * NSTR;
  const float* W = (mat == 0 ? Wq : (mat == 1 ? Wk : Wv));
  const float* bias = (mat == 0 ? bq : (mat == 1 ? bk : bv));
  float* C = (mat == 0 ? Qp : (mat == 1 ? Kp : Vp)) + (i64)b * NSTR;
  int m0 = blockIdx.x * 128, n0 = blockIdx.y * 128;
  int tid = threadIdx.x;
  int w = tid >> 6, l = tid & 63;
  int wr = w >> 1, wc = w & 1;
  int lc = l & 15, lq = l >> 4;
  int srow = tid >> 1, skh = (tid & 1) * 16;
  const float* Ap = A + (i64)(m0 + srow) * 256 + skh;
  const float* Wp = W + (i64)(n0 + srow) * 256 + skh;
  float4 ar[4], wv4[4];
#pragma unroll
  for (int j = 0; j < 4; j++) { ar[j] = *(const float4*)(Ap + j * 4);
                                wv4[j] = *(const float4*)(Wp + j * 4); }
  f32x4 acc[4][4];
#pragma unroll
  for (int i = 0; i < 4; i++)
#pragma unroll
    for (int j = 0; j < 4; j++)
#pragma unroll
      for (int r = 0; r < 4; r++) acc[i][j][r] = 0.f;
  int koff = lq * 8;
  for (int kt = 0; kt < 256; kt += 32) {
    __syncthreads();
#pragma unroll
    for (int j = 0; j < 4; j++) {
      u16 h0, h1, h2, h3, l0, l1, l2, l3;
      splitbf(ar[j].x, h0, l0); splitbf(ar[j].y, h1, l1);
      splitbf(ar[j].z, h2, l2); splitbf(ar[j].w, h3, l3);
      *(ushort4*)&Ah[srow][skh + j * 4] = make_ushort4(h0, h1, h2, h3);
      *(ushort4*)&Al[srow][skh + j * 4] = make_ushort4(l0, l1, l2, l3);
      splitbf(wv4[j].x, h0, l0); splitbf(wv4[j].y, h1, l1);
      splitbf(wv4[j].z, h2, l2); splitbf(wv4[j].w, h3, l3);
      *(ushort4*)&Bh[srow][skh + j * 4] = make_ushort4(h0, h1, h2, h3);
      *(ushort4*)&Bl[srow][skh + j * 4] = make_ushort4(l0, l1, l2, l3);
    }
    __syncthreads();
    if (kt + 32 < 256) {
#pragma unroll
      for (int j = 0; j < 4; j++) { ar[j] = *(const float4*)(Ap + kt + 32 + j * 4);
                                    wv4[j] = *(const float4*)(Wp + kt + 32 + j * 4); }
    }
    short8v ah[4], al4[4], bh[4], bl4[4];
#pragma unroll
    for (int i = 0; i < 4; i++) {
      int r = wr * 64 + i * 16 + lc;
      ah[i]  = *(const short8v*)&Ah[r][koff];
      al4[i] = *(const short8v*)&Al[r][koff];
    }
#pragma unroll
    for (int j = 0; j < 4; j++) {
      int r = wc * 64 + j * 16 + lc;
      bh[j]  = *(const short8v*)&Bh[r][koff];
      bl4[j] = *(const short8v*)&Bl[r][koff];
    }
#pragma unroll
    for (int i = 0; i < 4; i++)
#pragma unroll
      for (int j = 0; j < 4; j++) {
        acc[i][j] = __builtin_amdgcn_mfma_f32_16x16x32_bf16(ah[i], bh[j], acc[i][j], 0, 0, 0);
        acc[i][j] = __builtin_amdgcn_mfma_f32_16x16x32_bf16(al4[i], bh[j], acc[i][j], 0, 0, 0);
        acc[i][j] = __builtin_amdgcn_mfma_f32_16x16x32_bf16(ah[i], bl4[j], acc[i][j], 0, 0, 0);
      }
  }
#pragma unroll
  for (int j = 0; j < 4; j++) {
    int col = n0 + wc * 64 + j * 16 + lc;
    float bv = bias[col];
#pragma unroll
    for (int i = 0; i < 4; i++) {
      int rbase = m0 + wr * 64 + i * 16 + lq * 4;
#pragma unroll
      for (int r = 0; r < 4; r++) {
        float v = acc[i][j][r] + bv;
        int row = rbase + r;
        if (mat == 0) C[(i64)row * 256 + col] = v;
        else C[((i64)(col & 3) * 2048 + row) * 64 + (col >> 2)] = v;
      }
    }
  }
}

// ---- Y3 = [X | norm(F1) | norm(F2)] @ W3^T, z=4 paired, + stats -------------
__global__ __launch_bounds__(256) void k_y3(
    const float* __restrict__ Xbase, const float* __restrict__ F1b,
    const float* __restrict__ F2b, const float* __restrict__ W3b,
    float* __restrict__ Cb,
    const float* __restrict__ pA, const float* __restrict__ pB,
    float* __restrict__ pout, int li) {
  __shared__ __align__(16) u16 Ah[128][36], Al[128][36], Bh[128][36], Bl[128][36];
  __shared__ float mv[1024], rv[1024];
  __shared__ float cs[128][2];
  int z = blockIdx.z;
  const float* X = Xbase + (i64)z * NSTR;
  const float* F1 = F1b + (i64)z * NSTR;
  const float* F2 = F2b + (i64)z * NSTR2;
  const float* W3 = W3b + (i64)li * 262144;
  float* C = Cb + (i64)z * NSTR;
  int m0 = blockIdx.x * 128, n0 = blockIdx.y * 128;
  int tid = threadIdx.x;
  int w = tid >> 6, l = tid & 63;
  int wr = w >> 1, wc = w & 1;
  int lc = l & 15, lq = l >> 4;
  int srow = tid >> 1, skh = (tid & 1) * 16;
  for (int c = tid; c < 768; c += 256) {
    int col = 256 + c;
    const float* P; int cols, idx;
    if (col < 512) { P = pA; cols = 256; idx = col - 256; }
    else           { P = pB; cols = 512; idx = col - 512; }
    float s = 0.f, ss = 0.f;
    for (int hh = 0; hh < 64; hh++) {
      s  += P[((i64)(z * 64 + hh) * cols + idx) * 2];
      ss += P[((i64)(z * 64 + hh) * cols + idx) * 2 + 1];
    }
    float mu = s * (1.f / 32768.f);
    mv[col] = mu;
    rv[col] = 1.0f / sqrtf(ss * (1.f / 32768.f) - mu * mu + 1e-5f);
  }
  __syncthreads();
  auto loadA = [&](int kt, float4* v) {
    int col0 = kt + skh;
    const float* ap;
    if (col0 < 256)      ap = X  + (i64)(m0 + srow) * 256 + col0;
    else if (col0 < 512) ap = F1 + (i64)(m0 + srow) * 256 + (col0 - 256);
    else                 ap = F2 + (i64)(m0 + srow) * 512 + (col0 - 512);
#pragma unroll
    for (int j = 0; j < 4; j++) v[j] = *(const float4*)(ap + j * 4);
  };
  const float* Wp = W3 + (i64)(n0 + srow) * 1024 + skh;
  float4 ar[4], wv4[4];
  loadA(0, ar);
#pragma unroll
  for (int j = 0; j < 4; j++) wv4[j] = *(const float4*)(Wp + j * 4);
  f32x4 acc[4][4];
#pragma unroll
  for (int i = 0; i < 4; i++)
#pragma unroll
    for (int j = 0; j < 4; j++)
#pragma unroll
      for (int r = 0; r < 4; r++) acc[i][j][r] = 0.f;
  int koff = lq * 8;
  for (int kt = 0; kt < 1024; kt += 32) {
    __syncthreads();
    int col0 = kt + skh;
#pragma unroll
    for (int j = 0; j < 4; j++) {
      float4 a = ar[j];
      if (col0 >= 256) {
        float4 mu = *(const float4*)&mv[col0 + j * 4];
        float4 rs = *(const float4*)&rv[col0 + j * 4];
        a.x = lrelu((a.x - mu.x) * rs.x);
        a.y = lrelu((a.y - mu.y) * rs.y);
        a.z = lrelu((a.z - mu.z) * rs.z);
        a.w = lrelu((a.w - mu.w) * rs.w);
      }
      u16 h0, h1, h2, h3, l0, l1, l2, l3;
      splitbf(a.x, h0, l0); splitbf(a.y, h1, l1);
      splitbf(a.z, h2, l2); splitbf(a.w, h3, l3);
      *(ushort4*)&Ah[srow][skh + j * 4] = make_ushort4(h0, h1, h2, h3);
      *(ushort4*)&Al[srow][skh + j * 4] = make_ushort4(l0, l1, l2, l3);
      splitbf(wv4[j].x, h0, l0); splitbf(wv4[j].y, h1, l1);
      splitbf(wv4[j].z, h2, l2); splitbf(wv4[j].w, h3, l3);
      *(ushort4*)&Bh[srow][skh + j * 4] = make_ushort4(h0, h1, h2, h3);
      *(ushort4*)&Bl[srow][skh + j * 4] = make_ushort4(l0, l1, l2, l3);
    }
    __syncthreads();
    if (kt + 32 < 1024) {
      loadA(kt + 32, ar);
#pragma unroll
      for (int j = 0; j < 4; j++) wv4[j] = *(const float4*)(Wp + kt + 32 + j * 4);
    }
    short8v ah[4], al4[4], bh[4], bl4[4];
#pragma unroll
    for (int i = 0; i < 4; i++) {
      int r = wr * 64 + i * 16 + lc;
      ah[i]  = *(const short8v*)&Ah[r][koff];
      al4[i] = *(const short8v*)&Al[r][koff];
    }
#pragma unroll
    for (int j = 0; j < 4; j++) {
      int r = wc * 64 + j * 16 + lc;
      bh[j]  = *(const short8v*)&Bh[r][koff];
      bl4[j] = *(const short8v*)&Bl[r][koff];
    }
#pragma unroll
    for (int i = 0; i < 4; i++)
#pragma unroll
      for (int j = 0; j < 4; j++) {
        acc[i][j] = __builtin_amdgcn_mfma_f32_16x16x32_bf16(ah[i], bh[j], acc[i][j], 0, 0, 0);
        acc[i][j] = __builtin_amdgcn_mfma_f32_16x16x32_bf16(al4[i], bh[j], acc[i][j], 0, 0, 0);
        acc[i][j] = __builtin_amdgcn_mfma_f32_16x16x32_bf16(ah[i], bl4[j], acc[i][j], 0, 0, 0);
      }
  }
  float sj[4] = {0.f, 0.f, 0.f, 0.f}, ssj[4] = {0.f, 0.f, 0.f, 0.f};
#pragma unroll
  for (int j = 0; j < 4; j++) {
    int col = n0 + wc * 64 + j * 16 + lc;
#pragma unroll
    for (int i = 0; i < 4; i++) {
      int rbase = m0 + wr * 64 + i * 16 + lq * 4;
#pragma unroll
      for (int r = 0; r < 4; r++) {
        float v = acc[i][j][r];
        C[(i64)(rbase + r) * 256 + col] = v;
        sj[j] += v; ssj[j] += v * v;
      }
    }
  }
#pragma unroll
  for (int j = 0; j < 4; j++) {
    sj[j]  += __shfl_xor(sj[j], 16);  sj[j]  += __shfl_xor(sj[j], 32);
    ssj[j] += __shfl_xor(ssj[j], 16); ssj[j] += __shfl_xor(ssj[j], 32);
  }
  __syncthreads();
  if (wr == 0 && lq == 0) {
#pragma unroll
    for (int j = 0; j < 4; j++) {
      int cl = wc * 64 + j * 16 + lc;
      cs[cl][0] = sj[j]; cs[cl][1] = ssj[j];
    }
  }
  __syncthreads();
  if (wr == 1 && lq == 0) {
#pragma unroll
    for (int j = 0; j < 4; j++) {
      int cl = wc * 64 + j * 16 + lc;
      cs[cl][0] += sj[j]; cs[cl][1] += ssj[j];
    }
  }
  __syncthreads();
  if (tid < 128) {
    i64 slot = ((i64)(z * 16 + blockIdx.x) * 256 + n0 + tid) * 2;
    pout[slot] = cs[tid][0];
    pout[slot + 1] = cs[tid][1];
  }
}

// ---- fused gather: RM = P + max_k Q[j]; partial stats. z-major --------------
__global__ __launch_bounds__(256) void k_gstat(const float* __restrict__ P,
                                               const float* __restrict__ Q,
                                               int ldpq,
                                               const int* __restrict__ knn,
                                               int O, float* __restrict__ RM,
                                               float* __restrict__ part) {
  int b = blockIdx.z;
  int o = blockIdx.x * 256 + threadIdx.x;
  int n0 = blockIdx.y * 32;
  P += (i64)b * 2048 * ldpq; Q += (i64)b * 2048 * ldpq; RM += (i64)b * 2048 * O;
  knn += ((i64)b * 2048 + n0) * KNB;
  __shared__ int js[32 * KNB];
  for (int i = threadIdx.x; i < 32 * KNB; i += 256) js[i] = knn[i];
  __syncthreads();
  float s = 0.f, ss = 0.f;
  for (int r = 0; r < 32; r++) {
    int n = n0 + r;
    float p = P[(i64)n * ldpq + o];
    float qm = -3.4e38f, qs = 0.f, qss = 0.f;
#pragma unroll
    for (int k = 0; k < KNB; k++) {
      float q = Q[(i64)js[r * KNB + k] * ldpq + o];
      qm = fmaxf(qm, q); qs += q; qss += q * q;
    }
    RM[(i64)n * O + o] = p + qm;
    s  += 16.f * p + qs;
    ss += 16.f * p * p + 2.f * p * qs + qss;
  }
  i64 slot = ((i64)b * 64 + blockIdx.y) * O + o;
  part[slot * 2] = s; part[slot * 2 + 1] = ss;
}

// ---- normalize + act, stats from PART; z-major dst --------------------------
__global__ __launch_bounds__(256) void k_normP(const float* __restrict__ src,
                                               float* __restrict__ dst, int cols,
                                               const float* __restrict__ part,
                                               int nch, float inv, int act) {
  int b = blockIdx.z;
  i64 n = blockIdx.x;
  int c = blockIdx.y * 256 + threadIdx.x;
  float s = 0.f, ss = 0.f;
  for (int h = 0; h < nch; h++) {
    s  += part[((i64)(b * nch + h) * cols + c) * 2];
    ss += part[((i64)(b * nch + h) * cols + c) * 2 + 1];
  }
  float mu = s * inv;
  float rs = 1.0f / sqrtf(ss * inv - mu * mu + 1e-5f);
  i64 off = ((i64)b * 2048 + n) * cols + c;
  float v = (src[off] - mu) * rs;
  dst[off] = (act == 1) ? lrelu(v) : fmaxf(v, 0.f);
}

// ---- flash attention: grid (32, 4, B) ---------------------------------------
__global__ __launch_bounds__(256) void k_flash(const float* __restrict__ Qp,
                                               const float* __restrict__ Kp,
                                               const float* __restrict__ Vp,
                                               float* __restrict__ Op) {
  __shared__ __align__(16) u16 Kh[64][76], Kl[64][76];
  __shared__ __align__(16) u16 Vh[64][76], Vl[64][76];   // [d][m]
  __shared__ __align__(16) u16 Ph[4][16][76], Pl[4][16][76];
  int qt = blockIdx.x, h = blockIdx.y, b = blockIdx.z;
  const float* Qb = Qp + (i64)b * NSTR;
  const float* Khm = Kp + (i64)b * NSTR + (i64)h * 131072;
  const float* Vhm = Vp + (i64)b * NSTR + (i64)h * 131072;
  int tid = threadIdx.x;
  int w = tid >> 6, l = tid & 63;
  int lc = l & 15, lq = l >> 4;
  short8v qh[2], ql[2];
  int qrow = qt * 64 + w * 16 + lc;
#pragma unroll
  for (int ks = 0; ks < 2; ks++) {
#pragma unroll
    for (int j = 0; j < 8; j++) {
      float v = Qb[(i64)qrow * 256 + 4 * (ks * 32 + lq * 8 + j) + h];
      u16 hh, ll; splitbf(v, hh, ll);
      qh[ks][j] = (short)hh; ql[ks][j] = (short)ll;
    }
  }
  float m_r[4] = {-3.0e38f, -3.0e38f, -3.0e38f, -3.0e38f};
  float l_r[4] = {0.f, 0.f, 0.f, 0.f};
  f32x4 acc[4];
#pragma unroll
  for (int j = 0; j < 4; j++)
#pragma unroll
    for (int r = 0; r < 4; r++) acc[j][r] = 0.f;

  for (int kt = 0; kt < 32; kt++) {
    __syncthreads();
    {
      const float* Kt = Khm + (i64)kt * 4096;
      const float* Vt = Vhm + (i64)kt * 4096;
#pragma unroll
      for (int q = 0; q < 4; q++) {
        int v = q * 256 + tid;
        int m = v >> 4, d4 = (v & 15) * 4;
        u16 h0, h1, h2, h3, l0, l1, l2, l3;
        float4 kf = *(const float4*)(Kt + (i64)v * 4);
        splitbf(kf.x, h0, l0); splitbf(kf.y, h1, l1);
        splitbf(kf.z, h2, l2); splitbf(kf.w, h3, l3);
        *(ushort4*)&Kh[m][d4] = make_ushort4(h0, h1, h2, h3);
        *(ushort4*)&Kl[m][d4] = make_ushort4(l0, l1, l2, l3);
        float4 vf = *(const float4*)(Vt + (i64)v * 4);
        splitbf(vf.x, h0, l0); splitbf(vf.y, h1, l1);
        splitbf(vf.z, h2, l2); splitbf(vf.w, h3, l3);
        Vh[d4 + 0][m] = h0; Vh[d4 + 1][m] = h1;
        Vh[d4 + 2][m] = h2; Vh[d4 + 3][m] = h3;
        Vl[d4 + 0][m] = l0; Vl[d4 + 1][m] = l1;
        Vl[d4 + 2][m] = l2; Vl[d4 + 3][m] = l3;
      }
    }
    __syncthreads();
    f32x4 s[4];
#pragma unroll
    for (int j = 0; j < 4; j++)
#pragma unroll
      for (int r = 0; r < 4; r++) s[j][r] = 0.f;
#pragma unroll
    for (int ks = 0; ks < 2; ks++) {
      int ko = ks * 32 + lq * 8;
#pragma unroll
      for (int j = 0; j < 4; j++) {
        short8v bh = *(const short8v*)&Kh[j * 16 + lc][ko];
        short8v bl = *(const short8v*)&Kl[j * 16 + lc][ko];
        s[j] = __builtin_amdgcn_mfma_f32_16x16x32_bf16(qh[ks], bh, s[j], 0, 0, 0);
        s[j] = __builtin_amdgcn_mfma_f32_16x16x32_bf16(ql[ks], bh, s[j], 0, 0, 0);
        s[j] = __builtin_amdgcn_mfma_f32_16x16x32_bf16(qh[ks], bl, s[j], 0, 0, 0);
      }
    }
#pragma unroll
    for (int j = 0; j < 4; j++)
#pragma unroll
      for (int r = 0; r < 4; r++) s[j][r] *= 0.125f;
    float rmax[4];
#pragma unroll
    for (int r = 0; r < 4; r++)
      rmax[r] = fmaxf(fmaxf(s[0][r], s[1][r]), fmaxf(s[2][r], s[3][r]));
#pragma unroll
    for (int mask = 1; mask < 16; mask <<= 1)
#pragma unroll
      for (int r = 0; r < 4; r++) rmax[r] = fmaxf(rmax[r], __shfl_xor(rmax[r], mask));
    float fs[4], rsum[4];
#pragma unroll
    for (int r = 0; r < 4; r++) {
      float mn = fmaxf(m_r[r], rmax[r]);
      fs[r] = expf(m_r[r] - mn);
      m_r[r] = mn; rsum[r] = 0.f;
    }
#pragma unroll
    for (int j = 0; j < 4; j++)
#pragma unroll
      for (int r = 0; r < 4; r++) {
        float p = expf(s[j][r] - m_r[r]);
        rsum[r] += p;
        u16 hh, ll; splitbf(p, hh, ll);
        Ph[w][lq * 4 + r][j * 16 + lc] = hh;
        Pl[w][lq * 4 + r][j * 16 + lc] = ll;
      }
#pragma unroll
    for (int mask = 1; mask < 16; mask <<= 1)
#pragma unroll
      for (int r = 0; r < 4; r++) rsum[r] += __shfl_xor(rsum[r], mask);
#pragma unroll
    for (int r = 0; r < 4; r++) l_r[r] = l_r[r] * fs[r] + rsum[r];
#pragma unroll
    for (int j = 0; j < 4; j++)
#pragma unroll
      for (int r = 0; r < 4; r++) acc[j][r] *= fs[r];
#pragma unroll
    for (int ks = 0; ks < 2; ks++) {
      int ko = ks * 32 + lq * 8;
      short8v ph = *(const short8v*)&Ph[w][lc][ko];
      short8v pl = *(const short8v*)&Pl[w][lc][ko];
#pragma unroll
      for (int j = 0; j < 4; j++) {
        short8v bh = *(const short8v*)&Vh[j * 16 + lc][ko];
        short8v bl = *(const short8v*)&Vl[j * 16 + lc][ko];
        acc[j] = __builtin_amdgcn_mfma_f32_16x16x32_bf16(ph, bh, acc[j], 0, 0, 0);
        acc[j] = __builtin_amdgcn_mfma_f32_16x16x32_bf16(pl, bh, acc[j], 0, 0, 0);
        acc[j] = __builtin_amdgcn_mfma_f32_16x16x32_bf16(ph, bl, acc[j], 0, 0, 0);
      }
    }
  }
  float* Ob = Op + (i64)b * NSTR;
#pragma unroll
  for (int j = 0; j < 4; j++) {
    int dd = j * 16 + lc;
#pragma unroll
    for (int r = 0; r < 4; r++) {
      int q = qt * 64 + w * 16 + lq * 4 + r;
      Ob[(i64)q * 256 + 4 * dd + h] = acc[j][r] / l_r[r];
    }
  }
}

}  // namespace

// ============================================================================
extern "C" void kernel_launch(void* const* d_in, const int* in_sizes, int n_in,
                              void* d_out, int out_size, void* d_ws, size_t ws_size,
                              hipStream_t stream) {
  float* outp = (float*)d_out;
  auto diag = [&](float v) {
    k_diag<<<dim3((out_size + 255) / 256), dim3(256), 0, stream>>>(outp, out_size, v);
  };

  static const int DSZ[19] = {12288, 1048576, 12288, 1048576, 262144, 524288, 524288,
                              131072, 512, 131072, 512, 131072, 512, 131072, 512,
                              524288, 1024, 262144, 512};
  if (n_in != 19) { diag(1000.f + (float)n_in); return; }
  for (int i = 0; i < 19; i++) {
    if (in_sizes[i] != DSZ[i]) { diag(2000.f + (float)i); return; }
  }
  if (out_size != 2097152) { diag(3000.f); return; }
  constexpr size_t NEED = 50331648;  // 48 MiB
  if (ws_size < NEED) { diag((float)(ws_size >> 20)); return; }

  // -------- workspace map ----------------------------------------------------
  char* w = (char*)d_ws;
  float* S0 = (float*)(w + 0);                  // [2][2048][256] 4 MB (f1)
  float* S1 = (float*)(w + 4 * MB);             // 4 MB (f2) -- adjacent: z-major
  int*   KN1 = (int*)(w + 8 * MB);              // 256 KB ([4] z-major w/ KN2)
  int*   KN2 = (int*)(w + 8 * MB + 262144);     // 256 KB
  float* PARTA = (float*)(w + 8912896);         // [4][64][256][2] 512 KB
  float* PARTB = (float*)(w + 9437184);         // [4][64][512][2] 1 MB
  float* PARTCg = (float*)(w + 10485760);       // [4][16][256][2] 128 KB
  float* PARTCa = (float*)(w + 10616832);       // [2][16][512][2] 128 KB
  float* BCOMB = (float*)(w + 10747904);        // [2][512] 4 KB
  float* UVS   = (float*)(w + 10752000);        // 3 MB
  float* WFULL = (float*)(w + 13897728);        // [2][512][512] 2 MB
  float* WOT   = (float*)(w + 15994880);        // [2][256][256] 512 KB
  char* AR = w + 16519168;                      // ~32.25 MB arena

  // gcn overlay
  float* PQ1 = (float*)(AR);                    // [4][2048][512] 16 MB
  float* PQ2 = (float*)(AR);                    // [2][2048][1024] 16 MB (after)
  float* F2  = (float*)(AR + 16 * MB);          // [4][2048][512] 16 MB
  float* Y3  = (float*)(AR);                    // [4][2048][256] 8 MB (after)
  float* F1d = (float*)d_out;                   // [4][2048][256] 8 MB scratch
  // attention overlay
  float* Qp = (float*)(AR);                     // 4 MB
  float* Kp = (float*)(AR + 4 * MB);            // 4 MB head-major
  float* Vp = (float*)(AR + 8 * MB);            // 4 MB head-major
  float* Oc = (float*)(AR + 12 * MB);           // 4 MB
  float* Hh = (float*)(AR + 16 * MB);           // 8 MB

  const float* W1b = (const float*)d_in[4];
  const float* W2b = (const float*)d_in[5];
  const float* W3b = (const float*)d_in[6];
  const float* Wqb = (const float*)d_in[7];   const float* bqb = (const float*)d_in[8];
  const float* Wkb = (const float*)d_in[9];   const float* bkb = (const float*)d_in[10];
  const float* Wvb = (const float*)d_in[11];  const float* bvb = (const float*)d_in[12];
  const float* Wob = (const float*)d_in[13];  const float* bob = (const float*)d_in[14];
  const float* Wm1b = (const float*)d_in[15]; const float* bm1b = (const float*)d_in[16];
  const float* Wm2b = (const float*)d_in[17]; const float* bm2b = (const float*)d_in[18];

  // -------- setup (3 launches) --------
  k_knnp<<<dim3(NPV / 4, 4), dim3(256), 0, stream>>>((const float*)d_in[0],
                                                     (const float*)d_in[2], KN1, KN2);
  k_setup<<<dim3(12804), dim3(256), 0, stream>>>(
      (const float*)d_in[1], (const float*)d_in[3], S0, S1,
      W1b, W2b, UVS, Wob, WOT, Wm1b, WFULL, bm1b, bob, BCOMB);
  // Wfull right half: Wcomb[li] = Wm1b[li] @ WoT[li]^T
  k_gemm<false, false, false><<<dim3(4, 2, 2), dim3(256), 0, stream>>>(
      Wm1b + 256, 512, 262144, nullptr, WOT, 256, 65536, nullptr,
      WFULL + 256, 512, 262144, 256, 0, 0, nullptr, 0, 0.f, nullptr, 0);

  // -------- paired gcn layer (8 launches) --------
  auto gcn = [&](int li) {
    const float* UV1 = UVS + (i64)li * 393216;
    const float* UV2 = UVS + (i64)li * 393216 + 131072;
    // hop1 (z=4): PQ1 = X @ [U1;V1]^T
    k_gemm<false, false, false><<<dim3(16, 4, 4), dim3(256), 0, stream>>>(
        S0, 256, NSTR, nullptr, UV1, 256, 0, nullptr, PQ1, 512, NSTR2, 256, 0, 0,
        nullptr, 0, 0.f, nullptr, 0);
    k_gstat<<<dim3(1, 64, 4), dim3(256), 0, stream>>>(PQ1, PQ1 + 256, 512, KN1,
                                                      256, F1d, PARTA);
    // hop2 per set (z=2): PQ2 = norm(F1) @ [U2;V2]^T
    for (int s = 0; s < 2; s++) {
      k_gemm<true, false, false><<<dim3(16, 8, 2), dim3(256), 0, stream>>>(
          F1d + (i64)s * 2 * NSTR, 256, NSTR, nullptr, UV2, 256, 0, nullptr,
          PQ2, 1024, NSTR4, 256, 0, 1,
          PARTA + (i64)s * 65536, 64, 1.f / 32768.f, nullptr, 0);
      k_gstat<<<dim3(2, 64, 2), dim3(256), 0, stream>>>(
          PQ2, PQ2 + 512, 1024, KN1 + (i64)s * 65536,
          512, F2 + (i64)s * 2 * NSTR2, PARTB + (i64)s * 131072);
    }
    // y3 (z=4) + estat, then normP -> slots (in place over inputs)
    k_y3<<<dim3(16, 2, 4), dim3(256), 0, stream>>>(S0, F1d, F2, W3b, Y3,
                                                   PARTA, PARTB, PARTCg, li);
    k_normP<<<dim3(2048, 1, 4), dim3(256), 0, stream>>>(Y3, S0, 256, PARTCg, 16,
                                                        1.f / 2048.f, 1);
  };

  // -------- cross attention (4 launches) --------
  auto attn = [&](const float* XA, const float* XB, float* XO, int li) {
    const float* Wq = Wqb + (i64)li * 65536;   const float* bq = bqb + (i64)li * 256;
    const float* Wk = Wkb + (i64)li * 65536;   const float* bk = bkb + (i64)li * 256;
    const float* Wv = Wvb + (i64)li * 65536;   const float* bv = bvb + (i64)li * 256;
    const float* Wm2 = Wm2b + (i64)li * 131072; const float* bm2 = bm2b + (i64)li * 256;
    k_qkv<<<dim3(16, 2, 6), dim3(256), 0, stream>>>(XA, XB, Wq, Wk, Wv,
                                                    bq, bk, bv, Qp, Kp, Vp);
    k_flash<<<dim3(32, 4, BB), dim3(256), 0, stream>>>(Qp, Kp, Vp, Oc);
    // Hh = [XA | Oc] @ Wfull^T + bcomb, epilogue stats
    k_gemm<false, true, true><<<dim3(16, 4, 2), dim3(256), 0, stream>>>(
        XA, 256, NSTR, Oc, WFULL + (i64)li * 262144, 512, 0,
        BCOMB + (i64)li * 512, Hh, 512, NSTR2, 512, 0, 0,
        nullptr, 0, 0.f, PARTCa, 512);
    // XO = relu(norm(Hh)) @ Wm2^T + bm2 (norm folded into A-staging)
    k_gemm<true, false, false><<<dim3(16, 2, 2), dim3(256), 0, stream>>>(
        Hh, 512, NSTR2, nullptr, Wm2, 512, 0, bm2, XO, 256, NSTR, 512, 0, 2,
        PARTCa, 16, 1.f / 2048.f, nullptr, 0);
  };

  // -------- 4 layers, 2-slot ping-pong --------
  gcn(0);                       // S0=f1.a, S1=f2.a
  attn(S0, S1, S0, 0);          // S0=f1.b
  attn(S1, S0, S1, 0);          // S1=f2.b
  gcn(1);                       // S0=f1.c, S1=f2.c
  attn(S0, S1, S0, 1);          // S0=f1.d
  attn(S1, S0, S1, 1);          // S1=f2.d

  k_final2<<<dim3(8192), dim3(256), 0, stream>>>(S0, S1, outp);
}

// Round 7
// 1574.384 us; speedup vs baseline: 62.0489x; 1.0434x over previous
//
#include <hip/hip_runtime.h>

// ============================================================================
// InformationInteractive (gcn, cross_attn, gcn, cross_attn).
// Round 18: counter evidence (knn stuck at 200us despite reg-cache; occupancy
// 31%) -> knn is serial-round bound. Changes:
//  - knn v3: 1 point/block, 4 waves x 512-candidate segments, each extracts
//    sorted top-17 (17 x 8-scan), LDS lists, wave0 4-way-merges (exact same
//    lex-min sequence as serial watermark scan -> bit-identical).
//  - hop2 z=4 with bf16(RTNE) PQ2 (16MB) -> hop2+gstat2 = 2 launches (was 4).
//  - Wm2 epilogue can dual/transpose-write d_out -> k_final2 launch removed.
//  Launches 36 -> 31.
// ============================================================================

namespace {

constexpr int BB = 2, NPV = 2048, CCH = 256, KNB = 16;
typedef long long i64;
typedef unsigned short u16;
typedef unsigned int u32;
constexpr i64 NSTR  = (i64)NPV * 256;
constexpr i64 NSTR2 = (i64)NPV * 512;
constexpr i64 NSTR4 = (i64)NPV * 1024;
constexpr i64 MB = 1048576;

typedef __attribute__((ext_vector_type(8))) short short8v;   // 8 bf16
typedef __attribute__((ext_vector_type(4))) float f32x4;

__device__ __forceinline__ float lrelu(float v) { return v >= 0.f ? v : 0.2f * v; }

__device__ __forceinline__ void splitbf(float x, u16& h, u16& l) {
  unsigned u = __float_as_uint(x);
  h = (u16)(u >> 16);
  float hf = __uint_as_float(u & 0xffff0000u);
  l = (u16)(__float_as_uint(x - hf) >> 16);
}

__device__ __forceinline__ u16 f2bf_rn(float x) {   // round-to-nearest-even
  u32 u = __float_as_uint(x);
  return (u16)((u + 0x7fffu + ((u >> 16) & 1u)) >> 16);
}
__device__ __forceinline__ float bf2f(u16 h) {
  return __uint_as_float((u32)h << 16);
}

// ---- diagnostics ------------------------------------------------------------
__global__ __launch_bounds__(256) void k_diag(float* out, int n, float v) {
  int i = blockIdx.x * 256 + threadIdx.x;
  if (i < n) out[i] = v;
}

// ---- setup: cvt both feats, UV splits, WoT, Wfull-left, bcomb --------------
__global__ __launch_bounds__(256) void k_setup(
    const float* __restrict__ fa, const float* __restrict__ fb,
    float* __restrict__ Xa, float* __restrict__ Xb,
    const float* __restrict__ W1b, const float* __restrict__ W2b,
    float* __restrict__ UVS,
    const float* __restrict__ Wob, float* __restrict__ WoT,
    const float* __restrict__ Wm1b_, float* __restrict__ Wfull,
    const float* __restrict__ bm1b_, const float* __restrict__ bob,
    float* __restrict__ bcomb) {
  int blk = blockIdx.x;
  int t = threadIdx.x;
  if (blk < 8192) {
    int gi = blk * 256 + t;
    bool second = gi >= (1 << 20);
    int idx = gi & ((1 << 20) - 1);
    int b = idx >> 19;
    int n = (idx >> 8) & (NPV - 1);
    int c = idx & (CCH - 1);
    const float* f = second ? fb : fa;
    float* X = second ? Xb : Xa;
    X[idx] = f[((i64)b * CCH + c) * NPV + n];
  } else if (blk < 11264) {
    int i = (blk - 8192) * 256 + t;     // 0..786431
    int li = i / 393216;
    int r0 = i - li * 393216;
    const float* W1 = W1b + (i64)li * 131072;
    const float* W2 = W2b + (i64)li * 262144;
    float* dst = UVS + (i64)li * 393216;
    if (r0 < 131072) {
      int r = r0 >> 8, c = r0 & 255;
      dst[r0] = (r < 256) ? W1[(i64)r * 512 + c] - W1[(i64)r * 512 + 256 + c]
                          : W1[(i64)(r - 256) * 512 + 256 + c];
    } else {
      int j = r0 - 131072;
      int r = j >> 8, c = j & 255;
      dst[131072 + j] = (r < 512) ? W2[(i64)r * 512 + c] - W2[(i64)r * 512 + 256 + c]
                                  : W2[(i64)(r - 512) * 512 + 256 + c];
    }
  } else if (blk < 11776) {
    int i = (blk - 11264) * 256 + t;    // WoT[li][c][k] = Wo[li][k][c]
    int li = i >> 16, rem = i & 65535;
    int c = rem >> 8, k = rem & 255;
    WoT[(i64)li * 65536 + c * 256 + k] = Wob[(i64)li * 65536 + k * 256 + c];
  } else if (blk < 12800) {
    int i = (blk - 11776) * 256 + t;    // Wfull left half
    int li = i >> 17, rem = i & 131071;
    int o = rem >> 8, c = rem & 255;
    Wfull[(i64)li * 262144 + o * 512 + c] = Wm1b_[(i64)li * 262144 + o * 512 + c];
  } else {
    int g = (blk - 12800) * 256 + t;    // bcomb[li][o]
    int li = g >> 9, o = g & 511;
    const float* wm1 = Wm1b_ + (i64)li * 262144 + (i64)o * 512 + 256;
    const float* bo = bob + (i64)li * 256;
    float acc = bm1b_[(i64)li * 512 + o];
    for (int k = 0; k < 256; k++) acc += wm1[k] * bo[k];
    bcomb[(i64)li * 512 + o] = acc;
  }
}

// ---- knn v3: 1 point/block, 4 waves x 512-cand segments, LDS merge ---------
// Per-wave: 17 lex-min extractions of its segment (watermarked scan over 8
// regs + 6-shfl butterfly) == sorted top-17 of segment. Wave0 lanes 0-3 merge
// the 4 sorted lists -> identical global extraction sequence as serial scan.
__global__ __launch_bounds__(256) void k_knnp(const float* __restrict__ c1,
                                              const float* __restrict__ c2,
                                              int* __restrict__ o1,
                                              int* __restrict__ o2) {
#pragma clang fp contract(off)   // match np mul-then-add distance arithmetic
  __shared__ float4 csq[NPV];
  __shared__ float md[4 * 17];
  __shared__ int   mi[4 * 17];
  int set = blockIdx.y >> 1, b = blockIdx.y & 1;
  const float* cb = (set ? c2 : c1) + (i64)b * 3 * NPV;
  int* ob = (set ? o2 : o1) + (i64)b * NPV * KNB;
  int tid = threadIdx.x;
  for (int m = tid; m < NPV; m += 256) {
    float x = cb[m], y = cb[NPV + m], z = cb[2 * NPV + m];
    csq[m] = make_float4(x, y, z, x * x + y * y + z * z);
  }
  __syncthreads();
  int w = tid >> 6, lane = tid & 63;
  int n = blockIdx.x;
  float4 cn = csq[n];
  float xn = cn.x, yn = cn.y, zn = cn.z, sn = cn.w;
  float dc[8];
#pragma unroll
  for (int t = 0; t < 8; t++) {
    float4 c = csq[w * 512 + t * 64 + lane];
    float dot = xn * c.x + yn * c.y + zn * c.z;
    dc[t] = (sn + c.w) - 2.0f * dot;
  }
  float wd = -3.4e38f; int wm = -1;
  for (int r = 0; r < KNB + 1; r++) {
    float bd = 3.4e38f; int bm = 0x7fffffff;
#pragma unroll
    for (int t = 0; t < 8; t++) {
      int m = w * 512 + t * 64 + lane;
      float d = dc[t];
      bool valid = (d > wd) || (d == wd && m > wm);
      if (valid && (d < bd || (d == bd && m < bm))) { bd = d; bm = m; }
    }
    for (int mask = 1; mask < 64; mask <<= 1) {
      float od = __shfl_xor(bd, mask);
      int om = __shfl_xor(bm, mask);
      if (od < bd || (od == bd && om < bm)) { bd = od; bm = om; }
    }
    if (lane == 0) { md[w * 17 + r] = bd; mi[w * 17 + r] = bm; }
    wd = bd; wm = bm;
  }
  __syncthreads();
  if (w == 0) {
    int ptr = 0;
    float hd = (lane < 4) ? md[lane * 17] : 3.4e38f;
    int   hm = (lane < 4) ? mi[lane * 17] : 0x7fffffff;
    int* o = ob + (i64)n * KNB;
    for (int r = 0; r < KNB + 1; r++) {
      float bd = hd; int bm = hm;
      for (int mask = 1; mask < 64; mask <<= 1) {
        float od = __shfl_xor(bd, mask);
        int om = __shfl_xor(bm, mask);
        if (od < bd || (od == bd && om < bm)) { bd = od; bm = om; }
      }
      if (r > 0 && lane == 0) o[r - 1] = bm & (NPV - 1);
      if (lane < 4 && hd == bd && hm == bm) {
        ptr++;
        hd = (ptr < 17) ? md[lane * 17 + ptr] : 3.4e38f;
        hm = (ptr < 17) ? mi[lane * 17 + ptr] : 0x7fffffff;
      }
    }
  }
}

// ---- MFMA split-precision GEMM: C[M,N] = A[M,K]@W[N,K]^T (+bias / +=) -------
// OMODE: 0 = f32 out; 1 = bf16(RTNE) out (C is u16*).
// tmode: 0 none; 1 = also write transposed to out2; 2 = transposed ONLY.
template <bool ANORM, bool ACAT, bool ESTAT, int OMODE>
__global__ __launch_bounds__(256) void k_gemm(
    const float* __restrict__ A, int lda, i64 sA,
    const float* __restrict__ A2,
    const float* __restrict__ W, int ldw, i64 sW,
    const float* __restrict__ bias,
    float* __restrict__ C, int ldc, i64 sC,
    int K, int mode, int act,
    const float* __restrict__ pin, int nchA, float invA,
    float* __restrict__ pout, int ncolsTot,
    int tmode, float* __restrict__ out2) {
  __shared__ __align__(16) u16 Ah[128][36], Al[128][36], Bh[128][36], Bl[128][36];
  __shared__ float mv[512], rv[512];
  __shared__ float cs[128][2];
  int b = blockIdx.z;
  A += (i64)b * sA;
  if (ACAT) A2 += (i64)b * NSTR;
  int m0 = blockIdx.x * 128, n0 = blockIdx.y * 128;
  int tid = threadIdx.x;
  int w = tid >> 6, l = tid & 63;
  int wr = w >> 1, wc = w & 1;
  int lc = l & 15, lq = l >> 4;
  int srow = tid >> 1, skh = (tid & 1) * 16;

  if (ANORM) {
    for (int c = tid; c < K; c += 256) {
      float s = 0.f, ss = 0.f;
      for (int hh = 0; hh < nchA; hh++) {
        s  += pin[((i64)(b * nchA + hh) * K + c) * 2];
        ss += pin[((i64)(b * nchA + hh) * K + c) * 2 + 1];
      }
      float mu = s * invA;
      mv[c] = mu;
      rv[c] = 1.0f / sqrtf(ss * invA - mu * mu + 1e-5f);
    }
    __syncthreads();
  }

  const float* Ap = A + (i64)(m0 + srow) * lda + skh;
  const float* Wp = W + (i64)b * sW + (i64)(n0 + srow) * ldw + skh;

  auto loadA = [&](int kt, float4* v) {
#pragma unroll
    for (int j = 0; j < 4; j++) {
      if (ACAT) {
        int col0 = kt + skh;
        const float* ap = (col0 < 256)
            ? A  + (i64)(m0 + srow) * 256 + col0
            : A2 + (i64)(m0 + srow) * 256 + (col0 - 256);
        v[j] = *(const float4*)(ap + j * 4);
      } else {
        v[j] = *(const float4*)(Ap + kt + j * 4);
      }
    }
  };
  auto loadW = [&](int kt, float4* v) {
#pragma unroll
    for (int j = 0; j < 4; j++) v[j] = *(const float4*)(Wp + kt + j * 4);
  };

  float4 ar[4], wv4[4];
  loadA(0, ar); loadW(0, wv4);

  f32x4 acc[4][4];
#pragma unroll
  for (int i = 0; i < 4; i++)
#pragma unroll
    for (int j = 0; j < 4; j++)
#pragma unroll
      for (int r = 0; r < 4; r++) acc[i][j][r] = 0.f;

  int koff = lq * 8;
  for (int kt = 0; kt < K; kt += 32) {
    __syncthreads();
#pragma unroll
    for (int j = 0; j < 4; j++) {
      float4 a = ar[j];
      if (ANORM) {
        float4 mu = *(const float4*)&mv[kt + skh + j * 4];
        float4 rs = *(const float4*)&rv[kt + skh + j * 4];
        a.x = (a.x - mu.x) * rs.x; a.y = (a.y - mu.y) * rs.y;
        a.z = (a.z - mu.z) * rs.z; a.w = (a.w - mu.w) * rs.w;
        if (act == 1) { a.x = lrelu(a.x); a.y = lrelu(a.y);
                        a.z = lrelu(a.z); a.w = lrelu(a.w); }
        else { a.x = fmaxf(a.x, 0.f); a.y = fmaxf(a.y, 0.f);
               a.z = fmaxf(a.z, 0.f); a.w = fmaxf(a.w, 0.f); }
      }
      u16 h0, h1, h2, h3, l0, l1, l2, l3;
      splitbf(a.x, h0, l0); splitbf(a.y, h1, l1);
      splitbf(a.z, h2, l2); splitbf(a.w, h3, l3);
      *(ushort4*)&Ah[srow][skh + j * 4] = make_ushort4(h0, h1, h2, h3);
      *(ushort4*)&Al[srow][skh + j * 4] = make_ushort4(l0, l1, l2, l3);
      float4 bb = wv4[j];
      splitbf(bb.x, h0, l0); splitbf(bb.y, h1, l1);
      splitbf(bb.z, h2, l2); splitbf(bb.w, h3, l3);
      *(ushort4*)&Bh[srow][skh + j * 4] = make_ushort4(h0, h1, h2, h3);
      *(ushort4*)&Bl[srow][skh + j * 4] = make_ushort4(l0, l1, l2, l3);
    }
    __syncthreads();
    if (kt + 32 < K) { loadA(kt + 32, ar); loadW(kt + 32, wv4); }
    short8v ah[4], al4[4], bh[4], bl4[4];
#pragma unroll
    for (int i = 0; i < 4; i++) {
      int r = wr * 64 + i * 16 + lc;
      ah[i]  = *(const short8v*)&Ah[r][koff];
      al4[i] = *(const short8v*)&Al[r][koff];
    }
#pragma unroll
    for (int j = 0; j < 4; j++) {
      int r = wc * 64 + j * 16 + lc;
      bh[j]  = *(const short8v*)&Bh[r][koff];
      bl4[j] = *(const short8v*)&Bl[r][koff];
    }
#pragma unroll
    for (int i = 0; i < 4; i++) {
#pragma unroll
      for (int j = 0; j < 4; j++) {
        acc[i][j] = __builtin_amdgcn_mfma_f32_16x16x32_bf16(ah[i], bh[j], acc[i][j], 0, 0, 0);
        acc[i][j] = __builtin_amdgcn_mfma_f32_16x16x32_bf16(al4[i], bh[j], acc[i][j], 0, 0, 0);
        acc[i][j] = __builtin_amdgcn_mfma_f32_16x16x32_bf16(ah[i], bl4[j], acc[i][j], 0, 0, 0);
      }
    }
  }

  float sj[4] = {0.f, 0.f, 0.f, 0.f}, ssj[4] = {0.f, 0.f, 0.f, 0.f};
#pragma unroll
  for (int j = 0; j < 4; j++) {
    int col = n0 + wc * 64 + j * 16 + lc;
    float bv = (mode == 0 && bias) ? bias[col] : 0.f;
#pragma unroll
    for (int i = 0; i < 4; i++) {
      int rbase = m0 + wr * 64 + i * 16 + lq * 4;
#pragma unroll
      for (int r = 0; r < 4; r++) {
        int row = rbase + r;
        float v;
        if (OMODE == 1) {
          v = acc[i][j][r];
          ((u16*)C)[(i64)b * sC + (i64)row * ldc + col] = f2bf_rn(v);
        } else {
          float* cp = &C[(i64)b * sC + (i64)row * ldc + col];
          v = acc[i][j][r] + ((mode == 0) ? bv : *cp);
          if (tmode != 2) *cp = v;
          if (tmode != 0)
            out2[(i64)b * 524288 + (i64)col * 2048 + row] = v;
        }
        if (ESTAT) { sj[j] += v; ssj[j] += v * v; }
      }
    }
  }
  if (ESTAT) {
#pragma unroll
    for (int j = 0; j < 4; j++) {
      sj[j]  += __shfl_xor(sj[j], 16);  sj[j]  += __shfl_xor(sj[j], 32);
      ssj[j] += __shfl_xor(ssj[j], 16); ssj[j] += __shfl_xor(ssj[j], 32);
    }
    __syncthreads();
    if (wr == 0 && lq == 0) {
#pragma unroll
      for (int j = 0; j < 4; j++) {
        int cl = wc * 64 + j * 16 + lc;
        cs[cl][0] = sj[j]; cs[cl][1] = ssj[j];
      }
    }
    __syncthreads();
    if (wr == 1 && lq == 0) {
#pragma unroll
      for (int j = 0; j < 4; j++) {
        int cl = wc * 64 + j * 16 + lc;
        cs[cl][0] += sj[j]; cs[cl][1] += ssj[j];
      }
    }
    __syncthreads();
    if (tid < 128) {
      i64 slot = ((i64)(b * gridDim.x + blockIdx.x) * ncolsTot + n0 + tid) * 2;
      pout[slot] = cs[tid][0];
      pout[slot + 1] = cs[tid][1];
    }
  }
}

// ---- QKV: grid (16, 2, 6), z = mat*2 + b; K/V -> head-major ----------------
__global__ __launch_bounds__(256) void k_qkv(
    const float* __restrict__ XA, const float* __restrict__ XB,
    const float* __restrict__ Wq, const float* __restrict__ Wk,
    const float* __restrict__ Wv,
    const float* __restrict__ bq, const float* __restrict__ bk,
    const float* __restrict__ bv,
    float* __restrict__ Qp, float* __restrict__ Kp, float* __restrict__ Vp) {
  __shared__ __align__(16) u16 Ah[128][36], Al[128][36], Bh[128][36], Bl[128][36];
  int z = blockIdx.z;
  int mat = z >> 1, b = z & 1;
  const float* A = (mat == 0 ? XA : XB) + (i64)b * NSTR;
  const float* W = (mat == 0 ? Wq : (mat == 1 ? Wk : Wv));
  const float* bias = (mat == 0 ? bq : (mat == 1 ? bk : bv));
  float* C = (mat == 0 ? Qp : (mat == 1 ? Kp : Vp)) + (i64)b * NSTR;
  int m0 = blockIdx.x * 128, n0 = blockIdx.y * 128;
  int tid = threadIdx.x;
  int w = tid >> 6, l = tid & 63;
  int wr = w >> 1, wc = w & 1;
  int lc = l & 15, lq = l >> 4;
  int srow = tid >> 1, skh = (tid & 1) * 16;
  const float* Ap = A + (i64)(m0 + srow) * 256 + skh;
  const float* Wp = W + (i64)(n0 + srow) * 256 + skh;
  float4 ar[4], wv4[4];
#pragma unroll
  for (int j = 0; j < 4; j++) { ar[j] = *(const float4*)(Ap + j * 4);
                                wv4[j] = *(const float4*)(Wp + j * 4); }
  f32x4 acc[4][4];
#pragma unroll
  for (int i = 0; i < 4; i++)
#pragma unroll
    for (int j = 0; j < 4; j++)
#pragma unroll
      for (int r = 0; r < 4; r++) acc[i][j][r] = 0.f;
  int koff = lq * 8;
  for (int kt = 0; kt < 256; kt += 32) {
    __syncthreads();
#pragma unroll
    for (int j = 0; j < 4; j++) {
      u16 h0, h1, h2, h3, l0, l1, l2, l3;
      splitbf(ar[j].x, h0, l0); splitbf(ar[j].y, h1, l1);
      splitbf(ar[j].z, h2, l2); splitbf(ar[j].w, h3, l3);
      *(ushort4*)&Ah[srow][skh + j * 4] = make_ushort4(h0, h1, h2, h3);
      *(ushort4*)&Al[srow][skh + j * 4] = make_ushort4(l0, l1, l2, l3);
      splitbf(wv4[j].x, h0, l0); splitbf(wv4[j].y, h1, l1);
      splitbf(wv4[j].z, h2, l2); splitbf(wv4[j].w, h3, l3);
      *(ushort4*)&Bh[srow][skh + j * 4] = make_ushort4(h0, h1, h2, h3);
      *(ushort4*)&Bl[srow][skh + j * 4] = make_ushort4(l0, l1, l2, l3);
    }
    __syncthreads();
    if (kt + 32 < 256) {
#pragma unroll
      for (int j = 0; j < 4; j++) { ar[j] = *(const float4*)(Ap + kt + 32 + j * 4);
                                    wv4[j] = *(const float4*)(Wp + kt + 32 + j * 4); }
    }
    short8v ah[4], al4[4], bh[4], bl4[4];
#pragma unroll
    for (int i = 0; i < 4; i++) {
      int r = wr * 64 + i * 16 + lc;
      ah[i]  = *(const short8v*)&Ah[r][koff];
      al4[i] = *(const short8v*)&Al[r][koff];
    }
#pragma unroll
    for (int j = 0; j < 4; j++) {
      int r = wc * 64 + j * 16 + lc;
      bh[j]  = *(const short8v*)&Bh[r][koff];
      bl4[j] = *(const short8v*)&Bl[r][koff];
    }
#pragma unroll
    for (int i = 0; i < 4; i++)
#pragma unroll
      for (int j = 0; j < 4; j++) {
        acc[i][j] = __builtin_amdgcn_mfma_f32_16x16x32_bf16(ah[i], bh[j], acc[i][j], 0, 0, 0);
        acc[i][j] = __builtin_amdgcn_mfma_f32_16x16x32_bf16(al4[i], bh[j], acc[i][j], 0, 0, 0);
        acc[i][j] = __builtin_amdgcn_mfma_f32_16x16x32_bf16(ah[i], bl4[j], acc[i][j], 0, 0, 0);
      }
  }
#pragma unroll
  for (int j = 0; j < 4; j++) {
    int col = n0 + wc * 64 + j * 16 + lc;
    float bv = bias[col];
#pragma unroll
    for (int i = 0; i < 4; i++) {
      int rbase = m0 + wr * 64 + i * 16 + lq * 4;
#pragma unroll
      for (int r = 0; r < 4; r++) {
        float v = acc[i][j][r] + bv;
        int row = rbase + r;
        if (mat == 0) C[(i64)row * 256 + col] = v;
        else C[((i64)(col & 3) * 2048 + row) * 64 + (col >> 2)] = v;
      }
    }
  }
}

// ---- Y3 = [X | norm(F1) | norm(F2)] @ W3^T, z=4 paired, + stats -------------
__global__ __launch_bounds__(256) void k_y3(
    const float* __restrict__ Xbase, const float* __restrict__ F1b,
    const float* __restrict__ F2b, const float* __restrict__ W3b,
    float* __restrict__ Cb,
    const float* __restrict__ pA, const float* __restrict__ pB,
    float* __restrict__ pout, int li) {
  __shared__ __align__(16) u16 Ah[128][36], Al[128][36], Bh[128][36], Bl[128][36];
  __shared__ float mv[1024], rv[1024];
  __shared__ float cs[128][2];
  int z = blockIdx.z;
  const float* X = Xbase + (i64)z * NSTR;
  const float* F1 = F1b + (i64)z * NSTR;
  const float* F2 = F2b + (i64)z * NSTR2;
  const float* W3 = W3b + (i64)li * 262144;
  float* C = Cb + (i64)z * NSTR;
  int m0 = blockIdx.x * 128, n0 = blockIdx.y * 128;
  int tid = threadIdx.x;
  int w = tid >> 6, l = tid & 63;
  int wr = w >> 1, wc = w & 1;
  int lc = l & 15, lq = l >> 4;
  int srow = tid >> 1, skh = (tid & 1) * 16;
  for (int c = tid; c < 768; c += 256) {
    int col = 256 + c;
    const float* P; int cols, idx;
    if (col < 512) { P = pA; cols = 256; idx = col - 256; }
    else           { P = pB; cols = 512; idx = col - 512; }
    float s = 0.f, ss = 0.f;
    for (int hh = 0; hh < 64; hh++) {
      s  += P[((i64)(z * 64 + hh) * cols + idx) * 2];
      ss += P[((i64)(z * 64 + hh) * cols + idx) * 2 + 1];
    }
    float mu = s * (1.f / 32768.f);
    mv[col] = mu;
    rv[col] = 1.0f / sqrtf(ss * (1.f / 32768.f) - mu * mu + 1e-5f);
  }
  __syncthreads();
  auto loadA = [&](int kt, float4* v) {
    int col0 = kt + skh;
    const float* ap;
    if (col0 < 256)      ap = X  + (i64)(m0 + srow) * 256 + col0;
    else if (col0 < 512) ap = F1 + (i64)(m0 + srow) * 256 + (col0 - 256);
    else                 ap = F2 + (i64)(m0 + srow) * 512 + (col0 - 512);
#pragma unroll
    for (int j = 0; j < 4; j++) v[j] = *(const float4*)(ap + j * 4);
  };
  const float* Wp = W3 + (i64)(n0 + srow) * 1024 + skh;
  float4 ar[4], wv4[4];
  loadA(0, ar);
#pragma unroll
  for (int j = 0; j < 4; j++) wv4[j] = *(const float4*)(Wp + j * 4);
  f32x4 acc[4][4];
#pragma unroll
  for (int i = 0; i < 4; i++)
#pragma unroll
    for (int j = 0; j < 4; j++)
#pragma unroll
      for (int r = 0; r < 4; r++) acc[i][j][r] = 0.f;
  int koff = lq * 8;
  for (int kt = 0; kt < 1024; kt += 32) {
    __syncthreads();
    int col0 = kt + skh;
#pragma unroll
    for (int j = 0; j < 4; j++) {
      float4 a = ar[j];
      if (col0 >= 256) {
        float4 mu = *(const float4*)&mv[col0 + j * 4];
        float4 rs = *(const float4*)&rv[col0 + j * 4];
        a.x = lrelu((a.x - mu.x) * rs.x);
        a.y = lrelu((a.y - mu.y) * rs.y);
        a.z = lrelu((a.z - mu.z) * rs.z);
        a.w = lrelu((a.w - mu.w) * rs.w);
      }
      u16 h0, h1, h2, h3, l0, l1, l2, l3;
      splitbf(a.x, h0, l0); splitbf(a.y, h1, l1);
      splitbf(a.z, h2, l2); splitbf(a.w, h3, l3);
      *(ushort4*)&Ah[srow][skh + j * 4] = make_ushort4(h0, h1, h2, h3);
      *(ushort4*)&Al[srow][skh + j * 4] = make_ushort4(l0, l1, l2, l3);
      splitbf(wv4[j].x, h0, l0); splitbf(wv4[j].y, h1, l1);
      splitbf(wv4[j].z, h2, l2); splitbf(wv4[j].w, h3, l3);
      *(ushort4*)&Bh[srow][skh + j * 4] = make_ushort4(h0, h1, h2, h3);
      *(ushort4*)&Bl[srow][skh + j * 4] = make_ushort4(l0, l1, l2, l3);
    }
    __syncthreads();
    if (kt + 32 < 1024) {
      loadA(kt + 32, ar);
#pragma unroll
      for (int j = 0; j < 4; j++) wv4[j] = *(const float4*)(Wp + kt + 32 + j * 4);
    }
    short8v ah[4], al4[4], bh[4], bl4[4];
#pragma unroll
    for (int i = 0; i < 4; i++) {
      int r = wr * 64 + i * 16 + lc;
      ah[i]  = *(const short8v*)&Ah[r][koff];
      al4[i] = *(const short8v*)&Al[r][koff];
    }
#pragma unroll
    for (int j = 0; j < 4; j++) {
      int r = wc * 64 + j * 16 + lc;
      bh[j]  = *(const short8v*)&Bh[r][koff];
      bl4[j] = *(const short8v*)&Bl[r][koff];
    }
#pragma unroll
    for (int i = 0; i < 4; i++)
#pragma unroll
      for (int j = 0; j < 4; j++) {
        acc[i][j] = __builtin_amdgcn_mfma_f32_16x16x32_bf16(ah[i], bh[j], acc[i][j], 0, 0, 0);
        acc[i][j] = __builtin_amdgcn_mfma_f32_16x16x32_bf16(al4[i], bh[j], acc[i][j], 0, 0, 0);
        acc[i][j] = __builtin_amdgcn_mfma_f32_16x16x32_bf16(ah[i], bl4[j], acc[i][j], 0, 0, 0);
      }
  }
  float sj[4] = {0.f, 0.f, 0.f, 0.f}, ssj[4] = {0.f, 0.f, 0.f, 0.f};
#pragma unroll
  for (int j = 0; j < 4; j++) {
    int col = n0 + wc * 64 + j * 16 + lc;
#pragma unroll
    for (int i = 0; i < 4; i++) {
      int rbase = m0 + wr * 64 + i * 16 + lq * 4;
#pragma unroll
      for (int r = 0; r < 4; r++) {
        float v = acc[i][j][r];
        C[(i64)(rbase + r) * 256 + col] = v;
        sj[j] += v; ssj[j] += v * v;
      }
    }
  }
#pragma unroll
  for (int j = 0; j < 4; j++) {
    sj[j]  += __shfl_xor(sj[j], 16);  sj[j]  += __shfl_xor(sj[j], 32);
    ssj[j] += __shfl_xor(ssj[j], 16); ssj[j] += __shfl_xor(ssj[j], 32);
  }
  __syncthreads();
  if (wr == 0 && lq == 0) {
#pragma unroll
    for (int j = 0; j < 4; j++) {
      int cl = wc * 64 + j * 16 + lc;
      cs[cl][0] = sj[j]; cs[cl][1] = ssj[j];
    }
  }
  __syncthreads();
  if (wr == 1 && lq == 0) {
#pragma unroll
    for (int j = 0; j < 4; j++) {
      int cl = wc * 64 + j * 16 + lc;
      cs[cl][0] += sj[j]; cs[cl][1] += ssj[j];
    }
  }
  __syncthreads();
  if (tid < 128) {
    i64 slot = ((i64)(z * 16 + blockIdx.x) * 256 + n0 + tid) * 2;
    pout[slot] = cs[tid][0];
    pout[slot + 1] = cs[tid][1];
  }
}

// ---- fused gather: RM = P + max_k Q[j]; partial stats. BF16IN: u16 src -----
template <bool BF16IN>
__global__ __launch_bounds__(256) void k_gstat(const void* __restrict__ Pv,
                                               const void* __restrict__ Qv,
                                               int ldpq,
                                               const int* __restrict__ knn,
                                               int O, float* __restrict__ RM,
                                               float* __restrict__ part) {
  int b = blockIdx.z;
  int o = blockIdx.x * 256 + threadIdx.x;
  int n0 = blockIdx.y * 32;
  RM += (i64)b * 2048 * O;
  knn += ((i64)b * 2048 + n0) * KNB;
  __shared__ int js[32 * KNB];
  for (int i = threadIdx.x; i < 32 * KNB; i += 256) js[i] = knn[i];
  __syncthreads();
  i64 base = (i64)b * 2048 * ldpq;
  float s = 0.f, ss = 0.f;
  for (int r = 0; r < 32; r++) {
    int n = n0 + r;
    float p = BF16IN ? bf2f(((const u16*)Pv)[base + (i64)n * ldpq + o])
                     : ((const float*)Pv)[base + (i64)n * ldpq + o];
    float qm = -3.4e38f, qs = 0.f, qss = 0.f;
#pragma unroll
    for (int k = 0; k < KNB; k++) {
      i64 qoff = base + (i64)js[r * KNB + k] * ldpq + o;
      float q = BF16IN ? bf2f(((const u16*)Qv)[qoff]) : ((const float*)Qv)[qoff];
      qm = fmaxf(qm, q); qs += q; qss += q * q;
    }
    RM[(i64)n * O + o] = p + qm;
    s  += 16.f * p + qs;
    ss += 16.f * p * p + 2.f * p * qs + qss;
  }
  i64 slot = ((i64)b * 64 + blockIdx.y) * O + o;
  part[slot * 2] = s; part[slot * 2 + 1] = ss;
}

// ---- normalize + act, stats from PART; z-major dst --------------------------
__global__ __launch_bounds__(256) void k_normP(const float* __restrict__ src,
                                               float* __restrict__ dst, int cols,
                                               const float* __restrict__ part,
                                               int nch, float inv, int act) {
  int b = blockIdx.z;
  i64 n = blockIdx.x;
  int c = blockIdx.y * 256 + threadIdx.x;
  float s = 0.f, ss = 0.f;
  for (int h = 0; h < nch; h++) {
    s  += part[((i64)(b * nch + h) * cols + c) * 2];
    ss += part[((i64)(b * nch + h) * cols + c) * 2 + 1];
  }
  float mu = s * inv;
  float rs = 1.0f / sqrtf(ss * inv - mu * mu + 1e-5f);
  i64 off = ((i64)b * 2048 + n) * cols + c;
  float v = (src[off] - mu) * rs;
  dst[off] = (act == 1) ? lrelu(v) : fmaxf(v, 0.f);
}

// ---- flash attention: grid (32, 4, B) ---------------------------------------
__global__ __launch_bounds__(256) void k_flash(const float* __restrict__ Qp,
                                               const float* __restrict__ Kp,
                                               const float* __restrict__ Vp,
                                               float* __restrict__ Op) {
  __shared__ __align__(16) u16 Kh[64][76], Kl[64][76];
  __shared__ __align__(16) u16 Vh[64][76], Vl[64][76];   // [d][m]
  __shared__ __align__(16) u16 Ph[4][16][76], Pl[4][16][76];
  int qt = blockIdx.x, h = blockIdx.y, b = blockIdx.z;
  const float* Qb = Qp + (i64)b * NSTR;
  const float* Khm = Kp + (i64)b * NSTR + (i64)h * 131072;
  const float* Vhm = Vp + (i64)b * NSTR + (i64)h * 131072;
  int tid = threadIdx.x;
  int w = tid >> 6, l = tid & 63;
  int lc = l & 15, lq = l >> 4;
  short8v qh[2], ql[2];
  int qrow = qt * 64 + w * 16 + lc;
#pragma unroll
  for (int ks = 0; ks < 2; ks++) {
#pragma unroll
    for (int j = 0; j < 8; j++) {
      float v = Qb[(i64)qrow * 256 + 4 * (ks * 32 + lq * 8 + j) + h];
      u16 hh, ll; splitbf(v, hh, ll);
      qh[ks][j] = (short)hh; ql[ks][j] = (short)ll;
    }
  }
  float m_r[4] = {-3.0e38f, -3.0e38f, -3.0e38f, -3.0e38f};
  float l_r[4] = {0.f, 0.f, 0.f, 0.f};
  f32x4 acc[4];
#pragma unroll
  for (int j = 0; j < 4; j++)
#pragma unroll
    for (int r = 0; r < 4; r++) acc[j][r] = 0.f;

  for (int kt = 0; kt < 32; kt++) {
    __syncthreads();
    {
      const float* Kt = Khm + (i64)kt * 4096;
      const float* Vt = Vhm + (i64)kt * 4096;
#pragma unroll
      for (int q = 0; q < 4; q++) {
        int v = q * 256 + tid;
        int m = v >> 4, d4 = (v & 15) * 4;
        u16 h0, h1, h2, h3, l0, l1, l2, l3;
        float4 kf = *(const float4*)(Kt + (i64)v * 4);
        splitbf(kf.x, h0, l0); splitbf(kf.y, h1, l1);
        splitbf(kf.z, h2, l2); splitbf(kf.w, h3, l3);
        *(ushort4*)&Kh[m][d4] = make_ushort4(h0, h1, h2, h3);
        *(ushort4*)&Kl[m][d4] = make_ushort4(l0, l1, l2, l3);
        float4 vf = *(const float4*)(Vt + (i64)v * 4);
        splitbf(vf.x, h0, l0); splitbf(vf.y, h1, l1);
        splitbf(vf.z, h2, l2); splitbf(vf.w, h3, l3);
        Vh[d4 + 0][m] = h0; Vh[d4 + 1][m] = h1;
        Vh[d4 + 2][m] = h2; Vh[d4 + 3][m] = h3;
        Vl[d4 + 0][m] = l0; Vl[d4 + 1][m] = l1;
        Vl[d4 + 2][m] = l2; Vl[d4 + 3][m] = l3;
      }
    }
    __syncthreads();
    f32x4 s[4];
#pragma unroll
    for (int j = 0; j < 4; j++)
#pragma unroll
      for (int r = 0; r < 4; r++) s[j][r] = 0.f;
#pragma unroll
    for (int ks = 0; ks < 2; ks++) {
      int ko = ks * 32 + lq * 8;
#pragma unroll
      for (int j = 0; j < 4; j++) {
        short8v bh = *(const short8v*)&Kh[j * 16 + lc][ko];
        short8v bl = *(const short8v*)&Kl[j * 16 + lc][ko];
        s[j] = __builtin_amdgcn_mfma_f32_16x16x32_bf16(qh[ks], bh, s[j], 0, 0, 0);
        s[j] = __builtin_amdgcn_mfma_f32_16x16x32_bf16(ql[ks], bh, s[j], 0, 0, 0);
        s[j] = __builtin_amdgcn_mfma_f32_16x16x32_bf16(qh[ks], bl, s[j], 0, 0, 0);
      }
    }
#pragma unroll
    for (int j = 0; j < 4; j++)
#pragma unroll
      for (int r = 0; r < 4; r++) s[j][r] *= 0.125f;
    float rmax[4];
#pragma unroll
    for (int r = 0; r < 4; r++)
      rmax[r] = fmaxf(fmaxf(s[0][r], s[1][r]), fmaxf(s[2][r], s[3][r]));
#pragma unroll
    for (int mask = 1; mask < 16; mask <<= 1)
#pragma unroll
      for (int r = 0; r < 4; r++) rmax[r] = fmaxf(rmax[r], __shfl_xor(rmax[r], mask));
    float fs[4], rsum[4];
#pragma unroll
    for (int r = 0; r < 4; r++) {
      float mn = fmaxf(m_r[r], rmax[r]);
      fs[r] = expf(m_r[r] - mn);
      m_r[r] = mn; rsum[r] = 0.f;
    }
#pragma unroll
    for (int j = 0; j < 4; j++)
#pragma unroll
      for (int r = 0; r < 4; r++) {
        float p = expf(s[j][r] - m_r[r]);
        rsum[r] += p;
        u16 hh, ll; splitbf(p, hh, ll);
        Ph[w][lq * 4 + r][j * 16 + lc] = hh;
        Pl[w][lq * 4 + r][j * 16 + lc] = ll;
      }
#pragma unroll
    for (int mask = 1; mask < 16; mask <<= 1)
#pragma unroll
      for (int r = 0; r < 4; r++) rsum[r] += __shfl_xor(rsum[r], mask);
#pragma unroll
    for (int r = 0; r < 4; r++) l_r[r] = l_r[r] * fs[r] + rsum[r];
#pragma unroll
    for (int j = 0; j < 4; j++)
#pragma unroll
      for (int r = 0; r < 4; r++) acc[j][r] *= fs[r];
#pragma unroll
    for (int ks = 0; ks < 2; ks++) {
      int ko = ks * 32 + lq * 8;
      short8v ph = *(const short8v*)&Ph[w][lc][ko];
      short8v pl = *(const short8v*)&Pl[w][lc][ko];
#pragma unroll
      for (int j = 0; j < 4; j++) {
        short8v bh = *(const short8v*)&Vh[j * 16 + lc][ko];
        short8v bl = *(const short8v*)&Vl[j * 16 + lc][ko];
        acc[j] = __builtin_amdgcn_mfma_f32_16x16x32_bf16(ph, bh, acc[j], 0, 0, 0);
        acc[j] = __builtin_amdgcn_mfma_f32_16x16x32_bf16(pl, bh, acc[j], 0, 0, 0);
        acc[j] = __builtin_amdgcn_mfma_f32_16x16x32_bf16(ph, bl, acc[j], 0, 0, 0);
      }
    }
  }
  float* Ob = Op + (i64)b * NSTR;
#pragma unroll
  for (int j = 0; j < 4; j++) {
    int dd = j * 16 + lc;
#pragma unroll
    for (int r = 0; r < 4; r++) {
      int q = qt * 64 + w * 16 + lq * 4 + r;
      Ob[(i64)q * 256 + 4 * dd + h] = acc[j][r] / l_r[r];
    }
  }
}

}  // namespace

// ============================================================================
extern "C" void kernel_launch(void* const* d_in, const int* in_sizes, int n_in,
                              void* d_out, int out_size, void* d_ws, size_t ws_size,
                              hipStream_t stream) {
  float* outp = (float*)d_out;
  auto diag = [&](float v) {
    k_diag<<<dim3((out_size + 255) / 256), dim3(256), 0, stream>>>(outp, out_size, v);
  };

  static const int DSZ[19] = {12288, 1048576, 12288, 1048576, 262144, 524288, 524288,
                              131072, 512, 131072, 512, 131072, 512, 131072, 512,
                              524288, 1024, 262144, 512};
  if (n_in != 19) { diag(1000.f + (float)n_in); return; }
  for (int i = 0; i < 19; i++) {
    if (in_sizes[i] != DSZ[i]) { diag(2000.f + (float)i); return; }
  }
  if (out_size != 2097152) { diag(3000.f); return; }
  constexpr size_t NEED = 50331648;  // 48 MiB
  if (ws_size < NEED) { diag((float)(ws_size >> 20)); return; }

  // -------- workspace map ----------------------------------------------------
  char* w = (char*)d_ws;
  float* S0 = (float*)(w + 0);                  // [2][2048][256] 4 MB (f1)
  float* S1 = (float*)(w + 4 * MB);             // 4 MB (f2) adjacent (z-major)
  int*   KN1 = (int*)(w + 8 * MB);              // 256 KB
  int*   KN2 = (int*)(w + 8 * MB + 262144);     // 256 KB
  float* PARTA = (float*)(w + 8912896);         // [4][64][256][2] 512 KB
  float* PARTB = (float*)(w + 9437184);         // [4][64][512][2] 1 MB
  float* PARTCg = (float*)(w + 10485760);       // [4][16][256][2] 128 KB
  float* PARTCa = (float*)(w + 10616832);       // [2][16][512][2] 128 KB
  float* BCOMB = (float*)(w + 10747904);        // [2][512] 4 KB
  float* UVS   = (float*)(w + 10752000);        // 3 MB
  float* WFULL = (float*)(w + 13897728);        // [2][512][512] 2 MB
  char* AR = w + 15994880;                      // ~32.7 MB arena

  // setup overlay
  float* WOT = (float*)(AR + 24 * MB);          // 512 KB (setup only)
  // gcn overlay
  float* PQ1 = (float*)(AR);                    // [4][2048][512] f32 16 MB
  u16*   PQ2 = (u16*)(AR);                      // [4][2048][1024] bf16 16 MB
  float* F2  = (float*)(AR + 16 * MB);          // [4][2048][512] f32 16 MB
  float* Y3  = (float*)(AR);                    // [4][2048][256] f32 8 MB
  float* F1d = (float*)d_out;                   // [4][2048][256] 8 MB scratch
  // attention overlay
  float* Qp = (float*)(AR);                     // 4 MB
  float* Kp = (float*)(AR + 4 * MB);            // 4 MB head-major
  float* Vp = (float*)(AR + 8 * MB);            // 4 MB head-major
  float* Oc = (float*)(AR + 12 * MB);           // 4 MB
  float* Hh = (float*)(AR + 16 * MB);           // 8 MB

  const float* W1b = (const float*)d_in[4];
  const float* W2b = (const float*)d_in[5];
  const float* W3b = (const float*)d_in[6];
  const float* Wqb = (const float*)d_in[7];   const float* bqb = (const float*)d_in[8];
  const float* Wkb = (const float*)d_in[9];   const float* bkb = (const float*)d_in[10];
  const float* Wvb = (const float*)d_in[11];  const float* bvb = (const float*)d_in[12];
  const float* Wob = (const float*)d_in[13];  const float* bob = (const float*)d_in[14];
  const float* Wm1b = (const float*)d_in[15]; const float* bm1b = (const float*)d_in[16];
  const float* Wm2b = (const float*)d_in[17]; const float* bm2b = (const float*)d_in[18];

  // -------- setup (3 launches) --------
  k_knnp<<<dim3(NPV, 4), dim3(256), 0, stream>>>((const float*)d_in[0],
                                                 (const float*)d_in[2], KN1, KN2);
  k_setup<<<dim3(12804), dim3(256), 0, stream>>>(
      (const float*)d_in[1], (const float*)d_in[3], S0, S1,
      W1b, W2b, UVS, Wob, WOT, Wm1b, WFULL, bm1b, bob, BCOMB);
  k_gemm<false, false, false, 0><<<dim3(4, 2, 2), dim3(256), 0, stream>>>(
      Wm1b + 256, 512, 262144, nullptr, WOT, 256, 65536, nullptr,
      WFULL + 256, 512, 262144, 256, 0, 0, nullptr, 0, 0.f, nullptr, 0,
      0, nullptr);

  // -------- paired gcn layer (6 launches) --------
  auto gcn = [&](int li) {
    const float* UV1 = UVS + (i64)li * 393216;
    const float* UV2 = UVS + (i64)li * 393216 + 131072;
    // hop1 (z=4): PQ1 = X @ [U1;V1]^T (f32)
    k_gemm<false, false, false, 0><<<dim3(16, 4, 4), dim3(256), 0, stream>>>(
        S0, 256, NSTR, nullptr, UV1, 256, 0, nullptr, PQ1, 512, NSTR2, 256, 0, 0,
        nullptr, 0, 0.f, nullptr, 0, 0, nullptr);
    k_gstat<false><<<dim3(1, 64, 4), dim3(256), 0, stream>>>(
        PQ1, PQ1 + 256, 512, KN1, 256, F1d, PARTA);
    // hop2 (z=4): PQ2 = norm(F1) @ [U2;V2]^T -> bf16
    k_gemm<true, false, false, 1><<<dim3(16, 8, 4), dim3(256), 0, stream>>>(
        F1d, 256, NSTR, nullptr, UV2, 256, 0, nullptr,
        (float*)PQ2, 1024, NSTR4, 256, 0, 1,
        PARTA, 64, 1.f / 32768.f, nullptr, 0, 0, nullptr);
    k_gstat<true><<<dim3(2, 64, 4), dim3(256), 0, stream>>>(
        PQ2, PQ2 + 512, 1024, KN1, 512, F2, PARTB);
    // y3 (z=4) + estat, then normP -> slots
    k_y3<<<dim3(16, 2, 4), dim3(256), 0, stream>>>(S0, F1d, F2, W3b, Y3,
                                                   PARTA, PARTB, PARTCg, li);
    k_normP<<<dim3(2048, 1, 4), dim3(256), 0, stream>>>(Y3, S0, 256, PARTCg, 16,
                                                        1.f / 2048.f, 1);
  };

  // -------- cross attention (4 launches) --------
  // tmode: 0 = none, 1 = dual (slot + transposed out), 2 = transposed only
  auto attn = [&](const float* XA, const float* XB, float* XO, int li,
                  int tmode, float* out2) {
    const float* Wq = Wqb + (i64)li * 65536;   const float* bq = bqb + (i64)li * 256;
    const float* Wk = Wkb + (i64)li * 65536;   const float* bk = bkb + (i64)li * 256;
    const float* Wv = Wvb + (i64)li * 65536;   const float* bv = bvb + (i64)li * 256;
    const float* Wm2 = Wm2b + (i64)li * 131072; const float* bm2 = bm2b + (i64)li * 256;
    k_qkv<<<dim3(16, 2, 6), dim3(256), 0, stream>>>(XA, XB, Wq, Wk, Wv,
                                                    bq, bk, bv, Qp, Kp, Vp);
    k_flash<<<dim3(32, 4, BB), dim3(256), 0, stream>>>(Qp, Kp, Vp, Oc);
    k_gemm<false, true, true, 0><<<dim3(16, 4, 2), dim3(256), 0, stream>>>(
        XA, 256, NSTR, Oc, WFULL + (i64)li * 262144, 512, 0,
        BCOMB + (i64)li * 512, Hh, 512, NSTR2, 512, 0, 0,
        nullptr, 0, 0.f, PARTCa, 512, 0, nullptr);
    k_gemm<true, false, false, 0><<<dim3(16, 2, 2), dim3(256), 0, stream>>>(
        Hh, 512, NSTR2, nullptr, Wm2, 512, 0, bm2, XO, 256, NSTR, 512, 0, 2,
        PARTCa, 16, 1.f / 2048.f, nullptr, 0, tmode, out2);
  };

  // -------- 4 layers, 2-slot ping-pong --------
  gcn(0);                                  // S0=f1.a, S1=f2.a
  attn(S0, S1, S0, 0, 0, nullptr);         // S0=f1.b
  attn(S1, S0, S1, 0, 0, nullptr);         // S1=f2.b
  gcn(1);                                  // S0=f1.c, S1=f2.c
  attn(S0, S1, S0, 1, 1, outp);            // S0=f1.d (+ transposed out)
  attn(S1, S0, S1, 1, 2, outp + 1048576);  // f2.d -> transposed out only
}

// Round 9
// 1494.933 us; speedup vs baseline: 65.3466x; 1.0531x over previous
//
#include <hip/hip_runtime.h>

// ============================================================================
// InformationInteractive (gcn, cross_attn, gcn, cross_attn).
// Round 20: RECOVERY. r19's coop mega-kernels corrupted results (absmax ~7e3,
// signature of stats read-before-write => grid.sync not giving the assumed
// ordering). Revert to r18's 31-launch structure (passed, 1574us), keeping
// ONLY knn v4: 1024-thr blocks, 4 points x 4 segment-waves with SHARED coord
// staging (fixes r18's 306us knn: v3 re-staged 2048 coords per 1-point block).
// Segmented 17-extraction + 4-list lex-min merge == serial watermark scan,
// bit-identical. Everything else byte-identical to r18.
// ============================================================================

namespace {

constexpr int BB = 2, NPV = 2048, CCH = 256, KNB = 16;
typedef long long i64;
typedef unsigned short u16;
typedef unsigned int u32;
constexpr i64 NSTR  = (i64)NPV * 256;
constexpr i64 NSTR2 = (i64)NPV * 512;
constexpr i64 NSTR4 = (i64)NPV * 1024;
constexpr i64 MB = 1048576;

typedef __attribute__((ext_vector_type(8))) short short8v;   // 8 bf16
typedef __attribute__((ext_vector_type(4))) float f32x4;

__device__ __forceinline__ float lrelu(float v) { return v >= 0.f ? v : 0.2f * v; }

__device__ __forceinline__ void splitbf(float x, u16& h, u16& l) {
  unsigned u = __float_as_uint(x);
  h = (u16)(u >> 16);
  float hf = __uint_as_float(u & 0xffff0000u);
  l = (u16)(__float_as_uint(x - hf) >> 16);
}

__device__ __forceinline__ u16 f2bf_rn(float x) {   // round-to-nearest-even
  u32 u = __float_as_uint(x);
  return (u16)((u + 0x7fffu + ((u >> 16) & 1u)) >> 16);
}
__device__ __forceinline__ float bf2f(u16 h) {
  return __uint_as_float((u32)h << 16);
}

// ---- diagnostics ------------------------------------------------------------
__global__ __launch_bounds__(256) void k_diag(float* out, int n, float v) {
  int i = blockIdx.x * 256 + threadIdx.x;
  if (i < n) out[i] = v;
}

// ---- setup: cvt both feats, UV splits, WoT, Wfull-left, bcomb --------------
__global__ __launch_bounds__(256) void k_setup(
    const float* __restrict__ fa, const float* __restrict__ fb,
    float* __restrict__ Xa, float* __restrict__ Xb,
    const float* __restrict__ W1b, const float* __restrict__ W2b,
    float* __restrict__ UVS,
    const float* __restrict__ Wob, float* __restrict__ WoT,
    const float* __restrict__ Wm1b_, float* __restrict__ Wfull,
    const float* __restrict__ bm1b_, const float* __restrict__ bob,
    float* __restrict__ bcomb) {
  int blk = blockIdx.x;
  int t = threadIdx.x;
  if (blk < 8192) {
    int gi = blk * 256 + t;
    bool second = gi >= (1 << 20);
    int idx = gi & ((1 << 20) - 1);
    int b = idx >> 19;
    int n = (idx >> 8) & (NPV - 1);
    int c = idx & (CCH - 1);
    const float* f = second ? fb : fa;
    float* X = second ? Xb : Xa;
    X[idx] = f[((i64)b * CCH + c) * NPV + n];
  } else if (blk < 11264) {
    int i = (blk - 8192) * 256 + t;     // 0..786431
    int li = i / 393216;
    int r0 = i - li * 393216;
    const float* W1 = W1b + (i64)li * 131072;
    const float* W2 = W2b + (i64)li * 262144;
    float* dst = UVS + (i64)li * 393216;
    if (r0 < 131072) {
      int r = r0 >> 8, c = r0 & 255;
      dst[r0] = (r < 256) ? W1[(i64)r * 512 + c] - W1[(i64)r * 512 + 256 + c]
                          : W1[(i64)(r - 256) * 512 + 256 + c];
    } else {
      int j = r0 - 131072;
      int r = j >> 8, c = j & 255;
      dst[131072 + j] = (r < 512) ? W2[(i64)r * 512 + c] - W2[(i64)r * 512 + 256 + c]
                                  : W2[(i64)(r - 512) * 512 + 256 + c];
    }
  } else if (blk < 11776) {
    int i = (blk - 11264) * 256 + t;    // WoT[li][c][k] = Wo[li][k][c]
    int li = i >> 16, rem = i & 65535;
    int c = rem >> 8, k = rem & 255;
    WoT[(i64)li * 65536 + c * 256 + k] = Wob[(i64)li * 65536 + k * 256 + c];
  } else if (blk < 12800) {
    int i = (blk - 11776) * 256 + t;    // Wfull left half
    int li = i >> 17, rem = i & 131071;
    int o = rem >> 8, c = rem & 255;
    Wfull[(i64)li * 262144 + o * 512 + c] = Wm1b_[(i64)li * 262144 + o * 512 + c];
  } else {
    int g = (blk - 12800) * 256 + t;    // bcomb[li][o]
    int li = g >> 9, o = g & 511;
    const float* wm1 = Wm1b_ + (i64)li * 262144 + (i64)o * 512 + 256;
    const float* bo = bob + (i64)li * 256;
    float acc = bm1b_[(i64)li * 512 + o];
    for (int k = 0; k < 256; k++) acc += wm1[k] * bo[k];
    bcomb[(i64)li * 512 + o] = acc;
  }
}

// ---- knn v4: 1024 thr, 4 points x 4 segment-waves, shared staging ----------
// Per-wave: 17 lex-min extractions of its 512-candidate segment (watermarked
// scan over 8 regs + butterfly) == sorted top-17 of segment. Wave w<4 merges
// point w's 4 sorted lists -> identical extraction sequence as serial scan.
__global__ __launch_bounds__(1024) void k_knnp(const float* __restrict__ c1,
                                               const float* __restrict__ c2,
                                               int* __restrict__ o1,
                                               int* __restrict__ o2) {
#pragma clang fp contract(off)   // match np mul-then-add distance arithmetic
  __shared__ float4 csq[NPV];
  __shared__ float md[16 * 17];
  __shared__ int   mi[16 * 17];
  int set = blockIdx.y >> 1, b = blockIdx.y & 1;
  const float* cb = (set ? c2 : c1) + (i64)b * 3 * NPV;
  int* ob = (set ? o2 : o1) + (i64)b * NPV * KNB;
  int tid = threadIdx.x;
  for (int m = tid; m < NPV; m += 1024) {
    float x = cb[m], y = cb[NPV + m], z = cb[2 * NPV + m];
    csq[m] = make_float4(x, y, z, x * x + y * y + z * z);
  }
  __syncthreads();
  int w = tid >> 6, lane = tid & 63;
  int p = w & 3, s = w >> 2;
  int n = blockIdx.x * 4 + p;
  float4 cn = csq[n];
  float xn = cn.x, yn = cn.y, zn = cn.z, sn = cn.w;
  float dc[8];
#pragma unroll
  for (int t = 0; t < 8; t++) {
    float4 c = csq[s * 512 + t * 64 + lane];
    float dot = xn * c.x + yn * c.y + zn * c.z;
    dc[t] = (sn + c.w) - 2.0f * dot;
  }
  float wd = -3.4e38f; int wm = -1;
  for (int r = 0; r < KNB + 1; r++) {
    float bd = 3.4e38f; int bm = 0x7fffffff;
#pragma unroll
    for (int t = 0; t < 8; t++) {
      int m = s * 512 + t * 64 + lane;
      float d = dc[t];
      bool valid = (d > wd) || (d == wd && m > wm);
      if (valid && (d < bd || (d == bd && m < bm))) { bd = d; bm = m; }
    }
    for (int mask = 1; mask < 64; mask <<= 1) {
      float od = __shfl_xor(bd, mask);
      int om = __shfl_xor(bm, mask);
      if (od < bd || (od == bd && om < bm)) { bd = od; bm = om; }
    }
    if (lane == 0) { md[w * 17 + r] = bd; mi[w * 17 + r] = bm; }
    wd = bd; wm = bm;
  }
  __syncthreads();
  if (w < 4) {   // wave w merges point w's lists (waves lane*4+w, s=lane)
    int ptr = 0;
    float hd = (lane < 4) ? md[(lane * 4 + w) * 17] : 3.4e38f;
    int   hm = (lane < 4) ? mi[(lane * 4 + w) * 17] : 0x7fffffff;
    int* o = ob + (i64)(blockIdx.x * 4 + w) * KNB;
    for (int r = 0; r < KNB + 1; r++) {
      float bd = hd; int bm = hm;
      for (int mask = 1; mask < 64; mask <<= 1) {
        float od = __shfl_xor(bd, mask);
        int om = __shfl_xor(bm, mask);
        if (od < bd || (od == bd && om < bm)) { bd = od; bm = om; }
      }
      if (r > 0 && lane == 0) o[r - 1] = bm & (NPV - 1);
      if (lane < 4 && hd == bd && hm == bm) {
        ptr++;
        hd = (ptr < 17) ? md[(lane * 4 + w) * 17 + ptr] : 3.4e38f;
        hm = (ptr < 17) ? mi[(lane * 4 + w) * 17 + ptr] : 0x7fffffff;
      }
    }
  }
}

// ---- MFMA split-precision GEMM: C[M,N] = A[M,K]@W[N,K]^T (+bias / +=) -------
// OMODE: 0 = f32 out; 1 = bf16(RTNE) out (C is u16*).
// tmode: 0 none; 1 = also write transposed to out2; 2 = transposed ONLY.
template <bool ANORM, bool ACAT, bool ESTAT, int OMODE>
__global__ __launch_bounds__(256) void k_gemm(
    const float* __restrict__ A, int lda, i64 sA,
    const float* __restrict__ A2,
    const float* __restrict__ W, int ldw, i64 sW,
    const float* __restrict__ bias,
    float* __restrict__ C, int ldc, i64 sC,
    int K, int mode, int act,
    const float* __restrict__ pin, int nchA, float invA,
    float* __restrict__ pout, int ncolsTot,
    int tmode, float* __restrict__ out2) {
  __shared__ __align__(16) u16 Ah[128][36], Al[128][36], Bh[128][36], Bl[128][36];
  __shared__ float mv[512], rv[512];
  __shared__ float cs[128][2];
  int b = blockIdx.z;
  A += (i64)b * sA;
  if (ACAT) A2 += (i64)b * NSTR;
  int m0 = blockIdx.x * 128, n0 = blockIdx.y * 128;
  int tid = threadIdx.x;
  int w = tid >> 6, l = tid & 63;
  int wr = w >> 1, wc = w & 1;
  int lc = l & 15, lq = l >> 4;
  int srow = tid >> 1, skh = (tid & 1) * 16;

  if (ANORM) {
    for (int c = tid; c < K; c += 256) {
      float s = 0.f, ss = 0.f;
      for (int hh = 0; hh < nchA; hh++) {
        s  += pin[((i64)(b * nchA + hh) * K + c) * 2];
        ss += pin[((i64)(b * nchA + hh) * K + c) * 2 + 1];
      }
      float mu = s * invA;
      mv[c] = mu;
      rv[c] = 1.0f / sqrtf(ss * invA - mu * mu + 1e-5f);
    }
    __syncthreads();
  }

  const float* Ap = A + (i64)(m0 + srow) * lda + skh;
  const float* Wp = W + (i64)b * sW + (i64)(n0 + srow) * ldw + skh;

  auto loadA = [&](int kt, float4* v) {
#pragma unroll
    for (int j = 0; j < 4; j++) {
      if (ACAT) {
        int col0 = kt + skh;
        const float* ap = (col0 < 256)
            ? A  + (i64)(m0 + srow) * 256 + col0
            : A2 + (i64)(m0 + srow) * 256 + (col0 - 256);
        v[j] = *(const float4*)(ap + j * 4);
      } else {
        v[j] = *(const float4*)(Ap + kt + j * 4);
      }
    }
  };
  auto loadW = [&](int kt, float4* v) {
#pragma unroll
    for (int j = 0; j < 4; j++) v[j] = *(const float4*)(Wp + kt + j * 4);
  };

  float4 ar[4], wv4[4];
  loadA(0, ar); loadW(0, wv4);

  f32x4 acc[4][4];
#pragma unroll
  for (int i = 0; i < 4; i++)
#pragma unroll
    for (int j = 0; j < 4; j++)
#pragma unroll
      for (int r = 0; r < 4; r++) acc[i][j][r] = 0.f;

  int koff = lq * 8;
  for (int kt = 0; kt < K; kt += 32) {
    __syncthreads();
#pragma unroll
    for (int j = 0; j < 4; j++) {
      float4 a = ar[j];
      if (ANORM) {
        float4 mu = *(const float4*)&mv[kt + skh + j * 4];
        float4 rs = *(const float4*)&rv[kt + skh + j * 4];
        a.x = (a.x - mu.x) * rs.x; a.y = (a.y - mu.y) * rs.y;
        a.z = (a.z - mu.z) * rs.z; a.w = (a.w - mu.w) * rs.w;
        if (act == 1) { a.x = lrelu(a.x); a.y = lrelu(a.y);
                        a.z = lrelu(a.z); a.w = lrelu(a.w); }
        else { a.x = fmaxf(a.x, 0.f); a.y = fmaxf(a.y, 0.f);
               a.z = fmaxf(a.z, 0.f); a.w = fmaxf(a.w, 0.f); }
      }
      u16 h0, h1, h2, h3, l0, l1, l2, l3;
      splitbf(a.x, h0, l0); splitbf(a.y, h1, l1);
      splitbf(a.z, h2, l2); splitbf(a.w, h3, l3);
      *(ushort4*)&Ah[srow][skh + j * 4] = make_ushort4(h0, h1, h2, h3);
      *(ushort4*)&Al[srow][skh + j * 4] = make_ushort4(l0, l1, l2, l3);
      float4 bb = wv4[j];
      splitbf(bb.x, h0, l0); splitbf(bb.y, h1, l1);
      splitbf(bb.z, h2, l2); splitbf(bb.w, h3, l3);
      *(ushort4*)&Bh[srow][skh + j * 4] = make_ushort4(h0, h1, h2, h3);
      *(ushort4*)&Bl[srow][skh + j * 4] = make_ushort4(l0, l1, l2, l3);
    }
    __syncthreads();
    if (kt + 32 < K) { loadA(kt + 32, ar); loadW(kt + 32, wv4); }
    short8v ah[4], al4[4], bh[4], bl4[4];
#pragma unroll
    for (int i = 0; i < 4; i++) {
      int r = wr * 64 + i * 16 + lc;
      ah[i]  = *(const short8v*)&Ah[r][koff];
      al4[i] = *(const short8v*)&Al[r][koff];
    }
#pragma unroll
    for (int j = 0; j < 4; j++) {
      int r = wc * 64 + j * 16 + lc;
      bh[j]  = *(const short8v*)&Bh[r][koff];
      bl4[j] = *(const short8v*)&Bl[r][koff];
    }
#pragma unroll
    for (int i = 0; i < 4; i++) {
#pragma unroll
      for (int j = 0; j < 4; j++) {
        acc[i][j] = __builtin_amdgcn_mfma_f32_16x16x32_bf16(ah[i], bh[j], acc[i][j], 0, 0, 0);
        acc[i][j] = __builtin_amdgcn_mfma_f32_16x16x32_bf16(al4[i], bh[j], acc[i][j], 0, 0, 0);
        acc[i][j] = __builtin_amdgcn_mfma_f32_16x16x32_bf16(ah[i], bl4[j], acc[i][j], 0, 0, 0);
      }
    }
  }

  float sj[4] = {0.f, 0.f, 0.f, 0.f}, ssj[4] = {0.f, 0.f, 0.f, 0.f};
#pragma unroll
  for (int j = 0; j < 4; j++) {
    int col = n0 + wc * 64 + j * 16 + lc;
    float bv = (mode == 0 && bias) ? bias[col] : 0.f;
#pragma unroll
    for (int i = 0; i < 4; i++) {
      int rbase = m0 + wr * 64 + i * 16 + lq * 4;
#pragma unroll
      for (int r = 0; r < 4; r++) {
        int row = rbase + r;
        float v;
        if (OMODE == 1) {
          v = acc[i][j][r];
          ((u16*)C)[(i64)b * sC + (i64)row * ldc + col] = f2bf_rn(v);
        } else {
          float* cp = &C[(i64)b * sC + (i64)row * ldc + col];
          v = acc[i][j][r] + ((mode == 0) ? bv : *cp);
          if (tmode != 2) *cp = v;
          if (tmode != 0)
            out2[(i64)b * 524288 + (i64)col * 2048 + row] = v;
        }
        if (ESTAT) { sj[j] += v; ssj[j] += v * v; }
      }
    }
  }
  if (ESTAT) {
#pragma unroll
    for (int j = 0; j < 4; j++) {
      sj[j]  += __shfl_xor(sj[j], 16);  sj[j]  += __shfl_xor(sj[j], 32);
      ssj[j] += __shfl_xor(ssj[j], 16); ssj[j] += __shfl_xor(ssj[j], 32);
    }
    __syncthreads();
    if (wr == 0 && lq == 0) {
#pragma unroll
      for (int j = 0; j < 4; j++) {
        int cl = wc * 64 + j * 16 + lc;
        cs[cl][0] = sj[j]; cs[cl][1] = ssj[j];
      }
    }
    __syncthreads();
    if (wr == 1 && lq == 0) {
#pragma unroll
      for (int j = 0; j < 4; j++) {
        int cl = wc * 64 + j * 16 + lc;
        cs[cl][0] += sj[j]; cs[cl][1] += ssj[j];
      }
    }
    __syncthreads();
    if (tid < 128) {
      i64 slot = ((i64)(b * gridDim.x + blockIdx.x) * ncolsTot + n0 + tid) * 2;
      pout[slot] = cs[tid][0];
      pout[slot + 1] = cs[tid][1];
    }
  }
}

// ---- QKV: grid (16, 2, 6), z = mat*2 + b; K/V -> head-major ----------------
__global__ __launch_bounds__(256) void k_qkv(
    const float* __restrict__ XA, const float* __restrict__ XB,
    const float* __restrict__ Wq, const float* __restrict__ Wk,
    const float* __restrict__ Wv,
    const float* __restrict__ bq, const float* __restrict__ bk,
    const float* __restrict__ bv,
    float* __restrict__ Qp, float* __restrict__ Kp, float* __restrict__ Vp) {
  __shared__ __align__(16) u16 Ah[128][36], Al[128][36], Bh[128][36], Bl[128][36];
  int z = blockIdx.z;
  int mat = z >> 1, b = z & 1;
  const float* A = (mat == 0 ? XA : XB) + (i64)b * NSTR;
  const float* W = (mat == 0 ? Wq : (mat == 1 ? Wk : Wv));
  const float* bias = (mat == 0 ? bq : (mat == 1 ? bk : bv));
  float* C = (mat == 0 ? Qp : (mat == 1 ? Kp : Vp)) + (i64)b * NSTR;
  int m0 = blockIdx.x * 128, n0 = blockIdx.y * 128;
  int tid = threadIdx.x;
  int w = tid >> 6, l = tid & 63;
  int wr = w >> 1, wc = w & 1;
  int lc = l & 15, lq = l >> 4;
  int srow = tid >> 1, skh = (tid & 1) * 16;
  const float* Ap = A + (i64)(m0 + srow) * 256 + skh;
  const float* Wp = W + (i64)(n0 + srow) * 256 + skh;
  float4 ar[4], wv4[4];
#pragma unroll
  for (int j = 0; j < 4; j++) { ar[j] = *(const float4*)(Ap + j * 4);
                                wv4[j] = *(const float4*)(Wp + j * 4); }
  f32x4 acc[4][4];
#pragma unroll
  for (int i = 0; i < 4; i++)
#pragma unroll
    for (int j = 0; j < 4; j++)
#pragma unroll
      for (int r = 0; r < 4; r++) acc[i][j][r] = 0.f;
  int koff = lq * 8;
  for (int kt = 0; kt < 256; kt += 32) {
    __syncthreads();
#pragma unroll
    for (int j = 0; j < 4; j++) {
      u16 h0, h1, h2, h3, l0, l1, l2, l3;
      splitbf(ar[j].x, h0, l0); splitbf(ar[j].y, h1, l1);
      splitbf(ar[j].z, h2, l2); splitbf(ar[j].w, h3, l3);
      *(ushort4*)&Ah[srow][skh + j * 4] = make_ushort4(h0, h1, h2, h3);
      *(ushort4*)&Al[srow][skh + j * 4] = make_ushort4(l0, l1, l2, l3);
      splitbf(wv4[j].x, h0, l0); splitbf(wv4[j].y, h1, l1);
      splitbf(wv4[j].z, h2, l2); splitbf(wv4[j].w, h3, l3);
      *(ushort4*)&Bh[srow][skh + j * 4] = make_ushort4(h0, h1, h2, h3);
      *(ushort4*)&Bl[srow][skh + j * 4] = make_ushort4(l0, l1, l2, l3);
    }
    __syncthreads();
    if (kt + 32 < 256) {
#pragma unroll
      for (int j = 0; j < 4; j++) { ar[j] = *(const float4*)(Ap + kt + 32 + j * 4);
                                    wv4[j] = *(const float4*)(Wp + kt + 32 + j * 4); }
    }
    short8v ah[4], al4[4], bh[4], bl4[4];
#pragma unroll
    for (int i = 0; i < 4; i++) {
      int r = wr * 64 + i * 16 + lc;
      ah[i]  = *(const short8v*)&Ah[r][koff];
      al4[i] = *(const short8v*)&Al[r][koff];
    }
#pragma unroll
    for (int j = 0; j < 4; j++) {
      int r = wc * 64 + j * 16 + lc;
      bh[j]  = *(const short8v*)&Bh[r][koff];
      bl4[j] = *(const short8v*)&Bl[r][koff];
    }
#pragma unroll
    for (int i = 0; i < 4; i++)
#pragma unroll
      for (int j = 0; j < 4; j++) {
        acc[i][j] = __builtin_amdgcn_mfma_f32_16x16x32_bf16(ah[i], bh[j], acc[i][j], 0, 0, 0);
        acc[i][j] = __builtin_amdgcn_mfma_f32_16x16x32_bf16(al4[i], bh[j], acc[i][j], 0, 0, 0);
        acc[i][j] = __builtin_amdgcn_mfma_f32_16x16x32_bf16(ah[i], bl4[j], acc[i][j], 0, 0, 0);
      }
  }
#pragma unroll
  for (int j = 0; j < 4; j++) {
    int col = n0 + wc * 64 + j * 16 + lc;
    float bv = bias[col];
#pragma unroll
    for (int i = 0; i < 4; i++) {
      int rbase = m0 + wr * 64 + i * 16 + lq * 4;
#pragma unroll
      for (int r = 0; r < 4; r++) {
        float v = acc[i][j][r] + bv;
        int row = rbase + r;
        if (mat == 0) C[(i64)row * 256 + col] = v;
        else C[((i64)(col & 3) * 2048 + row) * 64 + (col >> 2)] = v;
      }
    }
  }
}

// ---- Y3 = [X | norm(F1) | norm(F2)] @ W3^T, z=4 paired, + stats -------------
__global__ __launch_bounds__(256) void k_y3(
    const float* __restrict__ Xbase, const float* __restrict__ F1b,
    const float* __restrict__ F2b, const float* __restrict__ W3b,
    float* __restrict__ Cb,
    const float* __restrict__ pA, const float* __restrict__ pB,
    float* __restrict__ pout, int li) {
  __shared__ __align__(16) u16 Ah[128][36], Al[128][36], Bh[128][36], Bl[128][36];
  __shared__ float mv[1024], rv[1024];
  __shared__ float cs[128][2];
  int z = blockIdx.z;
  const float* X = Xbase + (i64)z * NSTR;
  const float* F1 = F1b + (i64)z * NSTR;
  const float* F2 = F2b + (i64)z * NSTR2;
  const float* W3 = W3b + (i64)li * 262144;
  float* C = Cb + (i64)z * NSTR;
  int m0 = blockIdx.x * 128, n0 = blockIdx.y * 128;
  int tid = threadIdx.x;
  int w = tid >> 6, l = tid & 63;
  int wr = w >> 1, wc = w & 1;
  int lc = l & 15, lq = l >> 4;
  int srow = tid >> 1, skh = (tid & 1) * 16;
  for (int c = tid; c < 768; c += 256) {
    int col = 256 + c;
    const float* P; int cols, idx;
    if (col < 512) { P = pA; cols = 256; idx = col - 256; }
    else           { P = pB; cols = 512; idx = col - 512; }
    float s = 0.f, ss = 0.f;
    for (int hh = 0; hh < 64; hh++) {
      s  += P[((i64)(z * 64 + hh) * cols + idx) * 2];
      ss += P[((i64)(z * 64 + hh) * cols + idx) * 2 + 1];
    }
    float mu = s * (1.f / 32768.f);
    mv[col] = mu;
    rv[col] = 1.0f / sqrtf(ss * (1.f / 32768.f) - mu * mu + 1e-5f);
  }
  __syncthreads();
  auto loadA = [&](int kt, float4* v) {
    int col0 = kt + skh;
    const float* ap;
    if (col0 < 256)      ap = X  + (i64)(m0 + srow) * 256 + col0;
    else if (col0 < 512) ap = F1 + (i64)(m0 + srow) * 256 + (col0 - 256);
    else                 ap = F2 + (i64)(m0 + srow) * 512 + (col0 - 512);
#pragma unroll
    for (int j = 0; j < 4; j++) v[j] = *(const float4*)(ap + j * 4);
  };
  const float* Wp = W3 + (i64)(n0 + srow) * 1024 + skh;
  float4 ar[4], wv4[4];
  loadA(0, ar);
#pragma unroll
  for (int j = 0; j < 4; j++) wv4[j] = *(const float4*)(Wp + j * 4);
  f32x4 acc[4][4];
#pragma unroll
  for (int i = 0; i < 4; i++)
#pragma unroll
    for (int j = 0; j < 4; j++)
#pragma unroll
      for (int r = 0; r < 4; r++) acc[i][j][r] = 0.f;
  int koff = lq * 8;
  for (int kt = 0; kt < 1024; kt += 32) {
    __syncthreads();
    int col0 = kt + skh;
#pragma unroll
    for (int j = 0; j < 4; j++) {
      float4 a = ar[j];
      if (col0 >= 256) {
        float4 mu = *(const float4*)&mv[col0 + j * 4];
        float4 rs = *(const float4*)&rv[col0 + j * 4];
        a.x = lrelu((a.x - mu.x) * rs.x);
        a.y = lrelu((a.y - mu.y) * rs.y);
        a.z = lrelu((a.z - mu.z) * rs.z);
        a.w = lrelu((a.w - mu.w) * rs.w);
      }
      u16 h0, h1, h2, h3, l0, l1, l2, l3;
      splitbf(a.x, h0, l0); splitbf(a.y, h1, l1);
      splitbf(a.z, h2, l2); splitbf(a.w, h3, l3);
      *(ushort4*)&Ah[srow][skh + j * 4] = make_ushort4(h0, h1, h2, h3);
      *(ushort4*)&Al[srow][skh + j * 4] = make_ushort4(l0, l1, l2, l3);
      splitbf(wv4[j].x, h0, l0); splitbf(wv4[j].y, h1, l1);
      splitbf(wv4[j].z, h2, l2); splitbf(wv4[j].w, h3, l3);
      *(ushort4*)&Bh[srow][skh + j * 4] = make_ushort4(h0, h1, h2, h3);
      *(ushort4*)&Bl[srow][skh + j * 4] = make_ushort4(l0, l1, l2, l3);
    }
    __syncthreads();
    if (kt + 32 < 1024) {
      loadA(kt + 32, ar);
#pragma unroll
      for (int j = 0; j < 4; j++) wv4[j] = *(const float4*)(Wp + kt + 32 + j * 4);
    }
    short8v ah[4], al4[4], bh[4], bl4[4];
#pragma unroll
    for (int i = 0; i < 4; i++) {
      int r = wr * 64 + i * 16 + lc;
      ah[i]  = *(const short8v*)&Ah[r][koff];
      al4[i] = *(const short8v*)&Al[r][koff];
    }
#pragma unroll
    for (int j = 0; j < 4; j++) {
      int r = wc * 64 + j * 16 + lc;
      bh[j]  = *(const short8v*)&Bh[r][koff];
      bl4[j] = *(const short8v*)&Bl[r][koff];
    }
#pragma unroll
    for (int i = 0; i < 4; i++)
#pragma unroll
      for (int j = 0; j < 4; j++) {
        acc[i][j] = __builtin_amdgcn_mfma_f32_16x16x32_bf16(ah[i], bh[j], acc[i][j], 0, 0, 0);
        acc[i][j] = __builtin_amdgcn_mfma_f32_16x16x32_bf16(al4[i], bh[j], acc[i][j], 0, 0, 0);
        acc[i][j] = __builtin_amdgcn_mfma_f32_16x16x32_bf16(ah[i], bl4[j], acc[i][j], 0, 0, 0);
      }
  }
  float sj[4] = {0.f, 0.f, 0.f, 0.f}, ssj[4] = {0.f, 0.f, 0.f, 0.f};
#pragma unroll
  for (int j = 0; j < 4; j++) {
    int col = n0 + wc * 64 + j * 16 + lc;
#pragma unroll
    for (int i = 0; i < 4; i++) {
      int rbase = m0 + wr * 64 + i * 16 + lq * 4;
#pragma unroll
      for (int r = 0; r < 4; r++) {
        float v = acc[i][j][r];
        C[(i64)(rbase + r) * 256 + col] = v;
        sj[j] += v; ssj[j] += v * v;
      }
    }
  }
#pragma unroll
  for (int j = 0; j < 4; j++) {
    sj[j]  += __shfl_xor(sj[j], 16);  sj[j]  += __shfl_xor(sj[j], 32);
    ssj[j] += __shfl_xor(ssj[j], 16); ssj[j] += __shfl_xor(ssj[j], 32);
  }
  __syncthreads();
  if (wr == 0 && lq == 0) {
#pragma unroll
    for (int j = 0; j < 4; j++) {
      int cl = wc * 64 + j * 16 + lc;
      cs[cl][0] = sj[j]; cs[cl][1] = ssj[j];
    }
  }
  __syncthreads();
  if (wr == 1 && lq == 0) {
#pragma unroll
    for (int j = 0; j < 4; j++) {
      int cl = wc * 64 + j * 16 + lc;
      cs[cl][0] += sj[j]; cs[cl][1] += ssj[j];
    }
  }
  __syncthreads();
  if (tid < 128) {
    i64 slot = ((i64)(z * 16 + blockIdx.x) * 256 + n0 + tid) * 2;
    pout[slot] = cs[tid][0];
    pout[slot + 1] = cs[tid][1];
  }
}

// ---- fused gather: RM = P + max_k Q[j]; partial stats. BF16IN: u16 src -----
template <bool BF16IN>
__global__ __launch_bounds__(256) void k_gstat(const void* __restrict__ Pv,
                                               const void* __restrict__ Qv,
                                               int ldpq,
                                               const int* __restrict__ knn,
                                               int O, float* __restrict__ RM,
                                               float* __restrict__ part) {
  int b = blockIdx.z;
  int o = blockIdx.x * 256 + threadIdx.x;
  int n0 = blockIdx.y * 32;
  RM += (i64)b * 2048 * O;
  knn += ((i64)b * 2048 + n0) * KNB;
  __shared__ int js[32 * KNB];
  for (int i = threadIdx.x; i < 32 * KNB; i += 256) js[i] = knn[i];
  __syncthreads();
  i64 base = (i64)b * 2048 * ldpq;
  float s = 0.f, ss = 0.f;
  for (int r = 0; r < 32; r++) {
    int n = n0 + r;
    float p = BF16IN ? bf2f(((const u16*)Pv)[base + (i64)n * ldpq + o])
                     : ((const float*)Pv)[base + (i64)n * ldpq + o];
    float qm = -3.4e38f, qs = 0.f, qss = 0.f;
#pragma unroll
    for (int k = 0; k < KNB; k++) {
      i64 qoff = base + (i64)js[r * KNB + k] * ldpq + o;
      float q = BF16IN ? bf2f(((const u16*)Qv)[qoff]) : ((const float*)Qv)[qoff];
      qm = fmaxf(qm, q); qs += q; qss += q * q;
    }
    RM[(i64)n * O + o] = p + qm;
    s  += 16.f * p + qs;
    ss += 16.f * p * p + 2.f * p * qs + qss;
  }
  i64 slot = ((i64)b * 64 + blockIdx.y) * O + o;
  part[slot * 2] = s; part[slot * 2 + 1] = ss;
}

// ---- normalize + act, stats from PART; z-major dst --------------------------
__global__ __launch_bounds__(256) void k_normP(const float* __restrict__ src,
                                               float* __restrict__ dst, int cols,
                                               const float* __restrict__ part,
                                               int nch, float inv, int act) {
  int b = blockIdx.z;
  i64 n = blockIdx.x;
  int c = blockIdx.y * 256 + threadIdx.x;
  float s = 0.f, ss = 0.f;
  for (int h = 0; h < nch; h++) {
    s  += part[((i64)(b * nch + h) * cols + c) * 2];
    ss += part[((i64)(b * nch + h) * cols + c) * 2 + 1];
  }
  float mu = s * inv;
  float rs = 1.0f / sqrtf(ss * inv - mu * mu + 1e-5f);
  i64 off = ((i64)b * 2048 + n) * cols + c;
  float v = (src[off] - mu) * rs;
  dst[off] = (act == 1) ? lrelu(v) : fmaxf(v, 0.f);
}

// ---- flash attention: grid (32, 4, B) ---------------------------------------
__global__ __launch_bounds__(256) void k_flash(const float* __restrict__ Qp,
                                               const float* __restrict__ Kp,
                                               const float* __restrict__ Vp,
                                               float* __restrict__ Op) {
  __shared__ __align__(16) u16 Kh[64][76], Kl[64][76];
  __shared__ __align__(16) u16 Vh[64][76], Vl[64][76];   // [d][m]
  __shared__ __align__(16) u16 Ph[4][16][76], Pl[4][16][76];
  int qt = blockIdx.x, h = blockIdx.y, b = blockIdx.z;
  const float* Qb = Qp + (i64)b * NSTR;
  const float* Khm = Kp + (i64)b * NSTR + (i64)h * 131072;
  const float* Vhm = Vp + (i64)b * NSTR + (i64)h * 131072;
  int tid = threadIdx.x;
  int w = tid >> 6, l = tid & 63;
  int lc = l & 15, lq = l >> 4;
  short8v qh[2], ql[2];
  int qrow = qt * 64 + w * 16 + lc;
#pragma unroll
  for (int ks = 0; ks < 2; ks++) {
#pragma unroll
    for (int j = 0; j < 8; j++) {
      float v = Qb[(i64)qrow * 256 + 4 * (ks * 32 + lq * 8 + j) + h];
      u16 hh, ll; splitbf(v, hh, ll);
      qh[ks][j] = (short)hh; ql[ks][j] = (short)ll;
    }
  }
  float m_r[4] = {-3.0e38f, -3.0e38f, -3.0e38f, -3.0e38f};
  float l_r[4] = {0.f, 0.f, 0.f, 0.f};
  f32x4 acc[4];
#pragma unroll
  for (int j = 0; j < 4; j++)
#pragma unroll
    for (int r = 0; r < 4; r++) acc[j][r] = 0.f;

  for (int kt = 0; kt < 32; kt++) {
    __syncthreads();
    {
      const float* Kt = Khm + (i64)kt * 4096;
      const float* Vt = Vhm + (i64)kt * 4096;
#pragma unroll
      for (int q = 0; q < 4; q++) {
        int v = q * 256 + tid;
        int m = v >> 4, d4 = (v & 15) * 4;
        u16 h0, h1, h2, h3, l0, l1, l2, l3;
        float4 kf = *(const float4*)(Kt + (i64)v * 4);
        splitbf(kf.x, h0, l0); splitbf(kf.y, h1, l1);
        splitbf(kf.z, h2, l2); splitbf(kf.w, h3, l3);
        *(ushort4*)&Kh[m][d4] = make_ushort4(h0, h1, h2, h3);
        *(ushort4*)&Kl[m][d4] = make_ushort4(l0, l1, l2, l3);
        float4 vf = *(const float4*)(Vt + (i64)v * 4);
        splitbf(vf.x, h0, l0); splitbf(vf.y, h1, l1);
        splitbf(vf.z, h2, l2); splitbf(vf.w, h3, l3);
        Vh[d4 + 0][m] = h0; Vh[d4 + 1][m] = h1;
        Vh[d4 + 2][m] = h2; Vh[d4 + 3][m] = h3;
        Vl[d4 + 0][m] = l0; Vl[d4 + 1][m] = l1;
        Vl[d4 + 2][m] = l2; Vl[d4 + 3][m] = l3;
      }
    }
    __syncthreads();
    f32x4 s[4];
#pragma unroll
    for (int j = 0; j < 4; j++)
#pragma unroll
      for (int r = 0; r < 4; r++) s[j][r] = 0.f;
#pragma unroll
    for (int ks = 0; ks < 2; ks++) {
      int ko = ks * 32 + lq * 8;
#pragma unroll
      for (int j = 0; j < 4; j++) {
        short8v bh = *(const short8v*)&Kh[j * 16 + lc][ko];
        short8v bl = *(const short8v*)&Kl[j * 16 + lc][ko];
        s[j] = __builtin_amdgcn_mfma_f32_16x16x32_bf16(qh[ks], bh, s[j], 0, 0, 0);
        s[j] = __builtin_amdgcn_mfma_f32_16x16x32_bf16(ql[ks], bh, s[j], 0, 0, 0);
        s[j] = __builtin_amdgcn_mfma_f32_16x16x32_bf16(qh[ks], bl, s[j], 0, 0, 0);
      }
    }
#pragma unroll
    for (int j = 0; j < 4; j++)
#pragma unroll
      for (int r = 0; r < 4; r++) s[j][r] *= 0.125f;
    float rmax[4];
#pragma unroll
    for (int r = 0; r < 4; r++)
      rmax[r] = fmaxf(fmaxf(s[0][r], s[1][r]), fmaxf(s[2][r], s[3][r]));
#pragma unroll
    for (int mask = 1; mask < 16; mask <<= 1)
#pragma unroll
      for (int r = 0; r < 4; r++) rmax[r] = fmaxf(rmax[r], __shfl_xor(rmax[r], mask));
    float fs[4], rsum[4];
#pragma unroll
    for (int r = 0; r < 4; r++) {
      float mn = fmaxf(m_r[r], rmax[r]);
      fs[r] = expf(m_r[r] - mn);
      m_r[r] = mn; rsum[r] = 0.f;
    }
#pragma unroll
    for (int j = 0; j < 4; j++)
#pragma unroll
      for (int r = 0; r < 4; r++) {
        float p = expf(s[j][r] - m_r[r]);
        rsum[r] += p;
        u16 hh, ll; splitbf(p, hh, ll);
        Ph[w][lq * 4 + r][j * 16 + lc] = hh;
        Pl[w][lq * 4 + r][j * 16 + lc] = ll;
      }
#pragma unroll
    for (int mask = 1; mask < 16; mask <<= 1)
#pragma unroll
      for (int r = 0; r < 4; r++) rsum[r] += __shfl_xor(rsum[r], mask);
#pragma unroll
    for (int r = 0; r < 4; r++) l_r[r] = l_r[r] * fs[r] + rsum[r];
#pragma unroll
    for (int j = 0; j < 4; j++)
#pragma unroll
      for (int r = 0; r < 4; r++) acc[j][r] *= fs[r];
#pragma unroll
    for (int ks = 0; ks < 2; ks++) {
      int ko = ks * 32 + lq * 8;
      short8v ph = *(const short8v*)&Ph[w][lc][ko];
      short8v pl = *(const short8v*)&Pl[w][lc][ko];
#pragma unroll
      for (int j = 0; j < 4; j++) {
        short8v bh = *(const short8v*)&Vh[j * 16 + lc][ko];
        short8v bl = *(const short8v*)&Vl[j * 16 + lc][ko];
        acc[j] = __builtin_amdgcn_mfma_f32_16x16x32_bf16(ph, bh, acc[j], 0, 0, 0);
        acc[j] = __builtin_amdgcn_mfma_f32_16x16x32_bf16(pl, bh, acc[j], 0, 0, 0);
        acc[j] = __builtin_amdgcn_mfma_f32_16x16x32_bf16(ph, bl, acc[j], 0, 0, 0);
      }
    }
  }
  float* Ob = Op + (i64)b * NSTR;
#pragma unroll
  for (int j = 0; j < 4; j++) {
    int dd = j * 16 + lc;
#pragma unroll
    for (int r = 0; r < 4; r++) {
      int q = qt * 64 + w * 16 + lq * 4 + r;
      Ob[(i64)q * 256 + 4 * dd + h] = acc[j][r] / l_r[r];
    }
  }
}

}  // namespace

// ============================================================================
extern "C" void kernel_launch(void* const* d_in, const int* in_sizes, int n_in,
                              void* d_out, int out_size, void* d_ws, size_t ws_size,
                              hipStream_t stream) {
  float* outp = (float*)d_out;
  auto diag = [&](float v) {
    k_diag<<<dim3((out_size + 255) / 256), dim3(256), 0, stream>>>(outp, out_size, v);
  };

  static const int DSZ[19] = {12288, 1048576, 12288, 1048576, 262144, 524288, 524288,
                              131072, 512, 131072, 512, 131072, 512, 131072, 512,
                              524288, 1024, 262144, 512};
  if (n_in != 19) { diag(1000.f + (float)n_in); return; }
  for (int i = 0; i < 19; i++) {
    if (in_sizes[i] != DSZ[i]) { diag(2000.f + (float)i); return; }
  }
  if (out_size != 2097152) { diag(3000.f); return; }
  constexpr size_t NEED = 50331648;  // 48 MiB
  if (ws_size < NEED) { diag((float)(ws_size >> 20)); return; }

  // -------- workspace map ----------------------------------------------------
  char* w = (char*)d_ws;
  float* S0 = (float*)(w + 0);                  // [2][2048][256] (f1)
  float* S1 = (float*)(w + 4 * MB);             // (f2) adjacent (z-major [4])
  int*   KN1 = (int*)(w + 8 * MB);              // 256 KB
  int*   KN2 = (int*)(w + 8 * MB + 262144);     // 256 KB
  float* PARTA = (float*)(w + 8912896);         // [4][64][256][2] 512 KB
  float* PARTB = (float*)(w + 9437184);         // [4][64][512][2] 1 MB
  float* PARTCg = (float*)(w + 10485760);       // [4][16][256][2] 128 KB
  float* PARTCa = (float*)(w + 10616832);       // [2][16][512][2] 128 KB
  float* BCOMB = (float*)(w + 10747904);        // [2][512] 4 KB
  float* UVS   = (float*)(w + 10752000);        // 3 MB
  float* WFULL = (float*)(w + 13897728);        // [2][512][512] 2 MB
  char* AR = w + 15994880;                      // ~32.7 MB arena

  // setup overlay
  float* WOT = (float*)(AR + 24 * MB);          // 512 KB (setup only)
  // gcn overlay
  float* PQ1 = (float*)(AR);                    // [4][2048][512] f32 16 MB
  u16*   PQ2 = (u16*)(AR);                      // [4][2048][1024] bf16 16 MB
  float* F2  = (float*)(AR + 16 * MB);          // [4][2048][512] f32 16 MB
  float* Y3  = (float*)(AR);                    // [4][2048][256] f32 8 MB
  float* F1d = (float*)d_out;                   // [4][2048][256] 8 MB scratch
  // attention overlay
  float* Qp = (float*)(AR);                     // 4 MB
  float* Kp = (float*)(AR + 4 * MB);            // 4 MB head-major
  float* Vp = (float*)(AR + 8 * MB);            // 4 MB head-major
  float* Oc = (float*)(AR + 12 * MB);           // 4 MB
  float* Hh = (float*)(AR + 16 * MB);           // 8 MB

  const float* W1b = (const float*)d_in[4];
  const float* W2b = (const float*)d_in[5];
  const float* W3b = (const float*)d_in[6];
  const float* Wqb = (const float*)d_in[7];   const float* bqb = (const float*)d_in[8];
  const float* Wkb = (const float*)d_in[9];   const float* bkb = (const float*)d_in[10];
  const float* Wvb = (const float*)d_in[11];  const float* bvb = (const float*)d_in[12];
  const float* Wob = (const float*)d_in[13];  const float* bob = (const float*)d_in[14];
  const float* Wm1b = (const float*)d_in[15]; const float* bm1b = (const float*)d_in[16];
  const float* Wm2b = (const float*)d_in[17]; const float* bm2b = (const float*)d_in[18];

  // -------- setup (3 launches) --------
  k_knnp<<<dim3(NPV / 4, 4), dim3(1024), 0, stream>>>(
      (const float*)d_in[0], (const float*)d_in[2], KN1, KN2);
  k_setup<<<dim3(12804), dim3(256), 0, stream>>>(
      (const float*)d_in[1], (const float*)d_in[3], S0, S1,
      W1b, W2b, UVS, Wob, WOT, Wm1b, WFULL, bm1b, bob, BCOMB);
  k_gemm<false, false, false, 0><<<dim3(4, 2, 2), dim3(256), 0, stream>>>(
      Wm1b + 256, 512, 262144, nullptr, WOT, 256, 65536, nullptr,
      WFULL + 256, 512, 262144, 256, 0, 0, nullptr, 0, 0.f, nullptr, 0,
      0, nullptr);

  // -------- paired gcn layer (6 launches) --------
  auto gcn = [&](int li) {
    const float* UV1 = UVS + (i64)li * 393216;
    const float* UV2 = UVS + (i64)li * 393216 + 131072;
    // hop1 (z=4): PQ1 = X @ [U1;V1]^T (f32)
    k_gemm<false, false, false, 0><<<dim3(16, 4, 4), dim3(256), 0, stream>>>(
        S0, 256, NSTR, nullptr, UV1, 256, 0, nullptr, PQ1, 512, NSTR2, 256, 0, 0,
        nullptr, 0, 0.f, nullptr, 0, 0, nullptr);
    k_gstat<false><<<dim3(1, 64, 4), dim3(256), 0, stream>>>(
        PQ1, PQ1 + 256, 512, KN1, 256, F1d, PARTA);
    // hop2 (z=4): PQ2 = norm(F1) @ [U2;V2]^T -> bf16
    k_gemm<true, false, false, 1><<<dim3(16, 8, 4), dim3(256), 0, stream>>>(
        F1d, 256, NSTR, nullptr, UV2, 256, 0, nullptr,
        (float*)PQ2, 1024, NSTR4, 256, 0, 1,
        PARTA, 64, 1.f / 32768.f, nullptr, 0, 0, nullptr);
    k_gstat<true><<<dim3(2, 64, 4), dim3(256), 0, stream>>>(
        PQ2, PQ2 + 512, 1024, KN1, 512, F2, PARTB);
    // y3 (z=4) + estat, then normP -> slots
    k_y3<<<dim3(16, 2, 4), dim3(256), 0, stream>>>(S0, F1d, F2, W3b, Y3,
                                                   PARTA, PARTB, PARTCg, li);
    k_normP<<<dim3(2048, 1, 4), dim3(256), 0, stream>>>(Y3, S0, 256, PARTCg, 16,
                                                        1.f / 2048.f, 1);
  };

  // -------- cross attention (4 launches) --------
  // tmode: 0 = none, 1 = dual (slot + transposed out), 2 = transposed only
  auto attn = [&](const float* XA, const float* XB, float* XO, int li,
                  int tmode, float* out2) {
    const float* Wq = Wqb + (i64)li * 65536;   const float* bq = bqb + (i64)li * 256;
    const float* Wk = Wkb + (i64)li * 65536;   const float* bk = bkb + (i64)li * 256;
    const float* Wv = Wvb + (i64)li * 65536;   const float* bv = bvb + (i64)li * 256;
    const float* Wm2 = Wm2b + (i64)li * 131072; const float* bm2 = bm2b + (i64)li * 256;
    k_qkv<<<dim3(16, 2, 6), dim3(256), 0, stream>>>(XA, XB, Wq, Wk, Wv,
                                                    bq, bk, bv, Qp, Kp, Vp);
    k_flash<<<dim3(32, 4, BB), dim3(256), 0, stream>>>(Qp, Kp, Vp, Oc);
    k_gemm<false, true, true, 0><<<dim3(16, 4, 2), dim3(256), 0, stream>>>(
        XA, 256, NSTR, Oc, WFULL + (i64)li * 262144, 512, 0,
        BCOMB + (i64)li * 512, Hh, 512, NSTR2, 512, 0, 0,
        nullptr, 0, 0.f, PARTCa, 512, 0, nullptr);
    k_gemm<true, false, false, 0><<<dim3(16, 2, 2), dim3(256), 0, stream>>>(
        Hh, 512, NSTR2, nullptr, Wm2, 512, 0, bm2, XO, 256, NSTR, 512, 0, 2,
        PARTCa, 16, 1.f / 2048.f, nullptr, 0, tmode, out2);
  };

  // -------- 4 layers, 2-slot ping-pong --------
  gcn(0);                                  // S0=f1.a, S1=f2.a
  attn(S0, S1, S0, 0, 0, nullptr);         // S0=f1.b
  attn(S1, S0, S1, 0, 0, nullptr);         // S1=f2.b
  gcn(1);                                  // S0=f1.c, S1=f2.c
  attn(S0, S1, S0, 1, 1, outp);            // S0=f1.d (+ transposed out)
  attn(S1, S0, S1, 1, 2, outp + 1048576);  // f2.d -> transposed out only
}